// Round 1
// baseline (6091.355 us; speedup 1.0000x reference)
//
#include <hip/hip_runtime.h>
#include <math.h>

// DNC: B=32,T=64,I=64,O=64,H=512,N=128,W=64,IF=198
#define Bb 32
#define Tt 64
#define Ii 64
#define Oo 64
#define Hh 512
#define Nn 128
#define Wd 64
#define IFs 198
#define KV 640      /* I + W + H  (gates input vector) */
#define G4 2048     /* 4H */

#define NWG 128
#define NT 512

// ---- LDS layout (float offsets). Per-batch state (wgs 0..31) is disjoint
// from the regions P1 (all wgs) touches, so state survives across phases.
#define OFF_LINK   0        /* 128*129 padded (+1 col kills bank conflicts) */
#define OFF_MEM    16512    /* 128*65 padded */
#define OFF_V      24832    /* 640*8, layout [c*8 + b_local] */
#define OFF_C      29952    /* 512 */
#define OFF_H      30464    /* 512 */
#define OFF_PACC   30976    /* 512*4 gate partials */
#define OFF_ITF    33024    /* 224 */
#define OFF_ERASE  33248
#define OFF_WVEC   33312
#define OFF_USAGE  33376
#define OFF_PREC   33504
#define OFF_RW     33632
#define OFF_WW     33760
#define OFF_DOT    33888
#define OFF_MN     34016
#define OFF_BW     34144
#define OFF_FW     34272
#define OFF_CW     34400
#define OFF_SS     34528
#define OFF_SCAN   34656    /* 256 ping-pong */
#define OFF_RANK   34912    /* 128 ints */
#define OFF_OUTRED 35040    /* 512 */
#define OFF_SCAL   35552    /* 16 scalars */
#define SMEM_FLOATS 35568
#define SMEM_BYTES (SMEM_FLOATS * 4)

#define S_KN 0
#define S_WGAG 1
#define S_RSTR 2
#define S_RM0 3
#define S_RM1 4
#define S_RM2 5
#define S_WWSUM 6
#define S_CMX 7
#define S_CSUM 8
#define S_WSUM 9

// Device-global scratch (avoids any dependence on ws_size; rewritten every call)
__device__ __align__(16) float g_WT[KV * G4];   // WT[c][j] = [W_ih | W_hh] transposed
__device__ __align__(16) float g_bsum[G4];      // b_ih + b_hh
__device__ __align__(16) float g_hg[Bb * Hh];
__device__ __align__(16) float g_rvecg[Bb * Wd];
__device__ __align__(16) float g_gates[Bb * G4];
__device__ unsigned g_cnt;

__device__ __forceinline__ float sigf(float v) { return 1.f / (1.f + expf(-v)); }

// Custom grid barrier: monotone counter, relaxed spin, one acquire fence on exit.
__device__ __forceinline__ void gsync(unsigned& target) {
  __syncthreads();  // compiler drains vmcnt before s_barrier -> all wg stores complete
  if (threadIdx.x == 0) {
    __builtin_amdgcn_fence(__ATOMIC_RELEASE, "agent");   // L2 writeback (cross-XCD publish)
    __hip_atomic_fetch_add(&g_cnt, 1u, __ATOMIC_RELAXED, __HIP_MEMORY_SCOPE_AGENT);
    target += NWG;
    while (__hip_atomic_load(&g_cnt, __ATOMIC_RELAXED, __HIP_MEMORY_SCOPE_AGENT) < target) {
      __builtin_amdgcn_s_sleep(2);
    }
    __builtin_amdgcn_fence(__ATOMIC_ACQUIRE, "agent");   // invalidate L1 + XCD L2
  }
  __syncthreads();
}

__global__ __launch_bounds__(NT) void dnc_init(const float* __restrict__ W_ih,
                                               const float* __restrict__ W_hh,
                                               const float* __restrict__ b_ih,
                                               const float* __restrict__ b_hh) {
  int i0 = blockIdx.x * blockDim.x + threadIdx.x;
  int st = gridDim.x * blockDim.x;
  for (int idx = i0; idx < KV * G4; idx += st) {
    int c = idx >> 11, j = idx & (G4 - 1);   // coalesced writes
    g_WT[idx] = (c < 128) ? W_ih[j * 128 + c] : W_hh[j * 512 + (c - 128)];
  }
  for (int idx = i0; idx < G4; idx += st) g_bsum[idx] = b_ih[idx] + b_hh[idx];
  for (int idx = i0; idx < Bb * Hh; idx += st) g_hg[idx] = 0.f;
  for (int idx = i0; idx < Bb * Wd; idx += st) g_rvecg[idx] = 0.f;
  if (i0 == 0) g_cnt = 0u;
}

__global__ __launch_bounds__(NT) void dnc_main(const float* __restrict__ x,
                                               const float* __restrict__ W_if,
                                               const float* __restrict__ b_if,
                                               const float* __restrict__ W_out,
                                               const float* __restrict__ b_out,
                                               float* __restrict__ out) {
  extern __shared__ float sm[];
  const int tid = threadIdx.x;
  const int wg = blockIdx.x;
  const int jb = wg >> 2;   // 0..31 : j-tile of 64 gate rows / 2 out rows
  const int bb = wg & 3;    // 0..3  : batch tile of 8
  const int b0 = bb * 8;
  unsigned target = 0;

  // zero per-batch state (wg-private, no grid sync needed)
  if (wg < Bb) {
    for (int i = tid; i < 128 * 129; i += NT) sm[OFF_LINK + i] = 0.f;
    for (int i = tid; i < 128 * 65; i += NT) sm[OFF_MEM + i] = 0.f;
    if (tid < 128) { sm[OFF_USAGE + tid] = 0.f; sm[OFF_PREC + tid] = 0.f; sm[OFF_RW + tid] = 0.f; }
    sm[OFF_C + tid] = 0.f;
  }
  __syncthreads();

  for (int t = 0; t <= Tt; ++t) {
    // ================= P1 (all wgs): stage v = [x_t | rvec | h] for 8 batches
    for (int idx = tid; idx < KV * 8; idx += NT) {
      int c = idx >> 3, bl = idx & 7, b = b0 + bl;
      float val = 0.f;
      if (c < 64) {
        if (t < Tt) val = x[(b * Tt + t) * Ii + c];
      } else if (c < 128) {
        val = g_rvecg[b * Wd + (c - 64)];
      } else {
        val = g_hg[b * Hh + (c - 128)];
      }
      sm[OFF_V + idx] = val;
    }
    __syncthreads();

    // gates partials: thread owns 4 consecutive j for one batch over a K-quarter
    if (t < Tt) {
      const int jl = tid & 15, bl = (tid >> 4) & 7, ks = tid >> 7;
      const int j0 = jb * 64 + jl * 4;
      const float4* __restrict__ wp =
          ((const float4*)g_WT) + (size_t)(ks * 160) * (G4 / 4) + (j0 >> 2);
      const float* __restrict__ vp = sm + OFF_V + (ks * 160) * 8 + bl;
      float ax = 0.f, ay = 0.f, az = 0.f, aw = 0.f;
#pragma unroll 4
      for (int c = 0; c < 160; ++c) {
        float4 w4 = wp[c * (G4 / 4)];   // coalesced across lanes (j contiguous)
        float vv = vp[c * 8];
        ax += w4.x * vv; ay += w4.y * vv; az += w4.z * vv; aw += w4.w * vv;
      }
      float4 a; a.x = ax; a.y = ay; a.z = az; a.w = aw;
      ((float4*)(sm + OFF_PACC))[tid] = a;
    }
    // out_{t-1} partials (reuses staged h_{t-1}, rvec_{t-1})
    if (t > 0) {
      const int cs = tid & 31, bl = (tid >> 5) & 7;
      const int o = jb * 2 + (tid >> 8);
      float p = 0.f;
#pragma unroll
      for (int q = 0; q < 18; ++q) {
        int cc = cs * 18 + q;
        float hv = (cc < 512) ? sm[OFF_V + (128 + cc) * 8 + bl]
                              : sm[OFF_V + (64 + (cc - 512)) * 8 + bl];
        p += hv * W_out[o * 576 + cc];
      }
      sm[OFF_OUTRED + tid] = p;
    }
    __syncthreads();
    if (t < Tt && tid < 128) {  // K-reduce + bias, write gates
      const int jl = tid & 15, bl = tid >> 4;
      const int j0 = jb * 64 + jl * 4;
      const float4* pa = (const float4*)(sm + OFF_PACC);
      float4 a0 = pa[tid], a1 = pa[tid + 128], a2 = pa[tid + 256], a3 = pa[tid + 384];
      float4 bs = ((const float4*)g_bsum)[j0 >> 2];
      float4 g;
      g.x = a0.x + a1.x + a2.x + a3.x + bs.x;
      g.y = a0.y + a1.y + a2.y + a3.y + bs.y;
      g.z = a0.z + a1.z + a2.z + a3.z + bs.z;
      g.w = a0.w + a1.w + a2.w + a3.w + bs.w;
      *((float4*)(g_gates + (b0 + bl) * G4 + j0)) = g;
    }
    if (t > 0 && (tid & 31) == 0) {  // out reduce + write
      float s = 0.f;
      for (int q = 0; q < 32; ++q) s += sm[OFF_OUTRED + tid + q];
      const int o = jb * 2 + (tid >> 8);
      const int b = b0 + ((tid >> 5) & 7);
      out[(b * Tt + (t - 1)) * Oo + o] = s + b_out[o];
    }
    gsync(target);

    // ================= P2 (wgs 0..31): per-batch LSTM cell + DNC memory
    if (t < Tt) {
      if (wg < Bb) {
        const int b = wg;
        {  // LSTM elementwise
          const int k = tid;
          float ig = g_gates[b * G4 + k];
          float fg = g_gates[b * G4 + 512 + k];
          float gg = g_gates[b * G4 + 1024 + k];
          float og = g_gates[b * G4 + 1536 + k];
          float co = sm[OFF_C + k];
          float cn = sigf(fg) * co + sigf(ig) * tanhf(gg);
          float hn = sigf(og) * tanhf(cn);
          sm[OFF_C + k] = cn;
          sm[OFF_H + k] = hn;
          g_hg[b * Hh + k] = hn;
        }
        __syncthreads();
        // itf = h @ W_if.T + b_if   (port-bound: 405 KB fp32/step — bf16 later)
        if (tid < IFs) {
          const float4* wr = (const float4*)(W_if + tid * Hh);
          const float4* h4 = (const float4*)(sm + OFF_H);
          float acc = b_if[tid];
#pragma unroll 8
          for (int c4 = 0; c4 < Hh / 4; ++c4) {
            float4 w = wr[c4]; float4 h = h4[c4];
            acc += w.x * h.x + w.y * h.y + w.z * h.z + w.w * h.w;
          }
          sm[OFF_ITF + tid] = acc;
        }
        __syncthreads();
        // small derived values + stable ranks (matches jnp stable argsort)
        if (tid < 64) {
          float rk = sm[OFF_ITF + tid];
          sm[OFF_ERASE + tid] = sigf(rk);
          sm[OFF_WVEC + tid] = sm[OFF_ITF + 64 + tid];
          float sq = rk * rk;
          for (int off = 32; off > 0; off >>= 1) sq += __shfl_down(sq, off, 64);
          if (tid == 0) sm[OFF_SCAL + S_KN] = sqrtf(sq) + 1e-8f;
        } else if (tid == 64) {
          sm[OFF_SCAL + S_WGAG] = sigf(sm[OFF_ITF + 128]) * sigf(sm[OFF_ITF + 129]);
          float rs = sm[OFF_ITF + 194];
          sm[OFF_SCAL + S_RSTR] = (rs > 20.f) ? rs : log1pf(expf(rs));
          float m0 = sm[OFF_ITF + 195], m1 = sm[OFF_ITF + 196], m2 = sm[OFF_ITF + 197];
          float mx = fmaxf(m0, fmaxf(m1, m2));
          float e0 = expf(m0 - mx), e1 = expf(m1 - mx), e2 = expf(m2 - mx);
          float es = e0 + e1 + e2;
          sm[OFF_SCAL + S_RM0] = e0 / es;
          sm[OFF_SCAL + S_RM1] = e1 / es;
          sm[OFF_SCAL + S_RM2] = e2 / es;
        }
        if (tid < 128) {
          float ui = sm[OFF_USAGE + tid];
          int r = 0;
          for (int j2 = 0; j2 < 128; ++j2) {
            float uj = sm[OFF_USAGE + j2];
            r += (uj < ui || (uj == ui && j2 < tid)) ? 1 : 0;
          }
          ((int*)(sm + OFF_RANK))[tid] = r;
          sm[OFF_SS + r] = ui;  // scatter into sorted order
        }
        __syncthreads();
        // inclusive prefix-product of sorted usage (Hillis-Steele)
        if (tid < 128) sm[OFF_SCAN + tid] = sm[OFF_SS + tid];
        int cur = 0;
        for (int off = 1; off < 128; off <<= 1) {
          __syncthreads();
          if (tid < 128) {
            float v = sm[OFF_SCAN + cur * 128 + tid];
            if (tid >= off) v *= sm[OFF_SCAN + cur * 128 + tid - off];
            sm[OFF_SCAN + (1 - cur) * 128 + tid] = v;
          }
          cur ^= 1;
        }
        __syncthreads();
        if (tid < 128) {  // alloc -> ww
          int r = ((int*)(sm + OFF_RANK))[tid];
          float excl = (r > 0) ? sm[OFF_SCAN + cur * 128 + r - 1] : 1.f;
          float ui = sm[OFF_USAGE + tid];
          sm[OFF_WW + tid] = sm[OFF_SCAL + S_WGAG] * (1.f - ui) * excl;
        }
        __syncthreads();
        if (tid < 64) {  // ww sum
          float s = sm[OFF_WW + tid] + sm[OFF_WW + tid + 64];
          for (int off = 32; off > 0; off >>= 1) s += __shfl_down(s, off, 64);
          if (tid == 0) sm[OFF_SCAL + S_WWSUM] = s;
        }
        // mem update
        for (int idx = tid; idx < Nn * Wd; idx += NT) {
          int n = idx >> 6, w = idx & 63;
          float wwn = sm[OFF_WW + n];
          float m = sm[OFF_MEM + n * 65 + w];
          sm[OFF_MEM + n * 65 + w] =
              m * (1.f - wwn * sm[OFF_ERASE + w]) + wwn * sm[OFF_WVEC + w];
        }
        // link update (reads OLD prec)
        for (int idx = tid; idx < Nn * Nn; idx += NT) {
          int i2 = idx >> 7, j2 = idx & 127;
          float wwi = sm[OFF_WW + i2], wwj = sm[OFF_WW + j2];
          float L = sm[OFF_LINK + i2 * 129 + j2];
          L = (1.f - wwi - wwj) * L + sm[OFF_PREC + i2] * wwj;
          sm[OFF_LINK + i2 * 129 + j2] = (i2 == j2) ? 0.f : L;
        }
        if (tid < 128) {  // usage update (rank already consumed old usage)
          float u = sm[OFF_USAGE + tid];
          sm[OFF_USAGE + tid] = u + (1.f - u) * sm[OFF_WW + tid];
        }
        __syncthreads();
        // prec update + content dot/norms + bw/fw (uses NEW link, OLD rw)
        if (tid < 128) {
          sm[OFF_PREC + tid] =
              (1.f - sm[OFF_SCAL + S_WWSUM]) * sm[OFF_PREC + tid] + sm[OFF_WW + tid];
          float d = 0.f;
          for (int w = 0; w < 64; ++w) d += sm[OFF_ITF + w] * sm[OFF_MEM + tid * 65 + w];
          sm[OFF_DOT + tid] = d;
        } else if (tid < 256) {
          int n = tid - 128; float s2 = 0.f;
          for (int w = 0; w < 64; ++w) { float m = sm[OFF_MEM + n * 65 + w]; s2 += m * m; }
          sm[OFF_MN + n] = sqrtf(s2) + 1e-8f;
        } else if (tid < 384) {
          int m2 = tid - 256; float s = 0.f;
          for (int n = 0; n < 128; ++n) s += sm[OFF_LINK + n * 129 + m2] * sm[OFF_RW + n];
          sm[OFF_BW + m2] = s;
        } else {
          int n = tid - 384; float s = 0.f;
          for (int m2 = 0; m2 < 128; ++m2) s += sm[OFF_LINK + n * 129 + m2] * sm[OFF_RW + m2];
          sm[OFF_FW + n] = s;
        }
        __syncthreads();
        // cosine softmax
        if (tid < 128) {
          float q = sm[OFF_DOT + tid] / (sm[OFF_SCAL + S_KN] * sm[OFF_MN + tid]) *
                    sm[OFF_SCAL + S_RSTR];
          sm[OFF_CW + tid] = q;
        }
        __syncthreads();
        if (tid < 64) {
          float mx = fmaxf(sm[OFF_CW + tid], sm[OFF_CW + tid + 64]);
          for (int off = 32; off > 0; off >>= 1) mx = fmaxf(mx, __shfl_down(mx, off, 64));
          if (tid == 0) sm[OFF_SCAL + S_CMX] = mx;
        }
        __syncthreads();
        if (tid < 128) sm[OFF_CW + tid] = expf(sm[OFF_CW + tid] - sm[OFF_SCAL + S_CMX]);
        __syncthreads();
        if (tid < 64) {
          float s = sm[OFF_CW + tid] + sm[OFF_CW + tid + 64];
          for (int off = 32; off > 0; off >>= 1) s += __shfl_down(s, off, 64);
          if (tid == 0) sm[OFF_SCAL + S_CSUM] = s;
        }
        __syncthreads();
        if (tid < 128) {  // combined weights
          float cwv = sm[OFF_CW + tid] / sm[OFF_SCAL + S_CSUM];
          float wv = sm[OFF_SCAL + S_RM0] * sm[OFF_BW + tid] +
                     sm[OFF_SCAL + S_RM1] * sm[OFF_FW + tid] +
                     sm[OFF_SCAL + S_RM2] * cwv + 1e-8f;
          sm[OFF_CW + tid] = wv;
        }
        __syncthreads();
        if (tid < 64) {
          float s = sm[OFF_CW + tid] + sm[OFF_CW + tid + 64];
          for (int off = 32; off > 0; off >>= 1) s += __shfl_down(s, off, 64);
          if (tid == 0) sm[OFF_SCAL + S_WSUM] = s;
        }
        __syncthreads();
        if (tid < 128) sm[OFF_RW + tid] = sm[OFF_CW + tid] / sm[OFF_SCAL + S_WSUM];
        __syncthreads();
        if (tid < 64) {  // rvec = wts @ mem -> global (needed by P1 of t+1)
          float s = 0.f;
          for (int n = 0; n < 128; ++n) s += sm[OFF_RW + n] * sm[OFF_MEM + n * 65 + tid];
          g_rvecg[b * Wd + tid] = s;
        }
      }
      gsync(target);
    }
  }
}

extern "C" void kernel_launch(void* const* d_in, const int* in_sizes, int n_in,
                              void* d_out, int out_size, void* d_ws, size_t ws_size,
                              hipStream_t stream) {
  (void)in_sizes; (void)n_in; (void)d_ws; (void)ws_size; (void)out_size;
  const float* x    = (const float*)d_in[0];
  const float* W_ih = (const float*)d_in[1];
  const float* W_hh = (const float*)d_in[2];
  const float* b_ih = (const float*)d_in[3];
  const float* b_hh = (const float*)d_in[4];
  const float* W_if = (const float*)d_in[5];
  const float* b_if = (const float*)d_in[6];
  const float* W_out = (const float*)d_in[7];
  const float* b_out = (const float*)d_in[8];
  float* out = (float*)d_out;

  dnc_init<<<1280, NT, 0, stream>>>(W_ih, W_hh, b_ih, b_hh);

  // opt-in to >64KB dynamic LDS (idempotent; host-side, capture-safe)
  hipFuncSetAttribute((const void*)dnc_main,
                      hipFuncAttributeMaxDynamicSharedMemorySize, SMEM_BYTES);

  void* args[] = {(void*)&x, (void*)&W_if, (void*)&b_if,
                  (void*)&W_out, (void*)&b_out, (void*)&out};
  hipLaunchCooperativeKernel((void*)dnc_main, dim3(NWG), dim3(NT), args,
                             SMEM_BYTES, stream);
}

// Round 2
// 5672.201 us; speedup vs baseline: 1.0739x; 1.0739x over previous
//
#include <hip/hip_runtime.h>
#include <math.h>

// DNC: B=32,T=64,I=64,O=64,H=512,N=128,W=64,IF=198
#define Bb 32
#define Tt 64
#define Ii 64
#define Oo 64
#define Hh 512
#define Nn 128
#define Wd 64
#define IFs 198
#define KV 640      /* I + W + H  (gates input vector) */
#define G4 2048     /* 4H */

#define NWG 128
#define NT 512

// ---- LDS layout (float offsets). Per-batch state (wgs 0..31) is disjoint
// from the regions P1 (all wgs) touches, so state survives across phases.
#define OFF_LINK   0        /* 128*129 padded (+1 col kills bank conflicts) */
#define OFF_MEM    16512    /* 128*65 padded */
#define OFF_V      24832    /* 640*8, layout [c*8 + b_local] */
#define OFF_C      29952    /* 512 */
#define OFF_H      30464    /* 512 */
#define OFF_PACC   30976    /* 512*4 gate partials */
#define OFF_ITF    33024    /* 224 */
#define OFF_ERASE  33248
#define OFF_WVEC   33312
#define OFF_USAGE  33376
#define OFF_PREC   33504
#define OFF_RW     33632
#define OFF_WW     33760
#define OFF_DOT    33888
#define OFF_MN     34016
#define OFF_BW     34144
#define OFF_FW     34272
#define OFF_CW     34400
#define OFF_SS     34528
#define OFF_SCAN   34656    /* 256 ping-pong */
#define OFF_RANK   34912    /* 128 ints */
#define OFF_SCAL   35040    /* 16 scalars */
#define SMEM_FLOATS 35056
#define SMEM_BYTES (SMEM_FLOATS * 4)

#define S_KN 0
#define S_WGAG 1
#define S_RSTR 2
#define S_RM0 3
#define S_RM1 4
#define S_RM2 5
#define S_WWSUM 6
#define S_CMX 7
#define S_CSUM 8
#define S_WSUM 9

// Device-global scratch (rewritten every call)
__device__ __align__(16) float g_WT[KV * G4];   // WT[c][j] = [W_ih | W_hh] transposed
__device__ __align__(16) float g_bsum[G4];      // b_ih + b_hh
__device__ __align__(16) float g_hg[Bb * Hh];
__device__ __align__(16) float g_rvecg[Bb * Wd];
__device__ __align__(16) float g_gates[Bb * G4];
__device__ unsigned g_cnt;

__device__ __forceinline__ float sigf(float v) { return 1.f / (1.f + expf(-v)); }

// Coherent (cache-bypassing, sc0/sc1) word accesses for cross-wg data.
// Relaxed atomics at agent scope emit NO cache invalidation/writeback —
// unlike agent-scope fences, which buffer_inv the whole XCD L2 (the R1 bug).
__device__ __forceinline__ void cstore(float* p, float v) {
  __hip_atomic_store(p, v, __ATOMIC_RELAXED, __HIP_MEMORY_SCOPE_AGENT);
}
__device__ __forceinline__ float cload(const float* p) {
  return __hip_atomic_load(p, __ATOMIC_RELAXED, __HIP_MEMORY_SCOPE_AGENT);
}

// Grid barrier: monotone counter at coherent point. Workgroup-scope fences
// only (pure s_waitcnt, no cache maintenance). Data flows via cstore/cload,
// so no L2 flush is needed for visibility.
__device__ __forceinline__ void gsync(unsigned& target) {
  __builtin_amdgcn_fence(__ATOMIC_RELEASE, "workgroup");  // waitcnt only
  __syncthreads();   // all waves' vmcnt drained -> write-through stores visible
  if (threadIdx.x == 0) {
    __hip_atomic_fetch_add(&g_cnt, 1u, __ATOMIC_RELAXED, __HIP_MEMORY_SCOPE_AGENT);
    target += NWG;
    while (__hip_atomic_load(&g_cnt, __ATOMIC_RELAXED, __HIP_MEMORY_SCOPE_AGENT) < target) {
      __builtin_amdgcn_s_sleep(2);
    }
  }
  __builtin_amdgcn_fence(__ATOMIC_ACQUIRE, "workgroup");
  __syncthreads();
}

__global__ __launch_bounds__(NT) void dnc_init(const float* __restrict__ W_ih,
                                               const float* __restrict__ W_hh,
                                               const float* __restrict__ b_ih,
                                               const float* __restrict__ b_hh) {
  int i0 = blockIdx.x * blockDim.x + threadIdx.x;
  int st = gridDim.x * blockDim.x;
  for (int idx = i0; idx < KV * G4; idx += st) {
    int c = idx >> 11, j = idx & (G4 - 1);   // coalesced writes
    g_WT[idx] = (c < 128) ? W_ih[j * 128 + c] : W_hh[j * 512 + (c - 128)];
  }
  for (int idx = i0; idx < G4; idx += st) g_bsum[idx] = b_ih[idx] + b_hh[idx];
  for (int idx = i0; idx < Bb * Hh; idx += st) g_hg[idx] = 0.f;
  for (int idx = i0; idx < Bb * Wd; idx += st) g_rvecg[idx] = 0.f;
  if (i0 == 0) g_cnt = 0u;
}

__global__ __launch_bounds__(NT) void dnc_main(const float* __restrict__ x,
                                               const float* __restrict__ W_if,
                                               const float* __restrict__ b_if,
                                               const float* __restrict__ W_out,
                                               const float* __restrict__ b_out,
                                               float* __restrict__ out) {
  extern __shared__ float sm[];
  const int tid = threadIdx.x;
  const int wg = blockIdx.x;
  const int jb = wg >> 2;   // 0..31 : j-tile of 64 gate rows / 2 out rows
  const int bb = wg & 3;    // 0..3  : batch tile of 8
  const int b0 = bb * 8;
  unsigned target = 0;

  // zero per-batch state (wg-private, no grid sync needed)
  if (wg < Bb) {
    for (int i = tid; i < 128 * 129; i += NT) sm[OFF_LINK + i] = 0.f;
    for (int i = tid; i < 128 * 65; i += NT) sm[OFF_MEM + i] = 0.f;
    if (tid < 128) { sm[OFF_USAGE + tid] = 0.f; sm[OFF_PREC + tid] = 0.f; sm[OFF_RW + tid] = 0.f; }
    sm[OFF_C + tid] = 0.f;
  }
  __syncthreads();

  for (int t = 0; t <= Tt; ++t) {
    // ================= P1 (all wgs): stage v = [x_t | rvec | h] for 8 batches
    for (int idx = tid; idx < KV * 8; idx += NT) {
      int c = idx >> 3, bl = idx & 7, b = b0 + bl;
      float val = 0.f;
      if (c < 64) {
        if (t < Tt) val = x[(b * Tt + t) * Ii + c];
      } else if (c < 128) {
        val = cload(g_rvecg + b * Wd + (c - 64));
      } else {
        val = cload(g_hg + b * Hh + (c - 128));
      }
      sm[OFF_V + idx] = val;
    }
    __syncthreads();

    // gates partials: thread owns 4 consecutive j for one batch over a K-quarter
    if (t < Tt) {
      const int jl = tid & 15, bl = (tid >> 4) & 7, ks = tid >> 7;
      const int j0 = jb * 64 + jl * 4;
      const float4* __restrict__ wp =
          ((const float4*)g_WT) + (size_t)(ks * 160) * (G4 / 4) + (j0 >> 2);
      const float* __restrict__ vp = sm + OFF_V + (ks * 160) * 8 + bl;
      float ax = 0.f, ay = 0.f, az = 0.f, aw = 0.f;
#pragma unroll 4
      for (int c = 0; c < 160; ++c) {
        float4 w4 = wp[c * (G4 / 4)];   // coalesced across lanes (j contiguous)
        float vv = vp[c * 8];
        ax += w4.x * vv; ay += w4.y * vv; az += w4.z * vv; aw += w4.w * vv;
      }
      float4 a; a.x = ax; a.y = ay; a.z = az; a.w = aw;
      ((float4*)(sm + OFF_PACC))[tid] = a;
    }
    // out_{t-1}: partial over 18 c's then 32-lane shuffle reduce (no LDS,
    // kills the 16-way bank conflict of the old serial reduce)
    if (t > 0) {
      const int cs = tid & 31, bl = (tid >> 5) & 7;
      const int o = jb * 2 + (tid >> 8);
      float p = 0.f;
#pragma unroll
      for (int q = 0; q < 18; ++q) {
        int cc = cs * 18 + q;
        float hv = (cc < 512) ? sm[OFF_V + (128 + cc) * 8 + bl]
                              : sm[OFF_V + (64 + (cc - 512)) * 8 + bl];
        p += hv * W_out[o * 576 + cc];
      }
      for (int off = 16; off > 0; off >>= 1) p += __shfl_down(p, off, 32);
      if (cs == 0) {
        const int b = b0 + bl;
        out[(b * Tt + (t - 1)) * Oo + o] = p + b_out[o];
      }
    }
    __syncthreads();
    if (t < Tt && tid < 128) {  // K-reduce + bias, write gates (coherent words)
      const int jl = tid & 15, bl = tid >> 4;
      const int j0 = jb * 64 + jl * 4;
      const float4* pa = (const float4*)(sm + OFF_PACC);
      float4 a0 = pa[tid], a1 = pa[tid + 128], a2 = pa[tid + 256], a3 = pa[tid + 384];
      float4 bs = ((const float4*)g_bsum)[j0 >> 2];
      float* gp = g_gates + (b0 + bl) * G4 + j0;
      cstore(gp + 0, a0.x + a1.x + a2.x + a3.x + bs.x);
      cstore(gp + 1, a0.y + a1.y + a2.y + a3.y + bs.y);
      cstore(gp + 2, a0.z + a1.z + a2.z + a3.z + bs.z);
      cstore(gp + 3, a0.w + a1.w + a2.w + a3.w + bs.w);
    }
    gsync(target);

    // ================= P2 (wgs 0..31): per-batch LSTM cell + DNC memory
    if (t < Tt) {
      if (wg < Bb) {
        const int b = wg;
        {  // LSTM elementwise
          const int k = tid;
          float ig = cload(g_gates + b * G4 + k);
          float fg = cload(g_gates + b * G4 + 512 + k);
          float gg = cload(g_gates + b * G4 + 1024 + k);
          float og = cload(g_gates + b * G4 + 1536 + k);
          float co = sm[OFF_C + k];
          float cn = sigf(fg) * co + sigf(ig) * tanhf(gg);
          float hn = sigf(og) * tanhf(cn);
          sm[OFF_C + k] = cn;
          sm[OFF_H + k] = hn;
          cstore(g_hg + b * Hh + k, hn);
        }
        __syncthreads();
        // itf = h @ W_if.T + b_if
        if (tid < IFs) {
          const float4* wr = (const float4*)(W_if + tid * Hh);
          const float4* h4 = (const float4*)(sm + OFF_H);
          float acc = b_if[tid];
#pragma unroll 8
          for (int c4 = 0; c4 < Hh / 4; ++c4) {
            float4 w = wr[c4]; float4 h = h4[c4];
            acc += w.x * h.x + w.y * h.y + w.z * h.z + w.w * h.w;
          }
          sm[OFF_ITF + tid] = acc;
        }
        __syncthreads();
        // small derived values + stable ranks (matches jnp stable argsort)
        if (tid < 64) {
          float rk = sm[OFF_ITF + tid];
          sm[OFF_ERASE + tid] = sigf(rk);
          sm[OFF_WVEC + tid] = sm[OFF_ITF + 64 + tid];
          float sq = rk * rk;
          for (int off = 32; off > 0; off >>= 1) sq += __shfl_down(sq, off, 64);
          if (tid == 0) sm[OFF_SCAL + S_KN] = sqrtf(sq) + 1e-8f;
        } else if (tid == 64) {
          sm[OFF_SCAL + S_WGAG] = sigf(sm[OFF_ITF + 128]) * sigf(sm[OFF_ITF + 129]);
          float rs = sm[OFF_ITF + 194];
          sm[OFF_SCAL + S_RSTR] = (rs > 20.f) ? rs : log1pf(expf(rs));
          float m0 = sm[OFF_ITF + 195], m1 = sm[OFF_ITF + 196], m2 = sm[OFF_ITF + 197];
          float mx = fmaxf(m0, fmaxf(m1, m2));
          float e0 = expf(m0 - mx), e1 = expf(m1 - mx), e2 = expf(m2 - mx);
          float es = e0 + e1 + e2;
          sm[OFF_SCAL + S_RM0] = e0 / es;
          sm[OFF_SCAL + S_RM1] = e1 / es;
          sm[OFF_SCAL + S_RM2] = e2 / es;
        }
        if (tid < 128) {
          float ui = sm[OFF_USAGE + tid];
          int r = 0;
          for (int j2 = 0; j2 < 128; ++j2) {
            float uj = sm[OFF_USAGE + j2];
            r += (uj < ui || (uj == ui && j2 < tid)) ? 1 : 0;
          }
          ((int*)(sm + OFF_RANK))[tid] = r;
          sm[OFF_SS + r] = ui;  // scatter into sorted order
        }
        __syncthreads();
        // inclusive prefix-product of sorted usage (Hillis-Steele)
        if (tid < 128) sm[OFF_SCAN + tid] = sm[OFF_SS + tid];
        int cur = 0;
        for (int off = 1; off < 128; off <<= 1) {
          __syncthreads();
          if (tid < 128) {
            float v = sm[OFF_SCAN + cur * 128 + tid];
            if (tid >= off) v *= sm[OFF_SCAN + cur * 128 + tid - off];
            sm[OFF_SCAN + (1 - cur) * 128 + tid] = v;
          }
          cur ^= 1;
        }
        __syncthreads();
        if (tid < 128) {  // alloc -> ww
          int r = ((int*)(sm + OFF_RANK))[tid];
          float excl = (r > 0) ? sm[OFF_SCAN + cur * 128 + r - 1] : 1.f;
          float ui = sm[OFF_USAGE + tid];
          sm[OFF_WW + tid] = sm[OFF_SCAL + S_WGAG] * (1.f - ui) * excl;
        }
        __syncthreads();
        if (tid < 64) {  // ww sum
          float s = sm[OFF_WW + tid] + sm[OFF_WW + tid + 64];
          for (int off = 32; off > 0; off >>= 1) s += __shfl_down(s, off, 64);
          if (tid == 0) sm[OFF_SCAL + S_WWSUM] = s;
        }
        // mem update
        for (int idx = tid; idx < Nn * Wd; idx += NT) {
          int n = idx >> 6, w = idx & 63;
          float wwn = sm[OFF_WW + n];
          float m = sm[OFF_MEM + n * 65 + w];
          sm[OFF_MEM + n * 65 + w] =
              m * (1.f - wwn * sm[OFF_ERASE + w]) + wwn * sm[OFF_WVEC + w];
        }
        // link update (reads OLD prec)
        for (int idx = tid; idx < Nn * Nn; idx += NT) {
          int i2 = idx >> 7, j2 = idx & 127;
          float wwi = sm[OFF_WW + i2], wwj = sm[OFF_WW + j2];
          float L = sm[OFF_LINK + i2 * 129 + j2];
          L = (1.f - wwi - wwj) * L + sm[OFF_PREC + i2] * wwj;
          sm[OFF_LINK + i2 * 129 + j2] = (i2 == j2) ? 0.f : L;
        }
        if (tid < 128) {  // usage update (rank already consumed old usage)
          float u = sm[OFF_USAGE + tid];
          sm[OFF_USAGE + tid] = u + (1.f - u) * sm[OFF_WW + tid];
        }
        __syncthreads();
        // prec update + content dot/norms + bw/fw (uses NEW link, OLD rw)
        if (tid < 128) {
          sm[OFF_PREC + tid] =
              (1.f - sm[OFF_SCAL + S_WWSUM]) * sm[OFF_PREC + tid] + sm[OFF_WW + tid];
          float d = 0.f;
          for (int w = 0; w < 64; ++w) d += sm[OFF_ITF + w] * sm[OFF_MEM + tid * 65 + w];
          sm[OFF_DOT + tid] = d;
        } else if (tid < 256) {
          int n = tid - 128; float s2 = 0.f;
          for (int w = 0; w < 64; ++w) { float m = sm[OFF_MEM + n * 65 + w]; s2 += m * m; }
          sm[OFF_MN + n] = sqrtf(s2) + 1e-8f;
        } else if (tid < 384) {
          int m2 = tid - 256; float s = 0.f;
          for (int n = 0; n < 128; ++n) s += sm[OFF_LINK + n * 129 + m2] * sm[OFF_RW + n];
          sm[OFF_BW + m2] = s;
        } else {
          int n = tid - 384; float s = 0.f;
          for (int m2 = 0; m2 < 128; ++m2) s += sm[OFF_LINK + n * 129 + m2] * sm[OFF_RW + m2];
          sm[OFF_FW + n] = s;
        }
        __syncthreads();
        // cosine softmax
        if (tid < 128) {
          float q = sm[OFF_DOT + tid] / (sm[OFF_SCAL + S_KN] * sm[OFF_MN + tid]) *
                    sm[OFF_SCAL + S_RSTR];
          sm[OFF_CW + tid] = q;
        }
        __syncthreads();
        if (tid < 64) {
          float mx = fmaxf(sm[OFF_CW + tid], sm[OFF_CW + tid + 64]);
          for (int off = 32; off > 0; off >>= 1) mx = fmaxf(mx, __shfl_down(mx, off, 64));
          if (tid == 0) sm[OFF_SCAL + S_CMX] = mx;
        }
        __syncthreads();
        if (tid < 128) sm[OFF_CW + tid] = expf(sm[OFF_CW + tid] - sm[OFF_SCAL + S_CMX]);
        __syncthreads();
        if (tid < 64) {
          float s = sm[OFF_CW + tid] + sm[OFF_CW + tid + 64];
          for (int off = 32; off > 0; off >>= 1) s += __shfl_down(s, off, 64);
          if (tid == 0) sm[OFF_SCAL + S_CSUM] = s;
        }
        __syncthreads();
        if (tid < 128) {  // combined weights
          float cwv = sm[OFF_CW + tid] / sm[OFF_SCAL + S_CSUM];
          float wv = sm[OFF_SCAL + S_RM0] * sm[OFF_BW + tid] +
                     sm[OFF_SCAL + S_RM1] * sm[OFF_FW + tid] +
                     sm[OFF_SCAL + S_RM2] * cwv + 1e-8f;
          sm[OFF_CW + tid] = wv;
        }
        __syncthreads();
        if (tid < 64) {
          float s = sm[OFF_CW + tid] + sm[OFF_CW + tid + 64];
          for (int off = 32; off > 0; off >>= 1) s += __shfl_down(s, off, 64);
          if (tid == 0) sm[OFF_SCAL + S_WSUM] = s;
        }
        __syncthreads();
        if (tid < 128) sm[OFF_RW + tid] = sm[OFF_CW + tid] / sm[OFF_SCAL + S_WSUM];
        __syncthreads();
        if (tid < 64) {  // rvec = wts @ mem -> global (needed by P1 of t+1)
          float s = 0.f;
          for (int n = 0; n < 128; ++n) s += sm[OFF_RW + n] * sm[OFF_MEM + n * 65 + tid];
          cstore(g_rvecg + b * Wd + tid, s);
        }
      }
      gsync(target);
    }
  }
}

extern "C" void kernel_launch(void* const* d_in, const int* in_sizes, int n_in,
                              void* d_out, int out_size, void* d_ws, size_t ws_size,
                              hipStream_t stream) {
  (void)in_sizes; (void)n_in; (void)d_ws; (void)ws_size; (void)out_size;
  const float* x    = (const float*)d_in[0];
  const float* W_ih = (const float*)d_in[1];
  const float* W_hh = (const float*)d_in[2];
  const float* b_ih = (const float*)d_in[3];
  const float* b_hh = (const float*)d_in[4];
  const float* W_if = (const float*)d_in[5];
  const float* b_if = (const float*)d_in[6];
  const float* W_out = (const float*)d_in[7];
  const float* b_out = (const float*)d_in[8];
  float* out = (float*)d_out;

  dnc_init<<<1280, NT, 0, stream>>>(W_ih, W_hh, b_ih, b_hh);

  hipFuncSetAttribute((const void*)dnc_main,
                      hipFuncAttributeMaxDynamicSharedMemorySize, SMEM_BYTES);

  void* args[] = {(void*)&x, (void*)&W_if, (void*)&b_if,
                  (void*)&W_out, (void*)&b_out, (void*)&out};
  hipLaunchCooperativeKernel((void*)dnc_main, dim3(NWG), dim3(NT), args,
                             SMEM_BYTES, stream);
}

// Round 3
// 3674.050 us; speedup vs baseline: 1.6579x; 1.5439x over previous
//
#include <hip/hip_runtime.h>
#include <math.h>

// DNC: B=32,T=64,I=64,O=64,H=512,N=128,W=64,IF=198
#define Bb 32
#define Tt 64
#define Ii 64
#define Oo 64
#define Hh 512
#define Nn 128
#define Wd 64
#define IFs 198
#define KV 640      /* I + W + H  (gates input vector) */
#define G4 2048     /* 4H */

#define NWG 128
#define NT 512

// ---- LDS layout (float offsets). Per-batch state (wgs 0..31) is disjoint
// from the regions P1 (all wgs) touches, so state survives across phases.
#define OFF_LINK   0        /* 128*129 padded */
#define OFF_MEM    16512    /* 128*65 padded */
#define OFF_V      24832    /* 640*8, layout [c*8 + b_local] */
#define OFF_C      29952    /* 512 */
#define OFF_H      30464    /* 512 */
#define OFF_PACC   30976    /* 512*4 gate partials */
#define OFF_ITF    33024    /* 224 */
#define OFF_ERASE  33248
#define OFF_WVEC   33312
#define OFF_USAGE  33376
#define OFF_PREC   33504
#define OFF_RW     33632
#define OFF_WW     33760
#define OFF_DOT    33888
#define OFF_MN     34016
#define OFF_BW     34144
#define OFF_FW     34272
#define OFF_CW     34400
#define OFF_SS     34528
#define OFF_SCAN   34656    /* 256 ping-pong */
#define OFF_RANK   34912    /* 128 ints */
#define OFF_SCAL   35040    /* 16 scalars */
#define OFF_HRV    35056    /* 8*584: [bl][h(512)|rvec(64)] pad to 584 */
#define SMEM_FLOATS 39728   /* 158912 B <= 160 KiB */
#define SMEM_BYTES (SMEM_FLOATS * 4)

#define S_KN 0
#define S_WGAG 1
#define S_RSTR 2
#define S_RM0 3
#define S_RM1 4
#define S_RM2 5
#define S_WWSUM 6
#define S_CMX 7
#define S_CSUM 8
#define S_WSUM 9

__device__ __align__(16) float g_WT[KV * G4];   // WT[c][j] = [W_ih | W_hh] transposed
__device__ __align__(16) float g_bsum[G4];      // b_ih + b_hh
__device__ __align__(16) float g_hg[Bb * Hh];
__device__ __align__(16) float g_rvecg[Bb * Wd];
__device__ __align__(16) float g_gates[Bb * G4];
__device__ unsigned g_cnt;

__device__ __forceinline__ float sigf(float v) { return 1.f / (1.f + expf(-v)); }

// Coherent word accesses for cross-wg data (no cache-maintenance side effects).
__device__ __forceinline__ void cstore(float* p, float v) {
  __hip_atomic_store(p, v, __ATOMIC_RELAXED, __HIP_MEMORY_SCOPE_AGENT);
}
__device__ __forceinline__ float cload(const float* p) {
  return __hip_atomic_load(p, __ATOMIC_RELAXED, __HIP_MEMORY_SCOPE_AGENT);
}

// Grid barrier: counter at coherent point, workgroup-scope fences only.
__device__ __forceinline__ void gsync(unsigned& target) {
  __builtin_amdgcn_fence(__ATOMIC_RELEASE, "workgroup");
  __syncthreads();
  if (threadIdx.x == 0) {
    __hip_atomic_fetch_add(&g_cnt, 1u, __ATOMIC_RELAXED, __HIP_MEMORY_SCOPE_AGENT);
    target += NWG;
    while (__hip_atomic_load(&g_cnt, __ATOMIC_RELAXED, __HIP_MEMORY_SCOPE_AGENT) < target) {
      __builtin_amdgcn_s_sleep(2);
    }
  }
  __builtin_amdgcn_fence(__ATOMIC_ACQUIRE, "workgroup");
  __syncthreads();
}

__global__ __launch_bounds__(NT) void dnc_init(const float* __restrict__ W_ih,
                                               const float* __restrict__ W_hh,
                                               const float* __restrict__ b_ih,
                                               const float* __restrict__ b_hh) {
  int i0 = blockIdx.x * blockDim.x + threadIdx.x;
  int st = gridDim.x * blockDim.x;
  for (int idx = i0; idx < KV * G4; idx += st) {
    int c = idx >> 11, j = idx & (G4 - 1);
    g_WT[idx] = (c < 128) ? W_ih[j * 128 + c] : W_hh[j * 512 + (c - 128)];
  }
  for (int idx = i0; idx < G4; idx += st) g_bsum[idx] = b_ih[idx] + b_hh[idx];
  for (int idx = i0; idx < Bb * Hh; idx += st) g_hg[idx] = 0.f;
  for (int idx = i0; idx < Bb * Wd; idx += st) g_rvecg[idx] = 0.f;
  if (i0 == 0) g_cnt = 0u;
}

__global__ __launch_bounds__(NT) void dnc_main(const float* __restrict__ x,
                                               const float* __restrict__ W_if,
                                               const float* __restrict__ b_if,
                                               const float* __restrict__ W_out,
                                               const float* __restrict__ b_out,
                                               float* __restrict__ out) {
  extern __shared__ float sm[];
  const int tid = threadIdx.x;
  const int wg = blockIdx.x;
  // XCD-aligned mapping: wg→XCD ~ wg%8, so same-jb wgs {jb, jb+32, jb+64,
  // jb+96} share one XCD's L2 -> per-XCD weight slice (640KB) stays resident.
  const int jb = wg & 31;   // j-tile of 64 gate rows / 2 out rows
  const int bb = wg >> 5;   // batch tile of 8
  const int b0 = bb * 8;
  unsigned target = 0;

  if (wg < Bb) {
    for (int i = tid; i < 128 * 129; i += NT) sm[OFF_LINK + i] = 0.f;
    for (int i = tid; i < 128 * 65; i += NT) sm[OFF_MEM + i] = 0.f;
    if (tid < 128) { sm[OFF_USAGE + tid] = 0.f; sm[OFF_PREC + tid] = 0.f; sm[OFF_RW + tid] = 0.f; }
    sm[OFF_C + tid] = 0.f;
  }
  __syncthreads();

  for (int t = 0; t <= Tt; ++t) {
    // ===== P1 (all wgs): stage v = [x_t | rvec | h] (and hrv = [h|rvec])
    for (int idx = tid; idx < KV * 8; idx += NT) {
      int c = idx >> 3, bl = idx & 7, b = b0 + bl;
      float val = 0.f;
      if (c < 64) {
        if (t < Tt) val = x[(b * Tt + t) * Ii + c];
      } else if (c < 128) {
        val = cload(g_rvecg + b * Wd + (c - 64));
        sm[OFF_HRV + bl * 584 + 512 + (c - 64)] = val;
      } else {
        val = cload(g_hg + b * Hh + (c - 128));
        sm[OFF_HRV + bl * 584 + (c - 128)] = val;
      }
      sm[OFF_V + idx] = val;
    }
    __syncthreads();

    // gates partials: thread owns 4 consecutive j for one batch over a K-quarter
    if (t < Tt) {
      const int jl = tid & 15, bl = (tid >> 4) & 7, ks = tid >> 7;
      const int j0 = jb * 64 + jl * 4;
      const float4* __restrict__ wp =
          ((const float4*)g_WT) + (size_t)(ks * 160) * (G4 / 4) + (j0 >> 2);
      const float* __restrict__ vp = sm + OFF_V + (ks * 160) * 8 + bl;
      float ax = 0.f, ay = 0.f, az = 0.f, aw = 0.f;
#pragma unroll 8
      for (int c = 0; c < 160; ++c) {
        float4 w4 = wp[c * (G4 / 4)];
        float vv = vp[c * 8];
        ax += w4.x * vv; ay += w4.y * vv; az += w4.z * vv; aw += w4.w * vv;
      }
      float4 a; a.x = ax; a.y = ay; a.z = az; a.w = aw;
      ((float4*)(sm + OFF_PACC))[tid] = a;
    }
    // out_{t-1}: coalesced W_out (cc = q*32+cs), conflict-free hrv reads,
    // 32-lane shuffle reduce.
    if (t > 0) {
      const int cs = tid & 31, bl = (tid >> 5) & 7;
      const int o = jb * 2 + (tid >> 8);
      const float* hb = sm + OFF_HRV + bl * 584;
      float p = 0.f;
#pragma unroll
      for (int q = 0; q < 18; ++q) {
        int cc = q * 32 + cs;
        p += hb[cc] * W_out[o * 576 + cc];
      }
      for (int off = 16; off > 0; off >>= 1) p += __shfl_down(p, off, 32);
      if (cs == 0) {
        const int b = b0 + bl;
        out[(b * Tt + (t - 1)) * Oo + o] = p + b_out[o];
      }
    }
    __syncthreads();
    if (t < Tt && tid < 128) {  // K-reduce + bias, write gates (coherent words)
      const int jl = tid & 15, bl = tid >> 4;
      const int j0 = jb * 64 + jl * 4;
      const float4* pa = (const float4*)(sm + OFF_PACC);
      float4 a0 = pa[tid], a1 = pa[tid + 128], a2 = pa[tid + 256], a3 = pa[tid + 384];
      float4 bs = ((const float4*)g_bsum)[j0 >> 2];
      float* gp = g_gates + (b0 + bl) * G4 + j0;
      cstore(gp + 0, a0.x + a1.x + a2.x + a3.x + bs.x);
      cstore(gp + 1, a0.y + a1.y + a2.y + a3.y + bs.y);
      cstore(gp + 2, a0.z + a1.z + a2.z + a3.z + bs.z);
      cstore(gp + 3, a0.w + a1.w + a2.w + a3.w + bs.w);
    }
    gsync(target);

    // ===== P2 (wgs 0..31): per-batch LSTM cell + DNC memory
    if (t < Tt) {
      if (wg < Bb) {
        const int b = wg;
        {  // LSTM elementwise
          const int k = tid;
          float ig = cload(g_gates + b * G4 + k);
          float fg = cload(g_gates + b * G4 + 512 + k);
          float gg = cload(g_gates + b * G4 + 1024 + k);
          float og = cload(g_gates + b * G4 + 1536 + k);
          float co = sm[OFF_C + k];
          float cn = sigf(fg) * co + sigf(ig) * tanhf(gg);
          float hn = sigf(og) * tanhf(cn);
          sm[OFF_C + k] = cn;
          sm[OFF_H + k] = hn;
          cstore(g_hg + b * Hh + k, hn);
        }
        __syncthreads();
        // itf = h @ W_if.T + b_if
        if (tid < IFs) {
          const float4* wr = (const float4*)(W_if + tid * Hh);
          const float4* h4 = (const float4*)(sm + OFF_H);
          float acc = b_if[tid];
#pragma unroll 16
          for (int c4 = 0; c4 < Hh / 4; ++c4) {
            float4 w = wr[c4]; float4 h = h4[c4];
            acc += w.x * h.x + w.y * h.y + w.z * h.z + w.w * h.w;
          }
          sm[OFF_ITF + tid] = acc;
        }
        __syncthreads();
        // small derived values + stable ranks (matches jnp stable argsort)
        if (tid < 64) {
          float rk = sm[OFF_ITF + tid];
          sm[OFF_ERASE + tid] = sigf(rk);
          sm[OFF_WVEC + tid] = sm[OFF_ITF + 64 + tid];
          float sq = rk * rk;
          for (int off = 32; off > 0; off >>= 1) sq += __shfl_down(sq, off, 64);
          if (tid == 0) sm[OFF_SCAL + S_KN] = sqrtf(sq) + 1e-8f;
        } else if (tid == 64) {
          sm[OFF_SCAL + S_WGAG] = sigf(sm[OFF_ITF + 128]) * sigf(sm[OFF_ITF + 129]);
          float rs = sm[OFF_ITF + 194];
          sm[OFF_SCAL + S_RSTR] = (rs > 20.f) ? rs : log1pf(expf(rs));
          float m0 = sm[OFF_ITF + 195], m1 = sm[OFF_ITF + 196], m2 = sm[OFF_ITF + 197];
          float mx = fmaxf(m0, fmaxf(m1, m2));
          float e0 = expf(m0 - mx), e1 = expf(m1 - mx), e2 = expf(m2 - mx);
          float es = e0 + e1 + e2;
          sm[OFF_SCAL + S_RM0] = e0 / es;
          sm[OFF_SCAL + S_RM1] = e1 / es;
          sm[OFF_SCAL + S_RM2] = e2 / es;
        }
        if (tid < 128) {
          float ui = sm[OFF_USAGE + tid];
          int r = 0;
          for (int j2 = 0; j2 < 128; ++j2) {
            float uj = sm[OFF_USAGE + j2];
            r += (uj < ui || (uj == ui && j2 < tid)) ? 1 : 0;
          }
          ((int*)(sm + OFF_RANK))[tid] = r;
          sm[OFF_SS + r] = ui;
        }
        __syncthreads();
        // inclusive prefix-product of sorted usage (Hillis-Steele)
        if (tid < 128) sm[OFF_SCAN + tid] = sm[OFF_SS + tid];
        int cur = 0;
        for (int off = 1; off < 128; off <<= 1) {
          __syncthreads();
          if (tid < 128) {
            float v = sm[OFF_SCAN + cur * 128 + tid];
            if (tid >= off) v *= sm[OFF_SCAN + cur * 128 + tid - off];
            sm[OFF_SCAN + (1 - cur) * 128 + tid] = v;
          }
          cur ^= 1;
        }
        __syncthreads();
        if (tid < 128) {  // alloc -> ww
          int r = ((int*)(sm + OFF_RANK))[tid];
          float excl = (r > 0) ? sm[OFF_SCAN + cur * 128 + r - 1] : 1.f;
          float ui = sm[OFF_USAGE + tid];
          sm[OFF_WW + tid] = sm[OFF_SCAL + S_WGAG] * (1.f - ui) * excl;
        }
        __syncthreads();
        if (tid < 64) {  // ww sum
          float s = sm[OFF_WW + tid] + sm[OFF_WW + tid + 64];
          for (int off = 32; off > 0; off >>= 1) s += __shfl_down(s, off, 64);
          if (tid == 0) sm[OFF_SCAL + S_WWSUM] = s;
        }
        // mem update
        for (int idx = tid; idx < Nn * Wd; idx += NT) {
          int n = idx >> 6, w = idx & 63;
          float wwn = sm[OFF_WW + n];
          float m = sm[OFF_MEM + n * 65 + w];
          sm[OFF_MEM + n * 65 + w] =
              m * (1.f - wwn * sm[OFF_ERASE + w]) + wwn * sm[OFF_WVEC + w];
        }
        // link update (reads OLD prec)
        for (int idx = tid; idx < Nn * Nn; idx += NT) {
          int i2 = idx >> 7, j2 = idx & 127;
          float wwi = sm[OFF_WW + i2], wwj = sm[OFF_WW + j2];
          float L = sm[OFF_LINK + i2 * 129 + j2];
          L = (1.f - wwi - wwj) * L + sm[OFF_PREC + i2] * wwj;
          sm[OFF_LINK + i2 * 129 + j2] = (i2 == j2) ? 0.f : L;
        }
        if (tid < 128) {  // usage update
          float u = sm[OFF_USAGE + tid];
          sm[OFF_USAGE + tid] = u + (1.f - u) * sm[OFF_WW + tid];
        }
        __syncthreads();
        // prec update + content dot/norms + bw/fw (uses NEW link, OLD rw)
        if (tid < 128) {
          sm[OFF_PREC + tid] =
              (1.f - sm[OFF_SCAL + S_WWSUM]) * sm[OFF_PREC + tid] + sm[OFF_WW + tid];
          float d = 0.f;
          for (int w = 0; w < 64; ++w) d += sm[OFF_ITF + w] * sm[OFF_MEM + tid * 65 + w];
          sm[OFF_DOT + tid] = d;
        } else if (tid < 256) {
          int n = tid - 128; float s2 = 0.f;
          for (int w = 0; w < 64; ++w) { float m = sm[OFF_MEM + n * 65 + w]; s2 += m * m; }
          sm[OFF_MN + n] = sqrtf(s2) + 1e-8f;
        } else if (tid < 384) {
          int m2 = tid - 256; float s = 0.f;
          for (int n = 0; n < 128; ++n) s += sm[OFF_LINK + n * 129 + m2] * sm[OFF_RW + n];
          sm[OFF_BW + m2] = s;
        } else {
          int n = tid - 384; float s = 0.f;
          for (int m2 = 0; m2 < 128; ++m2) s += sm[OFF_LINK + n * 129 + m2] * sm[OFF_RW + m2];
          sm[OFF_FW + n] = s;
        }
        __syncthreads();
        // cosine softmax
        if (tid < 128) {
          float q = sm[OFF_DOT + tid] / (sm[OFF_SCAL + S_KN] * sm[OFF_MN + tid]) *
                    sm[OFF_SCAL + S_RSTR];
          sm[OFF_CW + tid] = q;
        }
        __syncthreads();
        if (tid < 64) {
          float mx = fmaxf(sm[OFF_CW + tid], sm[OFF_CW + tid + 64]);
          for (int off = 32; off > 0; off >>= 1) mx = fmaxf(mx, __shfl_down(mx, off, 64));
          if (tid == 0) sm[OFF_SCAL + S_CMX] = mx;
        }
        __syncthreads();
        if (tid < 128) sm[OFF_CW + tid] = expf(sm[OFF_CW + tid] - sm[OFF_SCAL + S_CMX]);
        __syncthreads();
        if (tid < 64) {
          float s = sm[OFF_CW + tid] + sm[OFF_CW + tid + 64];
          for (int off = 32; off > 0; off >>= 1) s += __shfl_down(s, off, 64);
          if (tid == 0) sm[OFF_SCAL + S_CSUM] = s;
        }
        __syncthreads();
        if (tid < 128) {  // combined weights
          float cwv = sm[OFF_CW + tid] / sm[OFF_SCAL + S_CSUM];
          float wv = sm[OFF_SCAL + S_RM0] * sm[OFF_BW + tid] +
                     sm[OFF_SCAL + S_RM1] * sm[OFF_FW + tid] +
                     sm[OFF_SCAL + S_RM2] * cwv + 1e-8f;
          sm[OFF_CW + tid] = wv;
        }
        __syncthreads();
        if (tid < 64) {
          float s = sm[OFF_CW + tid] + sm[OFF_CW + tid + 64];
          for (int off = 32; off > 0; off >>= 1) s += __shfl_down(s, off, 64);
          if (tid == 0) sm[OFF_SCAL + S_WSUM] = s;
        }
        __syncthreads();
        if (tid < 128) sm[OFF_RW + tid] = sm[OFF_CW + tid] / sm[OFF_SCAL + S_WSUM];
        __syncthreads();
        if (tid < 64) {  // rvec = wts @ mem -> global (needed by P1 of t+1)
          float s = 0.f;
          for (int n = 0; n < 128; ++n) s += sm[OFF_RW + n] * sm[OFF_MEM + n * 65 + tid];
          cstore(g_rvecg + b * Wd + tid, s);
        }
      }
      gsync(target);
    }
  }
}

extern "C" void kernel_launch(void* const* d_in, const int* in_sizes, int n_in,
                              void* d_out, int out_size, void* d_ws, size_t ws_size,
                              hipStream_t stream) {
  (void)in_sizes; (void)n_in; (void)d_ws; (void)ws_size; (void)out_size;
  const float* x    = (const float*)d_in[0];
  const float* W_ih = (const float*)d_in[1];
  const float* W_hh = (const float*)d_in[2];
  const float* b_ih = (const float*)d_in[3];
  const float* b_hh = (const float*)d_in[4];
  const float* W_if = (const float*)d_in[5];
  const float* b_if = (const float*)d_in[6];
  const float* W_out = (const float*)d_in[7];
  const float* b_out = (const float*)d_in[8];
  float* out = (float*)d_out;

  dnc_init<<<1280, NT, 0, stream>>>(W_ih, W_hh, b_ih, b_hh);

  hipFuncSetAttribute((const void*)dnc_main,
                      hipFuncAttributeMaxDynamicSharedMemorySize, SMEM_BYTES);

  void* args[] = {(void*)&x, (void*)&W_if, (void*)&b_if,
                  (void*)&W_out, (void*)&b_out, (void*)&out};
  hipLaunchCooperativeKernel((void*)dnc_main, dim3(NWG), dim3(NT), args,
                             SMEM_BYTES, stream);
}

// Round 5
// 2736.848 us; speedup vs baseline: 2.2257x; 1.3424x over previous
//
#include <hip/hip_runtime.h>
#include <math.h>

// DNC: B=32,T=64,I=64,O=64,H=512,N=128,W=64,IF=198
#define Bb 32
#define Tt 64
#define Ii 64
#define Oo 64
#define Hh 512
#define Nn 128
#define Wd 64
#define IFs 198
#define KV 640
#define G4 2048

#define NWG 128
#define NT 512
#define VST 648   /* padded V row stride: 648%32=8 -> bl rows hit different banks */

// ---- LDS layout (float offsets)
#define OFF_LINK   0                      /* 128*129 */
#define OFF_MEM    16512                  /* 128*65 */
#define OFF_V      24832                  /* 8*648 = 5184 */
#define OFF_C      30016                  /* 512 */
#define OFF_H      30528                  /* 576 [h|rvec] */
#define OFF_PACC   31104                  /* 4096, doubles as P2 scratch (SCR) */
#define OFF_ITF    35200                  /* 224 */
#define OFF_ERASE  35424
#define OFF_WVEC   35488
#define OFF_USAGE  35552
#define OFF_PREC   35680
#define OFF_RW     35808
#define OFF_WW     35936
#define OFF_DOT    36064
#define OFF_MN     36192
#define OFF_BW     36320
#define OFF_FW     36448
#define OFF_SCAN   36576
#define OFF_RANK   36704                  /* ints */
#define OFF_SS     36832
#define OFF_SCAL   36960                  /* 16 */
#define SMEM_FLOATS 36976                 /* 147904 B <= 160 KiB */
#define SMEM_BYTES (SMEM_FLOATS * 4)

#define S_KN 0
#define S_WGAG 1
#define S_RSTR 2
#define S_RM0 3
#define S_RM1 4
#define S_RM2 5
#define S_WWSUM 6

__device__ __align__(16) float g_WT[KV * G4];   // WT[c][j]
__device__ __align__(16) float g_bsum[G4];
__device__ __align__(16) float g_hg[Bb * Hh];
__device__ __align__(16) float g_rvecg[Bb * Wd];
__device__ __align__(16) float g_gates[Bb * G4];
__device__ unsigned g_hflag[Bb];    // batch b h/rvec(t) published <=> == t+1
__device__ unsigned g_gdone[NWG];   // P1 wg gates(t) published <=> == t+1

__device__ __forceinline__ float sigf(float v) { return 1.f / (1.f + expf(-v)); }

typedef unsigned long long u64;
union F2U { u64 u; float f[2]; };

// Bypassing (coherent-point) data accesses, relaxed.
__device__ __forceinline__ void cstore2(float* p, float a, float b) {
  F2U v; v.f[0] = a; v.f[1] = b;
  __hip_atomic_store((u64*)p, v.u, __ATOMIC_RELAXED, __HIP_MEMORY_SCOPE_AGENT);
}
__device__ __forceinline__ void cstore(float* p, float v) {
  __hip_atomic_store(p, v, __ATOMIC_RELAXED, __HIP_MEMORY_SCOPE_AGENT);
}
__device__ __forceinline__ F2U cload2(const float* p) {
  F2U v; v.u = __hip_atomic_load((const u64*)p, __ATOMIC_RELAXED, __HIP_MEMORY_SCOPE_AGENT);
  return v;
}
// Flag publish: RELEASE at agent scope -> buffer_wbl2 (writeback, no eviction of
// clean weight lines) + s_waitcnt before the store. Orders all prior stores
// (cached-dirty AND in-flight bypassing) ahead of the flag at the coherent point.
__device__ __forceinline__ void publish(unsigned* p, unsigned v) {
  __hip_atomic_store(p, v, __ATOMIC_RELEASE, __HIP_MEMORY_SCOPE_AGENT);
}
__device__ __forceinline__ unsigned cloadu(const unsigned* p) {
  return __hip_atomic_load(p, __ATOMIC_RELAXED, __HIP_MEMORY_SCOPE_AGENT);
}

#define TIN 512
__global__ __launch_bounds__(TIN) void dnc_init(const float* __restrict__ W_ih,
                                                const float* __restrict__ W_hh,
                                                const float* __restrict__ b_ih,
                                                const float* __restrict__ b_hh) {
  __shared__ float tile[64][65];
  const int tid = threadIdx.x;
  int i0 = blockIdx.x * blockDim.x + tid;
  int st = gridDim.x * blockDim.x;
  for (int idx = i0; idx < G4; idx += st) g_bsum[idx] = b_ih[idx] + b_hh[idx];
  for (int idx = i0; idx < Bb * Hh; idx += st) g_hg[idx] = 0.f;
  for (int idx = i0; idx < Bb * Wd; idx += st) g_rvecg[idx] = 0.f;
  if (i0 < Bb) g_hflag[i0] = 0u;
  if (i0 < NWG) g_gdone[i0] = 0u;

  for (int tileId = blockIdx.x; tileId < 320; tileId += gridDim.x) {
    int tc = tileId >> 5, tj = tileId & 31;
    for (int k = tid; k < 64 * 64; k += TIN) {
      int r = k >> 6, cl = k & 63;
      int j = tj * 64 + r, c = tc * 64 + cl;
      tile[r][cl] = (c < 128) ? W_ih[j * 128 + c] : W_hh[j * 512 + (c - 128)];
    }
    __syncthreads();
    for (int k = tid; k < 64 * 64; k += TIN) {
      int cl = k >> 6, r = k & 63;
      g_WT[(size_t)(tc * 64 + cl) * G4 + tj * 64 + r] = tile[r][cl];
    }
    __syncthreads();
  }
}

__global__ __launch_bounds__(NT) void dnc_main(const float* __restrict__ x,
                                               const float* __restrict__ W_if,
                                               const float* __restrict__ b_if,
                                               const float* __restrict__ W_out,
                                               const float* __restrict__ b_out,
                                               float* __restrict__ out) {
  extern __shared__ float sm[];
  float* SCR = sm + OFF_PACC;       // P2 scratch aliases P1's PACC (disjoint in time)
  const int tid = threadIdx.x;
  const int lane = tid & 63;
  const int wg = blockIdx.x;
  // XCD-aligned: same-jb wgs {jb, jb+32, jb+64, jb+96} share one XCD's L2.
  const int jb = wg & 31;
  const int bb = wg >> 5;
  const int b0 = bb * 8;

  if (wg < Bb) {
    for (int i = tid; i < 128 * 129; i += NT) sm[OFF_LINK + i] = 0.f;
    for (int i = tid; i < 128 * 65; i += NT) sm[OFF_MEM + i] = 0.f;
    if (tid < 128) { sm[OFF_USAGE + tid] = 0.f; sm[OFF_PREC + tid] = 0.f; sm[OFF_RW + tid] = 0.f; }
    sm[OFF_C + tid] = 0.f;
  }
  __syncthreads();

  for (int t = 0; t < Tt; ++t) {
    // ===== P1: wait for h/rvec(t-1) of my 8 batches
    if (tid < 8) {
      while (cloadu(&g_hflag[b0 + tid]) < (unsigned)t) __builtin_amdgcn_s_sleep(4);
    }
    __syncthreads();

    {  // stage V[bl][c] = [x_t | rvec | h], u64 coherent pairs, coalesced
      const int bl = tid >> 6, b = b0 + bl;
      float v0[5], v1[5];
#pragma unroll
      for (int k = 0; k < 5; ++k) {
        int cp = lane + k * 64;          // pair index < 320
        int c = cp * 2;
        if (c < 64) {
          const float2 xv = *(const float2*)(x + ((size_t)b * Tt + t) * Ii + c);
          v0[k] = xv.x; v1[k] = xv.y;
        } else if (c < 128) {
          F2U v = cload2(g_rvecg + b * Wd + (c - 64));
          v0[k] = v.f[0]; v1[k] = v.f[1];
        } else {
          F2U v = cload2(g_hg + b * Hh + (c - 128));
          v0[k] = v.f[0]; v1[k] = v.f[1];
        }
      }
#pragma unroll
      for (int k = 0; k < 5; ++k) {
        int c = (lane + k * 64) * 2;
        sm[OFF_V + bl * VST + c] = v0[k];
        sm[OFF_V + bl * VST + c + 1] = v1[k];
      }
    }
    __syncthreads();

    {  // gates partials: thread = (jl16, blh4, ks8): 4j x 2 batches x 80 c
      const int jl = tid & 15, blh = (tid >> 4) & 3, ks = tid >> 6;
      const int j0 = jb * 64 + jl * 4;
      const float4* __restrict__ wp =
          ((const float4*)g_WT) + (size_t)(ks * 80) * (G4 / 4) + (j0 >> 2);
      const float* __restrict__ va = sm + OFF_V + blh * VST + ks * 80;
      const float* __restrict__ vb = va + 4 * VST;
      float4 a1 = {0.f, 0.f, 0.f, 0.f}, a2 = {0.f, 0.f, 0.f, 0.f};
#pragma unroll 8
      for (int c = 0; c < 80; ++c) {
        float4 w4 = wp[(size_t)c * (G4 / 4)];
        float fa = va[c], fb = vb[c];
        a1.x += w4.x * fa; a1.y += w4.y * fa; a1.z += w4.z * fa; a1.w += w4.w * fa;
        a2.x += w4.x * fb; a2.y += w4.y * fb; a2.z += w4.z * fb; a2.w += w4.w * fb;
      }
      float4* pa = (float4*)(sm + OFF_PACC);
      pa[(ks * 8 + blh) * 16 + jl] = a1;
      pa[(ks * 8 + blh + 4) * 16 + jl] = a2;
    }
    __syncthreads();
    if (tid < 128) {  // K-reduce (8-way) + bias -> coherent u64 gate stores
      const int bl = tid >> 4, jl = tid & 15;
      const int j0 = jb * 64 + jl * 4;
      const float4* pa = (const float4*)(sm + OFF_PACC);
      float4 g = {0.f, 0.f, 0.f, 0.f};
#pragma unroll
      for (int ks = 0; ks < 8; ++ks) {
        float4 a = pa[(ks * 8 + bl) * 16 + jl];
        g.x += a.x; g.y += a.y; g.z += a.z; g.w += a.w;
      }
      float4 bs = ((const float4*)g_bsum)[j0 >> 2];
      float* gp = g_gates + (size_t)(b0 + bl) * G4 + j0;
      cstore2(gp, g.x + bs.x, g.y + bs.y);
      cstore2(gp + 2, g.z + bs.z, g.w + bs.w);
    }
    __syncthreads();
    if (tid == 0) publish(&g_gdone[wg], (unsigned)(t + 1));  // RELEASE

    // ===== P2 (wgs 0..31): per-batch LSTM + DNC memory + out projection
    if (wg < Bb) {
      const int b = wg;
      if (tid < 32) {
        while (cloadu(&g_gdone[(b >> 3) * 32 + tid]) < (unsigned)(t + 1))
          __builtin_amdgcn_s_sleep(4);
      }
      __syncthreads();
      if (tid < 256) {  // LSTM, 2 elems/thread, u64 coherent loads
        const int k0 = tid * 2;
        const float* gp = g_gates + (size_t)b * G4 + k0;
        F2U ig = cload2(gp), fg = cload2(gp + 512),
            gg = cload2(gp + 1024), og = cload2(gp + 1536);
        float hs[2];
#pragma unroll
        for (int e = 0; e < 2; ++e) {
          float co = sm[OFF_C + k0 + e];
          float cn = sigf(fg.f[e]) * co + sigf(ig.f[e]) * tanhf(gg.f[e]);
          float hn = sigf(og.f[e]) * tanhf(cn);
          sm[OFF_C + k0 + e] = cn;
          sm[OFF_H + k0 + e] = hn;
          hs[e] = hn;
        }
        cstore2(g_hg + b * Hh + k0, hs[0], hs[1]);
      }
      __syncthreads();
      if (tid < 2 * IFs) {  // itf partials: (o, half of K)
        const int o = tid >> 1, half = tid & 1;
        const float4* wr = (const float4*)(W_if + (size_t)o * Hh) + half * 64;
        const float4* h4 = (const float4*)(sm + OFF_H) + half * 64;
        float acc = 0.f;
#pragma unroll 8
        for (int c4 = 0; c4 < 64; ++c4) {
          float4 w = wr[c4]; float4 h = h4[c4];
          acc += w.x * h.x + w.y * h.y + w.z * h.z + w.w * h.w;
        }
        SCR[tid] = acc;
      }
      __syncthreads();
      if (tid < IFs) sm[OFF_ITF + tid] = SCR[2 * tid] + SCR[2 * tid + 1] + b_if[tid];
      __syncthreads();
      // derived scalars + erase/wvec/kn + rank partials (all independent)
      {
        const int i = tid >> 2, seg = tid & 3;
        const float ui = sm[OFF_USAGE + i];
        int r = 0;
        for (int j2 = seg * 32; j2 < seg * 32 + 32; ++j2) {
          float uj = sm[OFF_USAGE + j2];
          r += (uj < ui || (uj == ui && j2 < i)) ? 1 : 0;
        }
        ((int*)SCR)[tid] = r;
      }
      if (tid < 64) {
        float rk = sm[OFF_ITF + tid];
        sm[OFF_ERASE + tid] = sigf(rk);
        sm[OFF_WVEC + tid] = sm[OFF_ITF + 64 + tid];
        float sq = rk * rk;
        for (int off = 32; off > 0; off >>= 1) sq += __shfl_down(sq, off, 64);
        if (tid == 0) sm[OFF_SCAL + S_KN] = sqrtf(sq) + 1e-8f;
      } else if (tid == 64) {
        sm[OFF_SCAL + S_WGAG] = sigf(sm[OFF_ITF + 128]) * sigf(sm[OFF_ITF + 129]);
        float rs = sm[OFF_ITF + 194];
        sm[OFF_SCAL + S_RSTR] = (rs > 20.f) ? rs : log1pf(expf(rs));
        float m0 = sm[OFF_ITF + 195], m1 = sm[OFF_ITF + 196], m2 = sm[OFF_ITF + 197];
        float mx = fmaxf(m0, fmaxf(m1, m2));
        float e0 = expf(m0 - mx), e1 = expf(m1 - mx), e2 = expf(m2 - mx);
        float es = e0 + e1 + e2;
        sm[OFF_SCAL + S_RM0] = e0 / es;
        sm[OFF_SCAL + S_RM1] = e1 / es;
        sm[OFF_SCAL + S_RM2] = e2 / es;
      }
      __syncthreads();
      if (tid < 128) {  // rank reduce + scatter sorted usage
        const int* ri = (const int*)SCR;
        int r = ri[tid * 4] + ri[tid * 4 + 1] + ri[tid * 4 + 2] + ri[tid * 4 + 3];
        ((int*)(sm + OFF_RANK))[tid] = r;
        sm[OFF_SS + r] = sm[OFF_USAGE + tid];
      }
      __syncthreads();
      if (tid < 64) {  // prefix-product via single-wave shuffle scan (2 elems/lane)
        float s0 = sm[OFF_SS + 2 * tid], s1 = sm[OFF_SS + 2 * tid + 1];
        float p = s0 * s1;
#pragma unroll
        for (int off = 1; off < 64; off <<= 1) {
          float v = __shfl_up(p, off, 64);
          if (tid >= off) p *= v;
        }
        float excl = __shfl_up(p, 1, 64);
        if (tid == 0) excl = 1.f;
        sm[OFF_SCAN + 2 * tid] = excl * s0;
        sm[OFF_SCAN + 2 * tid + 1] = excl * s0 * s1;
      }
      __syncthreads();
      if (tid < 64) {  // ww + wwsum (single wave, 2 elems/lane)
        float wgag = sm[OFF_SCAL + S_WGAG];
        float wws = 0.f;
#pragma unroll
        for (int e = 0; e < 2; ++e) {
          int i = 2 * tid + e;
          int r = ((const int*)(sm + OFF_RANK))[i];
          float excl = (r > 0) ? sm[OFF_SCAN + r - 1] : 1.f;
          float w = wgag * (1.f - sm[OFF_USAGE + i]) * excl;
          sm[OFF_WW + i] = w;
          wws += w;
        }
        for (int off = 32; off > 0; off >>= 1) wws += __shfl_down(wws, off, 64);
        if (tid == 0) sm[OFF_SCAL + S_WWSUM] = wws;
      }
      __syncthreads();
      for (int idx = tid; idx < Nn * Wd; idx += NT) {  // mem update
        int n = idx >> 6, w = idx & 63;
        float wwn = sm[OFF_WW + n];
        float m = sm[OFF_MEM + n * 65 + w];
        sm[OFF_MEM + n * 65 + w] =
            m * (1.f - wwn * sm[OFF_ERASE + w]) + wwn * sm[OFF_WVEC + w];
      }
      for (int idx = tid; idx < Nn * Nn; idx += NT) {  // link update (old prec)
        int i2 = idx >> 7, j2 = idx & 127;
        float wwi = sm[OFF_WW + i2], wwj = sm[OFF_WW + j2];
        float L = sm[OFF_LINK + i2 * 129 + j2];
        L = (1.f - wwi - wwj) * L + sm[OFF_PREC + i2] * wwj;
        sm[OFF_LINK + i2 * 129 + j2] = (i2 == j2) ? 0.f : L;
      }
      if (tid < 128) {  // usage update (old usage already consumed)
        float u = sm[OFF_USAGE + tid];
        sm[OFF_USAGE + tid] = u + (1.f - u) * sm[OFF_WW + tid];
      }
      __syncthreads();
      // prec update + parallel partials: dot/mn (new mem), bw/fw (new link, old rw)
      if (tid < 128) {
        sm[OFF_PREC + tid] =
            (1.f - sm[OFF_SCAL + S_WWSUM]) * sm[OFF_PREC + tid] + sm[OFF_WW + tid];
      }
      {
        const int n = tid & 127, seg = tid >> 7;
        float d = 0.f, m2 = 0.f;
        for (int w = seg * 16; w < seg * 16 + 16; ++w) {
          float m = sm[OFF_MEM + n * 65 + w];
          d += sm[OFF_ITF + w] * m;
          m2 += m * m;
        }
        SCR[n * 4 + seg] = d;
        SCR[512 + n * 4 + seg] = m2;
        float bwp = 0.f, fwp = 0.f;
        for (int n2 = seg * 32; n2 < seg * 32 + 32; ++n2) {
          bwp += sm[OFF_LINK + n2 * 129 + n] * sm[OFF_RW + n2];
          fwp += sm[OFF_LINK + n * 129 + n2] * sm[OFF_RW + n2];
        }
        SCR[1024 + n * 4 + seg] = bwp;
        SCR[1536 + n * 4 + seg] = fwp;
      }
      __syncthreads();
      {  // reduce 4 partials each: 512 outputs exactly
        const int q = tid >> 7, n = tid & 127;
        const float* s = SCR + q * 512 + n * 4;
        float v = s[0] + s[1] + s[2] + s[3];
        if (q == 0) sm[OFF_DOT + n] = v;
        else if (q == 1) sm[OFF_MN + n] = sqrtf(v) + 1e-8f;
        else if (q == 2) sm[OFF_BW + n] = v;
        else sm[OFF_FW + n] = v;
      }
      __syncthreads();
      if (tid < 64) {  // cosine softmax + combine + normalize (single wave)
        float kn = sm[OFF_SCAL + S_KN], rstr = sm[OFF_SCAL + S_RSTR];
        float rm0 = sm[OFF_SCAL + S_RM0], rm1 = sm[OFF_SCAL + S_RM1],
              rm2 = sm[OFF_SCAL + S_RM2];
        int i0 = 2 * tid, i1 = 2 * tid + 1;
        float q0 = sm[OFF_DOT + i0] / (kn * sm[OFF_MN + i0]) * rstr;
        float q1 = sm[OFF_DOT + i1] / (kn * sm[OFF_MN + i1]) * rstr;
        float mx = fmaxf(q0, q1);
#pragma unroll
        for (int off = 32; off > 0; off >>= 1) mx = fmaxf(mx, __shfl_xor(mx, off, 64));
        float e0 = expf(q0 - mx), e1 = expf(q1 - mx);
        float es = e0 + e1;
#pragma unroll
        for (int off = 32; off > 0; off >>= 1) es += __shfl_xor(es, off, 64);
        float wv0 = rm0 * sm[OFF_BW + i0] + rm1 * sm[OFF_FW + i0] + rm2 * (e0 / es) + 1e-8f;
        float wv1 = rm0 * sm[OFF_BW + i1] + rm1 * sm[OFF_FW + i1] + rm2 * (e1 / es) + 1e-8f;
        float ws = wv0 + wv1;
#pragma unroll
        for (int off = 32; off > 0; off >>= 1) ws += __shfl_xor(ws, off, 64);
        sm[OFF_RW + i0] = wv0 / ws;
        sm[OFF_RW + i1] = wv1 / ws;
      }
      __syncthreads();
      {  // rvec partials: (w, 8 n-segments of 16)
        const int w = tid & 63, seg = tid >> 6;
        float p = 0.f;
        for (int n = seg * 16; n < seg * 16 + 16; ++n)
          p += sm[OFF_RW + n] * sm[OFF_MEM + n * 65 + w];
        SCR[w * 8 + seg] = p;
      }
      __syncthreads();
      if (tid < 64) {  // rvec reduce -> LDS + coherent publish
        const float* s = SCR + tid * 8;
        float r = s[0] + s[1] + s[2] + s[3] + s[4] + s[5] + s[6] + s[7];
        sm[OFF_H + 512 + tid] = r;
        cstore(g_rvecg + b * Wd + tid, r);
      }
      __syncthreads();
      {  // out_t = [h|rvec] @ W_out.T + b_out
        const int o = tid >> 3, seg = tid & 7;
        const float4* wrow = (const float4*)(W_out + (size_t)o * 576) + seg * 18;
        const float4* hb = (const float4*)(sm + OFF_H) + seg * 18;
        float p = 0.f;
#pragma unroll
        for (int q = 0; q < 18; ++q) {
          float4 w = wrow[q]; float4 h = hb[q];
          p += w.x * h.x + w.y * h.y + w.z * h.z + w.w * h.w;
        }
        p += __shfl_down(p, 4, 8);
        p += __shfl_down(p, 2, 8);
        p += __shfl_down(p, 1, 8);
        if (seg == 0) out[((size_t)b * Tt + t) * Oo + o] = p + b_out[o];
      }
      __syncthreads();
      if (tid == 0) publish(&g_hflag[b], (unsigned)(t + 1));  // RELEASE
    }
  }
}

extern "C" void kernel_launch(void* const* d_in, const int* in_sizes, int n_in,
                              void* d_out, int out_size, void* d_ws, size_t ws_size,
                              hipStream_t stream) {
  (void)in_sizes; (void)n_in; (void)d_ws; (void)ws_size; (void)out_size;
  const float* x    = (const float*)d_in[0];
  const float* W_ih = (const float*)d_in[1];
  const float* W_hh = (const float*)d_in[2];
  const float* b_ih = (const float*)d_in[3];
  const float* b_hh = (const float*)d_in[4];
  const float* W_if = (const float*)d_in[5];
  const float* b_if = (const float*)d_in[6];
  const float* W_out = (const float*)d_in[7];
  const float* b_out = (const float*)d_in[8];
  float* out = (float*)d_out;

  dnc_init<<<320, TIN, 0, stream>>>(W_ih, W_hh, b_ih, b_hh);

  hipFuncSetAttribute((const void*)dnc_main,
                      hipFuncAttributeMaxDynamicSharedMemorySize, SMEM_BYTES);

  void* args[] = {(void*)&x, (void*)&W_if, (void*)&b_if,
                  (void*)&W_out, (void*)&b_out, (void*)&out};
  hipLaunchCooperativeKernel((void*)dnc_main, dim3(NWG), dim3(NT), args,
                             SMEM_BYTES, stream);
}

// Round 6
// 2597.948 us; speedup vs baseline: 2.3447x; 1.0535x over previous
//
#include <hip/hip_runtime.h>
#include <math.h>

// DNC: B=32,T=64,I=64,O=64,H=512,N=128,W=64,IF=198
#define Bb 32
#define Tt 64
#define Ii 64
#define Oo 64
#define Hh 512
#define Nn 128
#define Wd 64
#define IFs 198
#define KV 640
#define G4 2048

#define NWG 128
#define NT 512
#define VST 648   /* padded V row stride */

// ---- LDS layout (float offsets)
#define OFF_LINK   0        /* 128*129 */
#define OFF_MEM    16512    /* 128*65  */
#define OFF_V      24832    /* 8*648   */
#define OFF_CC     30016    /* 128 c-state: [bl][16] (P1-persistent, ALL wgs) */
#define OFF_GL     30144    /* 8*68 gates [bl][4*16+pad] */
#define OFF_H      30688    /* 576 [h|rvec] (P2) */
#define OFF_PACC   31264    /* 1088 float4 = 4352 (padded rows x17) ; SCR alias */
#define OFF_ITF    35616    /* 224 */
#define OFF_ERASE  35840
#define OFF_WVEC   35904
#define OFF_USAGE  35968
#define OFF_PREC   36096
#define OFF_RW     36224
#define OFF_WW     36352
#define OFF_DOT    36480
#define OFF_MN     36608
#define OFF_BW     36736
#define OFF_FW     36864
#define OFF_SCAN   36992
#define OFF_RANK   37120
#define OFF_SS     37248
#define OFF_SCAL   37376    /* 16 */
#define SMEM_FLOATS 37392   /* 149568 B <= 160 KiB */
#define SMEM_BYTES (SMEM_FLOATS * 4)

#define S_KN 0
#define S_WGAG 1
#define S_RSTR 2
#define S_RM0 3
#define S_RM1 4
#define S_RM2 5
#define S_WWSUM 6

__device__ __align__(16) float g_WT[KV * G4];     // WT[c][j]
__device__ __align__(16) float g_bsum[G4];
__device__ __align__(16) float g_hg[2 * Bb * Hh]; // step-parity double buffer
__device__ __align__(16) float g_rvecg[Bb * Wd];
__device__ unsigned g_hdone[NWG];   // P1 wg published its h(t) slice <=> == t+1
__device__ unsigned g_rdone[Bb];    // P2 wg published rvec(t) <=> == t+1

__device__ __forceinline__ float sigf(float v) { return 1.f / (1.f + expf(-v)); }

typedef unsigned long long u64;
union F2U { u64 u; float f[2]; };

__device__ __forceinline__ void cstore2(float* p, float a, float b) {
  F2U v; v.f[0] = a; v.f[1] = b;
  __hip_atomic_store((u64*)p, v.u, __ATOMIC_RELAXED, __HIP_MEMORY_SCOPE_AGENT);
}
__device__ __forceinline__ void cstore(float* p, float v) {
  __hip_atomic_store(p, v, __ATOMIC_RELAXED, __HIP_MEMORY_SCOPE_AGENT);
}
__device__ __forceinline__ F2U cload2(const float* p) {
  F2U v; v.u = __hip_atomic_load((const u64*)p, __ATOMIC_RELAXED, __HIP_MEMORY_SCOPE_AGENT);
  return v;
}
// RELEASE publish (after __syncthreads): orders the wg's prior bypassing
// stores (already vmcnt-drained to the coherent point) ahead of the flag.
__device__ __forceinline__ void publish(unsigned* p, unsigned v) {
  __hip_atomic_store(p, v, __ATOMIC_RELEASE, __HIP_MEMORY_SCOPE_AGENT);
}
__device__ __forceinline__ unsigned cloadu(const unsigned* p) {
  return __hip_atomic_load(p, __ATOMIC_RELAXED, __HIP_MEMORY_SCOPE_AGENT);
}

#define TIN 512
__global__ __launch_bounds__(TIN) void dnc_init(const float* __restrict__ W_ih,
                                                const float* __restrict__ W_hh,
                                                const float* __restrict__ b_ih,
                                                const float* __restrict__ b_hh) {
  __shared__ float tile[64][65];
  const int tid = threadIdx.x;
  int i0 = blockIdx.x * blockDim.x + tid;
  int st = gridDim.x * blockDim.x;
  for (int idx = i0; idx < G4; idx += st) g_bsum[idx] = b_ih[idx] + b_hh[idx];
  for (int idx = i0; idx < 2 * Bb * Hh; idx += st) g_hg[idx] = 0.f;
  for (int idx = i0; idx < Bb * Wd; idx += st) g_rvecg[idx] = 0.f;
  if (i0 < NWG) g_hdone[i0] = 0u;
  if (i0 < Bb) g_rdone[i0] = 0u;

  for (int tileId = blockIdx.x; tileId < 320; tileId += gridDim.x) {
    int tc = tileId >> 5, tj = tileId & 31;
    for (int k = tid; k < 64 * 64; k += TIN) {
      int r = k >> 6, cl = k & 63;
      int j = tj * 64 + r, c = tc * 64 + cl;
      tile[r][cl] = (c < 128) ? W_ih[j * 128 + c] : W_hh[j * 512 + (c - 128)];
    }
    __syncthreads();
    for (int k = tid; k < 64 * 64; k += TIN) {
      int cl = k >> 6, r = k & 63;
      g_WT[(size_t)(tc * 64 + cl) * G4 + tj * 64 + r] = tile[r][cl];
    }
    __syncthreads();
  }
}

__global__ __launch_bounds__(NT) void dnc_main(const float* __restrict__ x,
                                               const float* __restrict__ W_if,
                                               const float* __restrict__ b_if,
                                               const float* __restrict__ W_out,
                                               const float* __restrict__ b_out,
                                               float* __restrict__ out) {
  extern __shared__ float sm[];
  float* SCR = sm + OFF_PACC;   // P2 scratch aliases PACC (disjoint in time)
  const int tid = threadIdx.x;
  const int wg = blockIdx.x;
  // wg = bb*32 + jb -> wg%8 == jb%8: the 4 sharers of weight slice jb sit on
  // one XCD (wg, wg±32, ...), keeping the 160KB slice L2-resident.
  const int jb = wg & 31;
  const int bb = wg >> 5;
  const int b0 = bb * 8;

  // per-wg persistent LSTM c-state (ALL wgs own 16 h-units x 8 batches now)
  if (tid < 128) sm[OFF_CC + tid] = 0.f;
  if (wg < Bb) {
    for (int i = tid; i < 128 * 129; i += NT) sm[OFF_LINK + i] = 0.f;
    for (int i = tid; i < 128 * 65; i += NT) sm[OFF_MEM + i] = 0.f;
    if (tid < 128) { sm[OFF_USAGE + tid] = 0.f; sm[OFF_PREC + tid] = 0.f; sm[OFF_RW + tid] = 0.f; }
  }
  __syncthreads();

  for (int t = 0; t < Tt; ++t) {
    // ===== P1-A: wait for all h(t-1) slices of my batch group
    if (tid < 32) {
      while (cloadu(&g_hdone[bb * 32 + tid]) < (unsigned)t) __builtin_amdgcn_s_sleep(4);
    }
    __syncthreads();
    // ===== P1-B: gather h(t-1) (16KB, overlaps P2 latency of other steps) + x(t)
    {
      const float* hsrc = g_hg + ((t + 1) & 1) * (Bb * Hh);
#pragma unroll
      for (int k = 0; k < 4; ++k) {
        int p = tid + k * 512;
        int bl = p >> 8, kp = (p & 255) * 2;
        F2U v = cload2(hsrc + (size_t)(b0 + bl) * Hh + kp);
        sm[OFF_V + bl * VST + 128 + kp] = v.f[0];
        sm[OFF_V + bl * VST + 128 + kp + 1] = v.f[1];
      }
      if (tid < 256) {
        int bl = tid >> 5, c0 = (tid & 31) * 2;
        float2 xv = *(const float2*)(x + ((size_t)(b0 + bl) * Tt + t) * Ii + c0);
        sm[OFF_V + bl * VST + c0] = xv.x;
        sm[OFF_V + bl * VST + c0 + 1] = xv.y;
      }
    }
    // ===== P1-C: wait for rvec(t-1) of my 8 batches (the true critical input)
    if (tid < 8) {
      while (cloadu(&g_rdone[b0 + tid]) < (unsigned)t) __builtin_amdgcn_s_sleep(4);
    }
    __syncthreads();
    if (tid < 256) {
      int bl = tid >> 5, w0 = (tid & 31) * 2;
      F2U v = cload2(g_rvecg + (b0 + bl) * Wd + w0);
      sm[OFF_V + bl * VST + 64 + w0] = v.f[0];
      sm[OFF_V + bl * VST + 64 + w0 + 1] = v.f[1];
    }
    __syncthreads();

    // ===== P1-D: gates GEMV. j-tile = {jb*16+[0,16)} + {0,512,1024,1536}
    {  // thread = (ks8, blh4, gq4, jl4): 4 j x 2 batches x 80 c
      const int jl4 = tid & 3, gq = (tid >> 2) & 3, blh = (tid >> 4) & 3, ks = tid >> 6;
      const float4* __restrict__ wp =
          (const float4*)g_WT + (size_t)(ks * 80) * (G4 / 4) + (jb * 4 + gq * 128 + jl4);
      const float* __restrict__ va = sm + OFF_V + blh * VST + ks * 80;
      const float* __restrict__ vb = va + 4 * VST;
      float4 a1 = {0.f, 0.f, 0.f, 0.f}, a2 = {0.f, 0.f, 0.f, 0.f};
#pragma unroll 8
      for (int c = 0; c < 80; ++c) {
        float4 w4 = wp[(size_t)c * (G4 / 4)];
        float fa = va[c], fb = vb[c];
        a1.x += w4.x * fa; a1.y += w4.y * fa; a1.z += w4.z * fa; a1.w += w4.w * fa;
        a2.x += w4.x * fb; a2.y += w4.y * fb; a2.z += w4.z * fb; a2.w += w4.w * fb;
      }
      float4* pa = (float4*)(sm + OFF_PACC);
      const int q16 = tid & 15;
      pa[(ks * 8 + blh) * 17 + q16] = a1;        // x17 row pad: conflict-break
      pa[(ks * 8 + blh + 4) * 17 + q16] = a2;
    }
    __syncthreads();
    if (tid < 128) {  // K-reduce(8) + bias -> GL, then LSTM below
      const int bl = tid >> 4, q16 = tid & 15;
      const float4* pa = (const float4*)(sm + OFF_PACC);
      float4 g = {0.f, 0.f, 0.f, 0.f};
#pragma unroll
      for (int ks = 0; ks < 8; ++ks) {
        float4 a = pa[(ks * 8 + bl) * 17 + q16];
        g.x += a.x; g.y += a.y; g.z += a.z; g.w += a.w;
      }
      float4 bs = ((const float4*)g_bsum)[jb * 4 + (q16 >> 2) * 128 + (q16 & 3)];
      g.x += bs.x; g.y += bs.y; g.z += bs.z; g.w += bs.w;
      *(float4*)(sm + OFF_GL + bl * 68 + q16 * 4) = g;
    }
    __syncthreads();
    if (tid < 64) {  // LSTM (local! gates never leave the CU), publish h slice
      const int bl = tid >> 3, jl0 = (tid & 7) * 2;
      const float* gl = sm + OFF_GL + bl * 68;
      float hs[2];
#pragma unroll
      for (int e = 0; e < 2; ++e) {
        int jl = jl0 + e;
        float ig = gl[jl], fg = gl[16 + jl], gg = gl[32 + jl], og = gl[48 + jl];
        float co = sm[OFF_CC + bl * 16 + jl];
        float cn = sigf(fg) * co + sigf(ig) * tanhf(gg);
        float hn = sigf(og) * tanhf(cn);
        sm[OFF_CC + bl * 16 + jl] = cn;
        hs[e] = hn;
      }
      cstore2(g_hg + (t & 1) * (Bb * Hh) + (size_t)(b0 + bl) * Hh + jb * 16 + jl0,
              hs[0], hs[1]);
    }
    __syncthreads();
    if (tid == 0) publish(&g_hdone[wg], (unsigned)(t + 1));

    // ===== P2 (wgs 0..31): itf + DNC + rvec + out for batch b = wg
    if (wg < Bb) {
      const int b = wg, grp = b >> 3;
      if (tid < 32) {
        while (cloadu(&g_hdone[grp * 32 + tid]) < (unsigned)(t + 1))
          __builtin_amdgcn_s_sleep(4);
      }
      __syncthreads();
      if (tid < 256) {  // gather h(t) of my batch (2KB)
        int k0 = tid * 2;
        F2U v = cload2(g_hg + (t & 1) * (Bb * Hh) + (size_t)b * Hh + k0);
        sm[OFF_H + k0] = v.f[0];
        sm[OFF_H + k0 + 1] = v.f[1];
      }
      __syncthreads();
      if (tid < 2 * IFs) {  // itf partials (o, K-half)
        const int o = tid >> 1, half = tid & 1;
        const float4* wr = (const float4*)(W_if + (size_t)o * Hh) + half * 64;
        const float4* h4 = (const float4*)(sm + OFF_H) + half * 64;
        float acc = 0.f;
#pragma unroll 8
        for (int c4 = 0; c4 < 64; ++c4) {
          float4 w = wr[c4]; float4 h = h4[c4];
          acc += w.x * h.x + w.y * h.y + w.z * h.z + w.w * h.w;
        }
        SCR[tid] = acc;
      }
      __syncthreads();
      if (tid < IFs) sm[OFF_ITF + tid] = SCR[2 * tid] + SCR[2 * tid + 1] + b_if[tid];
      __syncthreads();
      {  // rank partials [seg][i] (conflict-free)
        const int i = tid >> 2, seg = tid & 3;
        const float ui = sm[OFF_USAGE + i];
        int r = 0;
        for (int j2 = seg * 32; j2 < seg * 32 + 32; ++j2) {
          float uj = sm[OFF_USAGE + j2];
          r += (uj < ui || (uj == ui && j2 < i)) ? 1 : 0;
        }
        ((int*)SCR)[seg * 128 + i] = r;
      }
      if (tid < 64) {
        float rk = sm[OFF_ITF + tid];
        sm[OFF_ERASE + tid] = sigf(rk);
        sm[OFF_WVEC + tid] = sm[OFF_ITF + 64 + tid];
        float sq = rk * rk;
        for (int off = 32; off > 0; off >>= 1) sq += __shfl_down(sq, off, 64);
        if (tid == 0) sm[OFF_SCAL + S_KN] = sqrtf(sq) + 1e-8f;
      } else if (tid == 64) {
        sm[OFF_SCAL + S_WGAG] = sigf(sm[OFF_ITF + 128]) * sigf(sm[OFF_ITF + 129]);
        float rs = sm[OFF_ITF + 194];
        sm[OFF_SCAL + S_RSTR] = (rs > 20.f) ? rs : log1pf(expf(rs));
        float m0 = sm[OFF_ITF + 195], m1 = sm[OFF_ITF + 196], m2 = sm[OFF_ITF + 197];
        float mx = fmaxf(m0, fmaxf(m1, m2));
        float e0 = expf(m0 - mx), e1 = expf(m1 - mx), e2 = expf(m2 - mx);
        float es = e0 + e1 + e2;
        sm[OFF_SCAL + S_RM0] = e0 / es;
        sm[OFF_SCAL + S_RM1] = e1 / es;
        sm[OFF_SCAL + S_RM2] = e2 / es;
      }
      __syncthreads();
      if (tid < 128) {  // rank reduce + scatter sorted usage
        const int* ri = (const int*)SCR;
        int r = ri[tid] + ri[128 + tid] + ri[256 + tid] + ri[384 + tid];
        ((int*)(sm + OFF_RANK))[tid] = r;
        sm[OFF_SS + r] = sm[OFF_USAGE + tid];
      }
      __syncthreads();
      if (tid < 64) {  // prefix-product (single-wave shuffle scan, 2/lane)
        float s0 = sm[OFF_SS + 2 * tid], s1 = sm[OFF_SS + 2 * tid + 1];
        float p = s0 * s1;
#pragma unroll
        for (int off = 1; off < 64; off <<= 1) {
          float v = __shfl_up(p, off, 64);
          if (tid >= off) p *= v;
        }
        float excl = __shfl_up(p, 1, 64);
        if (tid == 0) excl = 1.f;
        sm[OFF_SCAN + 2 * tid] = excl * s0;
        sm[OFF_SCAN + 2 * tid + 1] = excl * s0 * s1;
      }
      __syncthreads();
      if (tid < 64) {  // ww + wwsum
        float wgag = sm[OFF_SCAL + S_WGAG];
        float wws = 0.f;
#pragma unroll
        for (int e = 0; e < 2; ++e) {
          int i = 2 * tid + e;
          int r = ((const int*)(sm + OFF_RANK))[i];
          float excl = (r > 0) ? sm[OFF_SCAN + r - 1] : 1.f;
          float w = wgag * (1.f - sm[OFF_USAGE + i]) * excl;
          sm[OFF_WW + i] = w;
          wws += w;
        }
        for (int off = 32; off > 0; off >>= 1) wws += __shfl_down(wws, off, 64);
        if (tid == 0) sm[OFF_SCAL + S_WWSUM] = wws;
      }
      __syncthreads();
      for (int idx = tid; idx < Nn * Wd; idx += NT) {  // mem update
        int n = idx >> 6, w = idx & 63;
        float wwn = sm[OFF_WW + n];
        float m = sm[OFF_MEM + n * 65 + w];
        sm[OFF_MEM + n * 65 + w] =
            m * (1.f - wwn * sm[OFF_ERASE + w]) + wwn * sm[OFF_WVEC + w];
      }
      for (int idx = tid; idx < Nn * Nn; idx += NT) {  // link update (old prec)
        int i2 = idx >> 7, j2 = idx & 127;
        float wwi = sm[OFF_WW + i2], wwj = sm[OFF_WW + j2];
        float L = sm[OFF_LINK + i2 * 129 + j2];
        L = (1.f - wwi - wwj) * L + sm[OFF_PREC + i2] * wwj;
        sm[OFF_LINK + i2 * 129 + j2] = (i2 == j2) ? 0.f : L;
      }
      if (tid < 128) {  // usage update
        float u = sm[OFF_USAGE + tid];
        sm[OFF_USAGE + tid] = u + (1.f - u) * sm[OFF_WW + tid];
      }
      __syncthreads();
      if (tid < 128) {  // prec update
        sm[OFF_PREC + tid] =
            (1.f - sm[OFF_SCAL + S_WWSUM]) * sm[OFF_PREC + tid] + sm[OFF_WW + tid];
      }
      {  // dot/mn/bw/fw partials -> SCR[q*512 + seg*128 + n] (conflict-free)
        const int n = tid & 127, seg = tid >> 7;
        float d = 0.f, m2 = 0.f;
        for (int w = seg * 16; w < seg * 16 + 16; ++w) {
          float m = sm[OFF_MEM + n * 65 + w];
          d += sm[OFF_ITF + w] * m;
          m2 += m * m;
        }
        SCR[seg * 128 + n] = d;
        SCR[512 + seg * 128 + n] = m2;
        float bwp = 0.f, fwp = 0.f;
        for (int n2 = seg * 32; n2 < seg * 32 + 32; ++n2) {
          bwp += sm[OFF_LINK + n2 * 129 + n] * sm[OFF_RW + n2];
          fwp += sm[OFF_LINK + n * 129 + n2] * sm[OFF_RW + n2];
        }
        SCR[1024 + seg * 128 + n] = bwp;
        SCR[1536 + seg * 128 + n] = fwp;
      }
      __syncthreads();
      {  // reduce 4 partials each
        const int q = tid >> 7, n = tid & 127;
        const float* s = SCR + q * 512;
        float v = s[n] + s[128 + n] + s[256 + n] + s[384 + n];
        if (q == 0) sm[OFF_DOT + n] = v;
        else if (q == 1) sm[OFF_MN + n] = sqrtf(v) + 1e-8f;
        else if (q == 2) sm[OFF_BW + n] = v;
        else sm[OFF_FW + n] = v;
      }
      __syncthreads();
      if (tid < 64) {  // cosine softmax + combine + normalize (single wave)
        float kn = sm[OFF_SCAL + S_KN], rstr = sm[OFF_SCAL + S_RSTR];
        float rm0 = sm[OFF_SCAL + S_RM0], rm1 = sm[OFF_SCAL + S_RM1],
              rm2 = sm[OFF_SCAL + S_RM2];
        int i0 = 2 * tid, i1 = 2 * tid + 1;
        float q0 = sm[OFF_DOT + i0] / (kn * sm[OFF_MN + i0]) * rstr;
        float q1 = sm[OFF_DOT + i1] / (kn * sm[OFF_MN + i1]) * rstr;
        float mx = fmaxf(q0, q1);
#pragma unroll
        for (int off = 32; off > 0; off >>= 1) mx = fmaxf(mx, __shfl_xor(mx, off, 64));
        float e0 = expf(q0 - mx), e1 = expf(q1 - mx);
        float es = e0 + e1;
#pragma unroll
        for (int off = 32; off > 0; off >>= 1) es += __shfl_xor(es, off, 64);
        float wv0 = rm0 * sm[OFF_BW + i0] + rm1 * sm[OFF_FW + i0] + rm2 * (e0 / es) + 1e-8f;
        float wv1 = rm0 * sm[OFF_BW + i1] + rm1 * sm[OFF_FW + i1] + rm2 * (e1 / es) + 1e-8f;
        float ws = wv0 + wv1;
#pragma unroll
        for (int off = 32; off > 0; off >>= 1) ws += __shfl_xor(ws, off, 64);
        sm[OFF_RW + i0] = wv0 / ws;
        sm[OFF_RW + i1] = wv1 / ws;
      }
      __syncthreads();
      {  // rvec partials -> SCR[seg*64 + w] (conflict-free)
        const int w = tid & 63, seg = tid >> 6;
        float p = 0.f;
        for (int n = seg * 16; n < seg * 16 + 16; ++n)
          p += sm[OFF_RW + n] * sm[OFF_MEM + n * 65 + w];
        SCR[seg * 64 + w] = p;
      }
      __syncthreads();
      if (tid < 64) {  // rvec reduce -> publish FIRST (critical path exit)
        float r = 0.f;
#pragma unroll
        for (int s2 = 0; s2 < 8; ++s2) r += SCR[s2 * 64 + tid];
        sm[OFF_H + 512 + tid] = r;
        cstore(g_rvecg + b * Wd + tid, r);
      }
      __syncthreads();
      if (tid == 0) publish(&g_rdone[b], (unsigned)(t + 1));
      {  // out projection (off critical path)
        const int o = tid >> 3, seg = tid & 7;
        const float4* wrow = (const float4*)(W_out + (size_t)o * 576) + seg * 18;
        const float4* hb = (const float4*)(sm + OFF_H) + seg * 18;
        float p = 0.f;
#pragma unroll
        for (int q = 0; q < 18; ++q) {
          float4 w = wrow[q]; float4 h = hb[q];
          p += w.x * h.x + w.y * h.y + w.z * h.z + w.w * h.w;
        }
        p += __shfl_down(p, 4, 8);
        p += __shfl_down(p, 2, 8);
        p += __shfl_down(p, 1, 8);
        if (seg == 0) out[((size_t)b * Tt + t) * Oo + o] = p + b_out[o];
      }
    }
  }
}

extern "C" void kernel_launch(void* const* d_in, const int* in_sizes, int n_in,
                              void* d_out, int out_size, void* d_ws, size_t ws_size,
                              hipStream_t stream) {
  (void)in_sizes; (void)n_in; (void)d_ws; (void)ws_size; (void)out_size;
  const float* x    = (const float*)d_in[0];
  const float* W_ih = (const float*)d_in[1];
  const float* W_hh = (const float*)d_in[2];
  const float* b_ih = (const float*)d_in[3];
  const float* b_hh = (const float*)d_in[4];
  const float* W_if = (const float*)d_in[5];
  const float* b_if = (const float*)d_in[6];
  const float* W_out = (const float*)d_in[7];
  const float* b_out = (const float*)d_in[8];
  float* out = (float*)d_out;

  dnc_init<<<320, TIN, 0, stream>>>(W_ih, W_hh, b_ih, b_hh);

  hipFuncSetAttribute((const void*)dnc_main,
                      hipFuncAttributeMaxDynamicSharedMemorySize, SMEM_BYTES);

  void* args[] = {(void*)&x, (void*)&W_if, (void*)&b_if,
                  (void*)&W_out, (void*)&b_out, (void*)&out};
  hipLaunchCooperativeKernel((void*)dnc_main, dim3(NWG), dim3(NT), args,
                             SMEM_BYTES, stream);
}

// Round 7
// 2215.051 us; speedup vs baseline: 2.7500x; 1.1729x over previous
//
#include <hip/hip_runtime.h>
#include <math.h>

// DNC: B=32,T=64,I=64,O=64,H=512,N=128,W=64,IF=198
#define Bb 32
#define Tt 64
#define Ii 64
#define Oo 64
#define Hh 512
#define Nn 128
#define Wd 64
#define IFs 198
#define KV 640
#define G4 2048

#define NWG 128
#define NT 512
#define VST 648

// ---- LDS layout (float offsets); link lives in REGISTERS now.
#define OFF_MEM    0        /* 128*65 = 8320 */
#define OFF_V      8320     /* 8*648 = 5184 */
#define OFF_CC     13504    /* 128 LSTM c-state slice */
#define OFF_GL     13632    /* 8*68 local gates */
#define OFF_HSL    14176    /* 128 h-slice [bl*16+jl] */
#define OFF_H      14304    /* 576 [h|rvec] (P2 tail) */
#define OFF_PACC   14880    /* 1024 float4 = 4096 ; SCR alias (needs 2048) */
#define OFF_ITF    18976    /* 224 */
#define OFF_ERASE  19200
#define OFF_WVEC   19264
#define OFF_USAGE  19328
#define OFF_PREC   19456
#define OFF_RW     19584
#define OFF_WW     19712
#define OFF_DOT    19840
#define OFF_MN     19968
#define OFF_BW     20096
#define OFF_FW     20224
#define OFF_SCAN   20352
#define OFF_SS     20480
#define OFF_SCAL   20608    /* 16 */
#define SMEM_FLOATS 20624   /* 82496 B */
#define SMEM_BYTES (SMEM_FLOATS * 4)

#define S_WWSUM 0
#define S_KN 1

__device__ __align__(16) float g_WT[KV * G4];      // WT[c][j]
__device__ __align__(16) float g_bsum[G4];
__device__ __align__(16) float g_hg[2 * Bb * Hh];  // step-parity double buffer
__device__ __align__(16) float g_rvecg[Bb * Wd];
__device__ __align__(16) float g_itfp[Bb * 200 * 32]; // itf partials [b][o(pad200)][jb]
__device__ unsigned g_hdone[NWG];   // P1 wg published h+itfp(t) <=> == t+1
__device__ unsigned g_rdone[Bb];    // P2 wg published rvec(t)  <=> == t+1

__device__ __forceinline__ float sigf(float v) { return 1.f / (1.f + expf(-v)); }

typedef unsigned long long u64;
union F2U { u64 u; float f[2]; };

__device__ __forceinline__ void cstore2(float* p, float a, float b) {
  F2U v; v.f[0] = a; v.f[1] = b;
  __hip_atomic_store((u64*)p, v.u, __ATOMIC_RELAXED, __HIP_MEMORY_SCOPE_AGENT);
}
__device__ __forceinline__ void cstore(float* p, float v) {
  __hip_atomic_store(p, v, __ATOMIC_RELAXED, __HIP_MEMORY_SCOPE_AGENT);
}
__device__ __forceinline__ F2U cload2(const float* p) {
  F2U v; v.u = __hip_atomic_load((const u64*)p, __ATOMIC_RELAXED, __HIP_MEMORY_SCOPE_AGENT);
  return v;
}
// RELEASE publish after __syncthreads (empirically validated R5/R6 recipe).
__device__ __forceinline__ void publish(unsigned* p, unsigned v) {
  __hip_atomic_store(p, v, __ATOMIC_RELEASE, __HIP_MEMORY_SCOPE_AGENT);
}
__device__ __forceinline__ unsigned cloadu(const unsigned* p) {
  return __hip_atomic_load(p, __ATOMIC_RELAXED, __HIP_MEMORY_SCOPE_AGENT);
}

#define TIN 512
__global__ __launch_bounds__(TIN) void dnc_init(const float* __restrict__ W_ih,
                                                const float* __restrict__ W_hh,
                                                const float* __restrict__ b_ih,
                                                const float* __restrict__ b_hh) {
  __shared__ float tile[64][65];
  const int tid = threadIdx.x;
  int i0 = blockIdx.x * blockDim.x + tid;
  int st = gridDim.x * blockDim.x;
  for (int idx = i0; idx < G4; idx += st) g_bsum[idx] = b_ih[idx] + b_hh[idx];
  for (int idx = i0; idx < 2 * Bb * Hh; idx += st) g_hg[idx] = 0.f;
  for (int idx = i0; idx < Bb * Wd; idx += st) g_rvecg[idx] = 0.f;
  if (i0 < NWG) g_hdone[i0] = 0u;
  if (i0 < Bb) g_rdone[i0] = 0u;

  for (int tileId = blockIdx.x; tileId < 320; tileId += gridDim.x) {
    int tc = tileId >> 5, tj = tileId & 31;
    for (int k = tid; k < 64 * 64; k += TIN) {
      int r = k >> 6, cl = k & 63;
      int j = tj * 64 + r, c = tc * 64 + cl;
      tile[r][cl] = (c < 128) ? W_ih[j * 128 + c] : W_hh[j * 512 + (c - 128)];
    }
    __syncthreads();
    for (int k = tid; k < 64 * 64; k += TIN) {
      int cl = k >> 6, r = k & 63;
      g_WT[(size_t)(tc * 64 + cl) * G4 + tj * 64 + r] = tile[r][cl];
    }
    __syncthreads();
  }
}

__global__ __launch_bounds__(NT) void dnc_main(const float* __restrict__ x,
                                               const float* __restrict__ W_if,
                                               const float* __restrict__ b_if,
                                               const float* __restrict__ W_out,
                                               const float* __restrict__ b_out,
                                               float* __restrict__ out) {
  extern __shared__ float sm[];
  float* SCR = sm + OFF_PACC;
  const int tid = threadIdx.x;
  const int lane = tid & 63;
  const int wg = blockIdx.x;
  // XCD-aligned: same-jb wgs {jb, jb+32, jb+64, jb+96} share an XCD's L2.
  const int jb = wg & 31;
  const int bb = wg >> 5;
  const int b0 = bb * 8;

  // persistent register link state (only meaningful for wg<32; cheap elsewhere)
  float regL[32], regLT[32];   // regL: col m=tid&127, rows ns*32+k ; regLT: row tid&127, cols ms*32+k
#pragma unroll
  for (int k = 0; k < 32; ++k) { regL[k] = 0.f; regLT[k] = 0.f; }

  if (tid < 128) sm[OFF_CC + tid] = 0.f;
  if (wg < Bb) {
    for (int i = tid; i < Nn * 65; i += NT) sm[OFF_MEM + i] = 0.f;
    if (tid < 128) { sm[OFF_USAGE + tid] = 0.f; sm[OFF_PREC + tid] = 0.f; sm[OFF_RW + tid] = 0.f; }
  }
  __syncthreads();

  for (int t = 0; t < Tt; ++t) {
    // ===== P1-A: wait for h(t-1)+itfp slices of my batch group
    if (tid < 32) {
      while (cloadu(&g_hdone[bb * 32 + tid]) < (unsigned)t) __builtin_amdgcn_s_sleep(4);
    }
    __syncthreads();
    {  // stage h(t-1) into V (c128..639)
      const float* hsrc = g_hg + ((t + 1) & 1) * (Bb * Hh);
#pragma unroll
      for (int k = 0; k < 4; ++k) {
        int p = tid + k * 512;
        int bl = p >> 8, kp = (p & 255) * 2;
        F2U v = cload2(hsrc + (size_t)(b0 + bl) * Hh + kp);
        sm[OFF_V + bl * VST + 128 + kp] = v.f[0];
        sm[OFF_V + bl * VST + 128 + kp + 1] = v.f[1];
      }
    }
    __syncthreads();

    // ===== P1-D: wave-specialized gates GEMV (c-order: h first, rvec last)
    {
      const int jl4 = tid & 3, gq = (tid >> 2) & 3, blh = (tid >> 4) & 3, ks = tid >> 6;
      const int fcol = jb * 4 + gq * 128 + jl4;
      const float* va = sm + OFF_V + blh * VST;
      const float* vb = va + 4 * VST;
      float4 a1 = {0.f, 0.f, 0.f, 0.f}, a2 = {0.f, 0.f, 0.f, 0.f};

#define GEMV_RANGE(C0, LEN)                                                    \
      {                                                                        \
        const float4* wp = (const float4*)g_WT + (size_t)(C0) * (G4 / 4) + fcol; \
        _Pragma("unroll 4")                                                    \
        for (int c = 0; c < (LEN); ++c) {                                      \
          float4 w4 = wp[(size_t)c * (G4 / 4)];                                \
          float fa = va[(C0) + c], fb = vb[(C0) + c];                          \
          a1.x += w4.x * fa; a1.y += w4.y * fa; a1.z += w4.z * fa; a1.w += w4.w * fa; \
          a2.x += w4.x * fb; a2.y += w4.y * fb; a2.z += w4.z * fb; a2.w += w4.w * fb; \
        }                                                                      \
      }

      if (ks < 6) {
        GEMV_RANGE(128 + 80 * ks, 80);
      } else if (ks == 6) {
        {  // stage x c0..47 (within-wave write->read)
          int bl = lane >> 3, c0 = (lane & 7) * 6;
          const float* xs = x + ((size_t)(b0 + bl) * Tt + t) * Ii + c0;
          float2 xa = *(const float2*)xs, xb = *(const float2*)(xs + 2),
                 xc = *(const float2*)(xs + 4);
          float* vd = sm + OFF_V + bl * VST + c0;
          vd[0] = xa.x; vd[1] = xa.y; vd[2] = xb.x; vd[3] = xb.y; vd[4] = xc.x; vd[5] = xc.y;
        }
        GEMV_RANGE(608, 32);
        GEMV_RANGE(0, 48);
      } else {
        {  // stage x c48..63
          int bl = lane >> 3, c0 = 48 + (lane & 7) * 2;
          float2 xa = *(const float2*)(x + ((size_t)(b0 + bl) * Tt + t) * Ii + c0);
          float* vd = sm + OFF_V + bl * VST + c0;
          vd[0] = xa.x; vd[1] = xa.y;
        }
        GEMV_RANGE(48, 16);
        if (lane < 8) {  // wait for rvec(t-1) — only THIS wave blocks
          while (cloadu(&g_rdone[b0 + lane]) < (unsigned)t) __builtin_amdgcn_s_sleep(4);
        }
        {  // stage rvec c64..127
          int bl = lane >> 3, w0 = (lane & 7) * 8;
          const float* rs = g_rvecg + (b0 + bl) * Wd + w0;
          float* vd = sm + OFF_V + bl * VST + 64 + w0;
#pragma unroll
          for (int e = 0; e < 4; ++e) {
            F2U v = cload2(rs + 2 * e);
            vd[2 * e] = v.f[0]; vd[2 * e + 1] = v.f[1];
          }
        }
        GEMV_RANGE(64, 64);
      }
      float4* pa = (float4*)(sm + OFF_PACC);
      const int q16 = tid & 15;
      pa[(ks * 8 + blh) * 16 + q16] = a1;
      pa[(ks * 8 + blh + 4) * 16 + q16] = a2;
    }
    __syncthreads();
    if (tid < 128) {  // K-reduce(8) + bias -> GL
      const int bl = tid >> 4, q16 = tid & 15;
      const float4* pa = (const float4*)(sm + OFF_PACC);
      float4 g = {0.f, 0.f, 0.f, 0.f};
#pragma unroll
      for (int ks = 0; ks < 8; ++ks) {
        float4 a = pa[(ks * 8 + bl) * 16 + q16];
        g.x += a.x; g.y += a.y; g.z += a.z; g.w += a.w;
      }
      float4 bs = ((const float4*)g_bsum)[jb * 4 + (q16 >> 2) * 128 + (q16 & 3)];
      g.x += bs.x; g.y += bs.y; g.z += bs.z; g.w += bs.w;
      *(float4*)(sm + OFF_GL + bl * 68 + q16 * 4) = g;
    }
    __syncthreads();
    if (tid < 64) {  // LSTM: gates never leave the CU; h -> HSL + coherent store
      const int bl = tid >> 3, jl0 = (tid & 7) * 2;
      const float* gl = sm + OFF_GL + bl * 68;
      float hs[2];
#pragma unroll
      for (int e = 0; e < 2; ++e) {
        int jl = jl0 + e;
        float ig = gl[jl], fg = gl[16 + jl], gg = gl[32 + jl], og = gl[48 + jl];
        float co = sm[OFF_CC + bl * 16 + jl];
        float cn = sigf(fg) * co + sigf(ig) * tanhf(gg);
        float hn = sigf(og) * tanhf(cn);
        sm[OFF_CC + bl * 16 + jl] = cn;
        sm[OFF_HSL + bl * 16 + jl] = hn;
        hs[e] = hn;
      }
      cstore2(g_hg + (t & 1) * (Bb * Hh) + (size_t)(b0 + bl) * Hh + jb * 16 + jl0,
              hs[0], hs[1]);
    }
    __syncthreads();
    if (tid < IFs) {  // itf partials for my 16-col slice of W_if (off P2's path)
      const int o = tid;
      const float4* wr = (const float4*)(W_if + (size_t)o * Hh + jb * 16);
      float4 w0 = wr[0], w1 = wr[1], w2 = wr[2], w3 = wr[3];
#pragma unroll
      for (int bl = 0; bl < 8; ++bl) {
        const float4* hb = (const float4*)(sm + OFF_HSL + bl * 16);
        float4 h0 = hb[0], h1 = hb[1], h2 = hb[2], h3 = hb[3];
        float s = w0.x * h0.x + w0.y * h0.y + w0.z * h0.z + w0.w * h0.w
                + w1.x * h1.x + w1.y * h1.y + w1.z * h1.z + w1.w * h1.w
                + w2.x * h2.x + w2.y * h2.y + w2.z * h2.z + w2.w * h2.w
                + w3.x * h3.x + w3.y * h3.y + w3.z * h3.z + w3.w * h3.w;
        cstore(g_itfp + ((size_t)(b0 + bl) * 200 + o) * 32 + jb, s);
      }
    }
    __syncthreads();   // all waves' coherent stores drained
    if (tid == 0) publish(&g_hdone[wg], (unsigned)(t + 1));

    // ===== P2 (wgs 0..31): DNC memory for batch b = wg
    if (wg < Bb) {
      const int b = wg, grp = b >> 3;
      if (tid < 32) {
        while (cloadu(&g_hdone[grp * 32 + tid]) < (unsigned)(t + 1))
          __builtin_amdgcn_s_sleep(4);
      }
      __syncthreads();
      if (tid < 2 * IFs) {  // gather itf partials: (o, half of 32 jb)
        const int o = tid >> 1, hf = tid & 1;
        const float* src = g_itfp + ((size_t)b * 200 + o) * 32 + hf * 16;
        float s = 0.f;
#pragma unroll
        for (int k = 0; k < 8; ++k) { F2U v = cload2(src + 2 * k); s += v.f[0] + v.f[1]; }
        s += __shfl_xor(s, 1, 64);
        if (hf == 0) sm[OFF_ITF + o] = s + b_if[o];
      }
      __syncthreads();
      // wave0 mega-block: scalars, rank, scan, ww, usage — zero barriers inside
      float kn_r = 0.f, rstr_r = 0.f, rm0_r = 0.f, rm1_r = 0.f, rm2_r = 0.f;
      if (tid < 64) {
        const int li = tid, i0 = 2 * li, i1 = i0 + 1;
        // derived scalars (all lanes redundantly)
        float wgag = sigf(sm[OFF_ITF + 128]) * sigf(sm[OFF_ITF + 129]);
        float rs = sm[OFF_ITF + 194];
        rstr_r = (rs > 20.f) ? rs : log1pf(expf(rs));
        float m0 = sm[OFF_ITF + 195], m1 = sm[OFF_ITF + 196], m2 = sm[OFF_ITF + 197];
        float mx = fmaxf(m0, fmaxf(m1, m2));
        float e0 = expf(m0 - mx), e1 = expf(m1 - mx), e2 = expf(m2 - mx);
        float es = e0 + e1 + e2;
        rm0_r = e0 / es; rm1_r = e1 / es; rm2_r = e2 / es;
        // erase/wvec/kn
        float rk = sm[OFF_ITF + li];
        sm[OFF_ERASE + li] = sigf(rk);
        sm[OFF_WVEC + li] = sm[OFF_ITF + 64 + li];
        float sq = rk * rk;
#pragma unroll
        for (int off = 32; off > 0; off >>= 1) sq += __shfl_xor(sq, off, 64);
        kn_r = sqrtf(sq) + 1e-8f;
        // stable ranks
        float u0 = sm[OFF_USAGE + i0], u1 = sm[OFF_USAGE + i1];
        int r0 = 0, r1 = 0;
        for (int jc = 0; jc < 32; ++jc) {
          float4 uj4 = *(const float4*)(sm + OFF_USAGE + jc * 4);
#pragma unroll
          for (int e = 0; e < 4; ++e) {
            float uj = (&uj4.x)[e];
            int j = jc * 4 + e;
            r0 += (uj < u0 || (uj == u0 && j < i0)) ? 1 : 0;
            r1 += (uj < u1 || (uj == u1 && j < i1)) ? 1 : 0;
          }
        }
        sm[OFF_SS + r0] = u0;
        sm[OFF_SS + r1] = u1;
        float s0 = sm[OFF_SS + i0], s1 = sm[OFF_SS + i1];
        float p = s0 * s1;
#pragma unroll
        for (int off = 1; off < 64; off <<= 1) {
          float v = __shfl_up(p, off, 64);
          if (li >= off) p *= v;
        }
        float E = __shfl_up(p, 1, 64);
        if (li == 0) E = 1.f;
        sm[OFF_SCAN + i0] = E * s0;
        sm[OFF_SCAN + i1] = E * s0 * s1;
        float ex0 = (r0 > 0) ? sm[OFF_SCAN + r0 - 1] : 1.f;
        float ex1 = (r1 > 0) ? sm[OFF_SCAN + r1 - 1] : 1.f;
        float w0 = wgag * (1.f - u0) * ex0;
        float w1 = wgag * (1.f - u1) * ex1;
        sm[OFF_WW + i0] = w0; sm[OFF_WW + i1] = w1;
        sm[OFF_USAGE + i0] = u0 + (1.f - u0) * w0;
        sm[OFF_USAGE + i1] = u1 + (1.f - u1) * w1;
        float wws = w0 + w1;
#pragma unroll
        for (int off = 32; off > 0; off >>= 1) wws += __shfl_xor(wws, off, 64);
        if (li == 0) sm[OFF_SCAL + S_WWSUM] = wws;
      }
      __syncthreads();
      // pass1: fused mem+dot+mn (LDS) + link update + bw/fw partials (registers)
      {
        const int n = tid & 127, ws = tid >> 7;
        float4 er[4], wv[4], kf[4];
#pragma unroll
        for (int r = 0; r < 4; ++r) {
          er[r] = *(const float4*)(sm + OFF_ERASE + ws * 16 + r * 4);
          wv[r] = *(const float4*)(sm + OFF_WVEC + ws * 16 + r * 4);
          kf[r] = *(const float4*)(sm + OFF_ITF + ws * 16 + r * 4);
        }
        float wwn = sm[OFF_WW + n];
        float dotp = 0.f, mnp = 0.f;
        const int base = OFF_MEM + n * 65 + ws * 16;
#pragma unroll
        for (int q = 0; q < 16; ++q) {
          float m = sm[base + q];
          float ee = (&er[q >> 2].x)[q & 3];
          float vv = (&wv[q >> 2].x)[q & 3];
          float kk = (&kf[q >> 2].x)[q & 3];
          m = m * (1.f - wwn * ee) + wwn * vv;
          sm[base + q] = m;
          dotp += kk * m;
          mnp += m * m;
        }
        SCR[ws * 128 + n] = dotp;
        SCR[512 + ws * 128 + n] = mnp;
        // link (registers): regL col m=n, rows ns*32+k ; regLT row n, cols ns*32+k
        const int m = n, ns = ws;
        float wwm = wwn;                    // ww[m]
        float prn = sm[OFF_PREC + m];       // prec[row] for regLT
        float bwp = 0.f, fwp = 0.f;
#pragma unroll
        for (int kq = 0; kq < 8; ++kq) {
          float4 ww4 = *(const float4*)(sm + OFF_WW + ns * 32 + kq * 4);
          float4 pr4 = *(const float4*)(sm + OFF_PREC + ns * 32 + kq * 4);
          float4 rw4 = *(const float4*)(sm + OFF_RW + ns * 32 + kq * 4);
#pragma unroll
          for (int e = 0; e < 4; ++e) {
            int k = kq * 4 + e;
            int nn = ns * 32 + k;
            float wwo = (&ww4.x)[e];
            float pro = (&pr4.x)[e];
            float rwo = (&rw4.x)[e];
            float L = regL[k];
            L = (1.f - wwo - wwm) * L + pro * wwm;
            if (nn == m) L = 0.f;
            regL[k] = L;
            bwp += L * rwo;                 // bw[m] partial (sum over n)
            float LT = regLT[k];
            LT = (1.f - wwm - wwo) * LT + prn * wwo;
            if (nn == m) LT = 0.f;
            regLT[k] = LT;
            fwp += LT * rwo;                // fw[row] partial (sum over m)
          }
        }
        SCR[1024 + ns * 128 + m] = bwp;
        SCR[1536 + ns * 128 + m] = fwp;
      }
      __syncthreads();
      {  // pass2: reduces + prec update
        const int n = tid & 127, role = tid >> 7;
        if (role == 0) {
          sm[OFF_DOT + n] = SCR[n] + SCR[128 + n] + SCR[256 + n] + SCR[384 + n];
          float wws = sm[OFF_SCAL + S_WWSUM];
          sm[OFF_PREC + n] = (1.f - wws) * sm[OFF_PREC + n] + sm[OFF_WW + n];
        } else if (role == 1) {
          float v = SCR[512 + n] + SCR[640 + n] + SCR[768 + n] + SCR[896 + n];
          sm[OFF_MN + n] = sqrtf(v) + 1e-8f;
        } else if (role == 2) {
          sm[OFF_BW + n] = SCR[1024 + n] + SCR[1152 + n] + SCR[1280 + n] + SCR[1408 + n];
        } else {
          sm[OFF_FW + n] = SCR[1536 + n] + SCR[1664 + n] + SCR[1792 + n] + SCR[1920 + n];
        }
      }
      __syncthreads();
      if (tid < 64) {  // cosine softmax + combine + normalize (wave0 registers)
        int i0 = 2 * tid, i1 = i0 + 1;
        float q0 = sm[OFF_DOT + i0] / (kn_r * sm[OFF_MN + i0]) * rstr_r;
        float q1 = sm[OFF_DOT + i1] / (kn_r * sm[OFF_MN + i1]) * rstr_r;
        float mx = fmaxf(q0, q1);
#pragma unroll
        for (int off = 32; off > 0; off >>= 1) mx = fmaxf(mx, __shfl_xor(mx, off, 64));
        float e0 = expf(q0 - mx), e1 = expf(q1 - mx);
        float es = e0 + e1;
#pragma unroll
        for (int off = 32; off > 0; off >>= 1) es += __shfl_xor(es, off, 64);
        float wv0 = rm0_r * sm[OFF_BW + i0] + rm1_r * sm[OFF_FW + i0] + rm2_r * (e0 / es) + 1e-8f;
        float wv1 = rm0_r * sm[OFF_BW + i1] + rm1_r * sm[OFF_FW + i1] + rm2_r * (e1 / es) + 1e-8f;
        float wsum = wv0 + wv1;
#pragma unroll
        for (int off = 32; off > 0; off >>= 1) wsum += __shfl_xor(wsum, off, 64);
        sm[OFF_RW + i0] = wv0 / wsum;
        sm[OFF_RW + i1] = wv1 / wsum;
      }
      __syncthreads();
      {  // rvec partials
        const int w = tid & 63, ns8 = tid >> 6;
        float4 rw4[4];
#pragma unroll
        for (int r = 0; r < 4; ++r)
          rw4[r] = *(const float4*)(sm + OFF_RW + ns8 * 16 + r * 4);
        float p = 0.f;
#pragma unroll
        for (int k = 0; k < 16; ++k)
          p += (&rw4[k >> 2].x)[k & 3] * sm[OFF_MEM + (ns8 * 16 + k) * 65 + w];
        SCR[ns8 * 64 + w] = p;
      }
      __syncthreads();
      if (tid < 64) {  // rvec reduce -> publish immediately (critical-path exit)
        float r = 0.f;
#pragma unroll
        for (int s2 = 0; s2 < 8; ++s2) r += SCR[s2 * 64 + tid];
        sm[OFF_H + 512 + tid] = r;
        cstore(g_rvecg + b * Wd + tid, r);
        if (tid == 0) publish(&g_rdone[b], (unsigned)(t + 1));  // wave0's own stores ordered
      }
      __syncthreads();
      // ---- tail (hidden behind P1's next leg): gather h, out projection
      if (tid < 256) {
        F2U v = cload2(g_hg + (t & 1) * (Bb * Hh) + (size_t)b * Hh + tid * 2);
        sm[OFF_H + tid * 2] = v.f[0];
        sm[OFF_H + tid * 2 + 1] = v.f[1];
      }
      __syncthreads();
      {
        const int o = tid >> 3, seg = tid & 7;
        const float4* wrow = (const float4*)(W_out + (size_t)o * 576) + seg * 18;
        const float4* hb = (const float4*)(sm + OFF_H) + seg * 18;
        float p = 0.f;
#pragma unroll
        for (int q = 0; q < 18; ++q) {
          float4 w = wrow[q]; float4 h = hb[q];
          p += w.x * h.x + w.y * h.y + w.z * h.z + w.w * h.w;
        }
        p += __shfl_down(p, 4, 8);
        p += __shfl_down(p, 2, 8);
        p += __shfl_down(p, 1, 8);
        if (seg == 0) out[((size_t)b * Tt + t) * Oo + o] = p + b_out[o];
      }
    }
  }
}

extern "C" void kernel_launch(void* const* d_in, const int* in_sizes, int n_in,
                              void* d_out, int out_size, void* d_ws, size_t ws_size,
                              hipStream_t stream) {
  (void)in_sizes; (void)n_in; (void)d_ws; (void)ws_size; (void)out_size;
  const float* x    = (const float*)d_in[0];
  const float* W_ih = (const float*)d_in[1];
  const float* W_hh = (const float*)d_in[2];
  const float* b_ih = (const float*)d_in[3];
  const float* b_hh = (const float*)d_in[4];
  const float* W_if = (const float*)d_in[5];
  const float* b_if = (const float*)d_in[6];
  const float* W_out = (const float*)d_in[7];
  const float* b_out = (const float*)d_in[8];
  float* out = (float*)d_out;

  dnc_init<<<320, TIN, 0, stream>>>(W_ih, W_hh, b_ih, b_hh);

  hipFuncSetAttribute((const void*)dnc_main,
                      hipFuncAttributeMaxDynamicSharedMemorySize, SMEM_BYTES);

  void* args[] = {(void*)&x, (void*)&W_if, (void*)&b_if,
                  (void*)&W_out, (void*)&b_out, (void*)&out};
  hipLaunchCooperativeKernel((void*)dnc_main, dim3(NWG), dim3(NT), args,
                             SMEM_BYTES, stream);
}

// Round 8
// 1671.350 us; speedup vs baseline: 3.6446x; 1.3253x over previous
//
#include <hip/hip_runtime.h>
#include <math.h>

// DNC: B=32,T=64,I=64,O=64,H=512,N=128,W=64,IF=198
#define Bb 32
#define Tt 64
#define Ii 64
#define Oo 64
#define Hh 512
#define Nn 128
#define Wd 64
#define IFs 198
#define KV 640
#define G4 2048

#define NP1 128
#define NWG 160          /* 128 P1 wgs + 32 P2 wgs */
#define NT 512
#define VST 648

// ---- LDS layout (float offsets). P1 wgs use V/CC/GL/HSL/PACC;
// P2 wgs use MEM/H/ITF..SCAL + SCR. Disjoint roles -> no aliasing hazards.
#define OFF_MEM    0        /* 128*65 = 8320 */
#define OFF_V      8320     /* 8*648 = 5184 */
#define OFF_CC     13504    /* 128 LSTM c-state slice */
#define OFF_GL     13632    /* 8*68 local gates */
#define OFF_HSL    14176    /* 128 h-slice */
#define OFF_H      14304    /* 576 [h|rvec] (P2) */
#define OFF_PACC   14880    /* 1024 float4 = 4096 ; SCR alias */
#define OFF_ITF    18976    /* 224 */
#define OFF_ERASE  19200
#define OFF_WVEC   19264
#define OFF_USAGE  19328
#define OFF_PREC   19456
#define OFF_RW     19584
#define OFF_WW     19712
#define OFF_DOT    19840
#define OFF_MN     19968
#define OFF_BW     20096
#define OFF_FW     20224
#define OFF_SCAN   20352
#define OFF_SS     20480
#define OFF_SCAL   20608    /* 16 */
#define SMEM_FLOATS 20624   /* 82496 B */
#define SMEM_BYTES (SMEM_FLOATS * 4)

#define S_WWSUM 0

__device__ __align__(16) float g_WT[KV * G4];      // WT[c][j]
__device__ __align__(16) float g_bsum[G4];
__device__ __align__(16) float g_hg[2 * Bb * Hh];  // step-parity double buffer
__device__ __align__(16) float g_rvecg[Bb * Wd];
__device__ __align__(16) float g_itfp[Bb * 32 * 200]; // [b][jb][o pad200]
__device__ unsigned g_idone[NP1];   // P1 wg published itfp(t) <=> == t+1
__device__ unsigned g_hdone[NP1];   // P1 wg published h(t)    <=> == t+1
__device__ unsigned g_rdone[Bb];    // P2 published rvec(t)    <=> == t+1

__device__ __forceinline__ float sigf(float v) { return 1.f / (1.f + expf(-v)); }

typedef unsigned long long u64;
union F2U { u64 u; float f[2]; };

__device__ __forceinline__ void cstore2(float* p, float a, float b) {
  F2U v; v.f[0] = a; v.f[1] = b;
  __hip_atomic_store((u64*)p, v.u, __ATOMIC_RELAXED, __HIP_MEMORY_SCOPE_AGENT);
}
__device__ __forceinline__ void cstore(float* p, float v) {
  __hip_atomic_store(p, v, __ATOMIC_RELAXED, __HIP_MEMORY_SCOPE_AGENT);
}
__device__ __forceinline__ F2U cload2(const float* p) {
  F2U v; v.u = __hip_atomic_load((const u64*)p, __ATOMIC_RELAXED, __HIP_MEMORY_SCOPE_AGENT);
  return v;
}
__device__ __forceinline__ float cload1(const float* p) {
  return __hip_atomic_load(p, __ATOMIC_RELAXED, __HIP_MEMORY_SCOPE_AGENT);
}
// RELEASE publish (R5-R7 validated recipe: after __syncthreads or same-wave stores)
__device__ __forceinline__ void publish(unsigned* p, unsigned v) {
  __hip_atomic_store(p, v, __ATOMIC_RELEASE, __HIP_MEMORY_SCOPE_AGENT);
}
__device__ __forceinline__ unsigned cloadu(const unsigned* p) {
  return __hip_atomic_load(p, __ATOMIC_RELAXED, __HIP_MEMORY_SCOPE_AGENT);
}

#define TIN 512
__global__ __launch_bounds__(TIN) void dnc_init(const float* __restrict__ W_ih,
                                                const float* __restrict__ W_hh,
                                                const float* __restrict__ b_ih,
                                                const float* __restrict__ b_hh) {
  __shared__ float tile[64][65];
  const int tid = threadIdx.x;
  int i0 = blockIdx.x * blockDim.x + tid;
  int st = gridDim.x * blockDim.x;
  for (int idx = i0; idx < G4; idx += st) g_bsum[idx] = b_ih[idx] + b_hh[idx];
  for (int idx = i0; idx < 2 * Bb * Hh; idx += st) g_hg[idx] = 0.f;
  for (int idx = i0; idx < Bb * Wd; idx += st) g_rvecg[idx] = 0.f;
  if (i0 < NP1) { g_idone[i0] = 0u; g_hdone[i0] = 0u; }
  if (i0 < Bb) g_rdone[i0] = 0u;

  for (int tileId = blockIdx.x; tileId < 320; tileId += gridDim.x) {
    int tc = tileId >> 5, tj = tileId & 31;
    for (int k = tid; k < 64 * 64; k += TIN) {
      int r = k >> 6, cl = k & 63;
      int j = tj * 64 + r, c = tc * 64 + cl;
      tile[r][cl] = (c < 128) ? W_ih[j * 128 + c] : W_hh[j * 512 + (c - 128)];
    }
    __syncthreads();
    for (int k = tid; k < 64 * 64; k += TIN) {
      int cl = k >> 6, r = k & 63;
      g_WT[(size_t)(tc * 64 + cl) * G4 + tj * 64 + r] = tile[r][cl];
    }
    __syncthreads();
  }
}

__global__ __launch_bounds__(NT) void dnc_main(const float* __restrict__ x,
                                               const float* __restrict__ W_if,
                                               const float* __restrict__ b_if,
                                               const float* __restrict__ W_out,
                                               const float* __restrict__ b_out,
                                               float* __restrict__ out) {
  extern __shared__ float sm[];
  float* SCR = sm + OFF_PACC;
  const int tid = threadIdx.x;
  const int lane = tid & 63;
  const int wg = blockIdx.x;

  if (wg < NP1) {
    // ======================= P1 role: gates GEMV + LSTM + itf partials
    const int jb = wg & 31;     // wg%8==jb%8 -> slice sharers on one XCD
    const int bb = wg >> 5;
    const int b0 = bb * 8;
    if (tid < 128) sm[OFF_CC + tid] = 0.f;
    __syncthreads();

    for (int t = 0; t < Tt; ++t) {
      // wait peers' h(t-1)
      if (tid < 32) {
        while (cloadu(&g_hdone[bb * 32 + tid]) < (unsigned)t) __builtin_amdgcn_s_sleep(1);
      }
      __syncthreads();
      {  // stage h(t-1) into V cols 128..639
        const float* hsrc = g_hg + ((t + 1) & 1) * (Bb * Hh);
#pragma unroll
        for (int k = 0; k < 4; ++k) {
          int p = tid + k * 512;
          int bl = p >> 8, kp = (p & 255) * 2;
          F2U v = cload2(hsrc + (size_t)(b0 + bl) * Hh + kp);
          sm[OFF_V + bl * VST + 128 + kp] = v.f[0];
          sm[OFF_V + bl * VST + 128 + kp + 1] = v.f[1];
        }
      }
      __syncthreads();

      // GEMV: each wave: 72 h/x cols first, then poll rvec, then 8 rvec cols
      {
        const int jl4 = tid & 3, gq = (tid >> 2) & 3, blh = (tid >> 4) & 3, ks = tid >> 6;
        const int fcol = jb * 4 + gq * 128 + jl4;
        const float* va = sm + OFF_V + blh * VST;
        const float* vb = va + 4 * VST;
        float4 a1 = {0.f, 0.f, 0.f, 0.f}, a2 = {0.f, 0.f, 0.f, 0.f};

#define GEMV_RANGE(C0, LEN)                                                    \
        {                                                                      \
          const float4* wp = (const float4*)g_WT + (size_t)(C0) * (G4 / 4) + fcol; \
          _Pragma("unroll 4")                                                  \
          for (int c = 0; c < (LEN); ++c) {                                    \
            float4 w4 = wp[(size_t)c * (G4 / 4)];                              \
            float fa = va[(C0) + c], fb = vb[(C0) + c];                        \
            a1.x += w4.x * fa; a1.y += w4.y * fa; a1.z += w4.z * fa; a1.w += w4.w * fa; \
            a2.x += w4.x * fb; a2.y += w4.y * fb; a2.z += w4.z * fb; a2.w += w4.w * fb; \
          }                                                                    \
        }

        if (ks < 7) {
          GEMV_RANGE(128 + 72 * ks, 72);          // h columns
        } else {
          {  // stage x (wave 7 only consumer)
            int bl = lane >> 3, c0 = (lane & 7) * 8;
            const float4* xs = (const float4*)(x + ((size_t)(b0 + bl) * Tt + t) * Ii + c0);
            float4 xa = xs[0], xb = xs[1];
            float* vd = sm + OFF_V + bl * VST + c0;
            vd[0] = xa.x; vd[1] = xa.y; vd[2] = xa.z; vd[3] = xa.w;
            vd[4] = xb.x; vd[5] = xb.y; vd[6] = xb.z; vd[7] = xb.w;
          }
          GEMV_RANGE(632, 8);                     // last 8 h columns
          GEMV_RANGE(0, 64);                      // x columns
        }
        {  // rvec tail: every wave stages + consumes its own 8 columns
          const int bl = lane >> 3, wv = (lane & 7);
          while (cloadu(&g_rdone[b0 + bl]) < (unsigned)t) __builtin_amdgcn_s_sleep(1);
          float rv = cload1(g_rvecg + (b0 + bl) * Wd + ks * 8 + wv);
          sm[OFF_V + bl * VST + 64 + ks * 8 + wv] = rv;
          GEMV_RANGE(64 + 8 * ks, 8);
        }
        float4* pa = (float4*)(sm + OFF_PACC);
        const int q16 = tid & 15;
        pa[(ks * 8 + blh) * 16 + q16] = a1;
        pa[(ks * 8 + blh + 4) * 16 + q16] = a2;
      }
      __syncthreads();
      if (tid < 128) {  // K-reduce(8) + bias -> GL
        const int bl = tid >> 4, q16 = tid & 15;
        const float4* pa = (const float4*)(sm + OFF_PACC);
        float4 g = {0.f, 0.f, 0.f, 0.f};
#pragma unroll
        for (int ks = 0; ks < 8; ++ks) {
          float4 a = pa[(ks * 8 + bl) * 16 + q16];
          g.x += a.x; g.y += a.y; g.z += a.z; g.w += a.w;
        }
        float4 bs = ((const float4*)g_bsum)[jb * 4 + (q16 >> 2) * 128 + (q16 & 3)];
        g.x += bs.x; g.y += bs.y; g.z += bs.z; g.w += bs.w;
        *(float4*)(sm + OFF_GL + bl * 68 + q16 * 4) = g;
      }
      __syncthreads();
      if (tid < 64) {  // LSTM -> HSL (h store to global deferred off critical path)
        const int bl = tid >> 3, jl0 = (tid & 7) * 2;
        const float* gl = sm + OFF_GL + bl * 68;
#pragma unroll
        for (int e = 0; e < 2; ++e) {
          int jl = jl0 + e;
          float ig = gl[jl], fg = gl[16 + jl], gg = gl[32 + jl], og = gl[48 + jl];
          float co = sm[OFF_CC + bl * 16 + jl];
          float cn = sigf(fg) * co + sigf(ig) * tanhf(gg);
          float hn = sigf(og) * tanhf(cn);
          sm[OFF_CC + bl * 16 + jl] = cn;
          sm[OFF_HSL + bl * 16 + jl] = hn;
        }
      }
      __syncthreads();
      if (tid < IFs) {  // itf partials -> [b][jb][o] coalesced coherent stores
        const int o = tid;
        const float4* wr = (const float4*)(W_if + (size_t)o * Hh + jb * 16);
        float4 w0 = wr[0], w1 = wr[1], w2 = wr[2], w3 = wr[3];
#pragma unroll
        for (int bl = 0; bl < 8; ++bl) {
          const float4* hb = (const float4*)(sm + OFF_HSL + bl * 16);
          float4 h0 = hb[0], h1 = hb[1], h2 = hb[2], h3 = hb[3];
          float s = w0.x * h0.x + w0.y * h0.y + w0.z * h0.z + w0.w * h0.w
                  + w1.x * h1.x + w1.y * h1.y + w1.z * h1.z + w1.w * h1.w
                  + w2.x * h2.x + w2.y * h2.y + w2.z * h2.z + w2.w * h2.w
                  + w3.x * h3.x + w3.y * h3.y + w3.z * h3.z + w3.w * h3.w;
          cstore(g_itfp + ((size_t)(b0 + bl) * 32 + jb) * 200 + o, s);
        }
      }
      __syncthreads();                         // itfp stores drained
      if (tid == 0) publish(&g_idone[wg], (unsigned)(t + 1));
      if (tid < 64) {  // h -> global (off P2's critical path)
        const int bl = tid >> 3, jl0 = (tid & 7) * 2;
        cstore2(g_hg + (t & 1) * (Bb * Hh) + (size_t)(b0 + bl) * Hh + jb * 16 + jl0,
                sm[OFF_HSL + bl * 16 + jl0], sm[OFF_HSL + bl * 16 + jl0 + 1]);
      }
      __syncthreads();
      if (tid == 0) publish(&g_hdone[wg], (unsigned)(t + 1));
    }
  } else {
    // ======================= P2 role: DNC memory for batch b
    const int b = wg - NP1;
    const int grp = b >> 3;
    float regL[32], regLT[32];
#pragma unroll
    for (int k = 0; k < 32; ++k) { regL[k] = 0.f; regLT[k] = 0.f; }
    for (int i = tid; i < Nn * 65; i += NT) sm[OFF_MEM + i] = 0.f;
    if (tid < 128) { sm[OFF_USAGE + tid] = 0.f; sm[OFF_PREC + tid] = 0.f; sm[OFF_RW + tid] = 0.f; }
    __syncthreads();

    for (int t = 0; t < Tt; ++t) {
      if (tid < 32) {
        while (cloadu(&g_idone[grp * 32 + tid]) < (unsigned)(t + 1))
          __builtin_amdgcn_s_sleep(1);
      }
      __syncthreads();
      if (tid < 2 * IFs) {  // gather itf partials: (o, 16-jb half)
        const int o = tid >> 1, hf = tid & 1;
        const float* src = g_itfp + ((size_t)b * 32 + hf * 16) * 200 + o;
        float s = 0.f;
#pragma unroll
        for (int k = 0; k < 16; ++k) s += cload1(src + k * 200);
        s += __shfl_xor(s, 1, 64);
        if (hf == 0) sm[OFF_ITF + o] = s + b_if[o];
      }
      __syncthreads();
      // wave0 mega-block: scalars, ranks, scan, ww, usage
      float kn_r = 0.f, rstr_r = 0.f, rm0_r = 0.f, rm1_r = 0.f, rm2_r = 0.f;
      if (tid < 64) {
        const int li = tid, i0 = 2 * li, i1 = i0 + 1;
        float wgag = sigf(sm[OFF_ITF + 128]) * sigf(sm[OFF_ITF + 129]);
        float rs = sm[OFF_ITF + 194];
        rstr_r = (rs > 20.f) ? rs : log1pf(expf(rs));
        float m0 = sm[OFF_ITF + 195], m1 = sm[OFF_ITF + 196], m2 = sm[OFF_ITF + 197];
        float mx = fmaxf(m0, fmaxf(m1, m2));
        float e0 = expf(m0 - mx), e1 = expf(m1 - mx), e2 = expf(m2 - mx);
        float es = e0 + e1 + e2;
        rm0_r = e0 / es; rm1_r = e1 / es; rm2_r = e2 / es;
        float rk = sm[OFF_ITF + li];
        sm[OFF_ERASE + li] = sigf(rk);
        sm[OFF_WVEC + li] = sm[OFF_ITF + 64 + li];
        float sq = rk * rk;
#pragma unroll
        for (int off = 32; off > 0; off >>= 1) sq += __shfl_xor(sq, off, 64);
        kn_r = sqrtf(sq) + 1e-8f;
        float u0 = sm[OFF_USAGE + i0], u1 = sm[OFF_USAGE + i1];
        int r0 = 0, r1 = 0;
        for (int jc = 0; jc < 32; ++jc) {
          float4 uj4 = *(const float4*)(sm + OFF_USAGE + jc * 4);
#pragma unroll
          for (int e = 0; e < 4; ++e) {
            float uj = (&uj4.x)[e];
            int j = jc * 4 + e;
            r0 += (uj < u0 || (uj == u0 && j < i0)) ? 1 : 0;
            r1 += (uj < u1 || (uj == u1 && j < i1)) ? 1 : 0;
          }
        }
        sm[OFF_SS + r0] = u0;
        sm[OFF_SS + r1] = u1;
        float s0 = sm[OFF_SS + i0], s1 = sm[OFF_SS + i1];
        float p = s0 * s1;
#pragma unroll
        for (int off = 1; off < 64; off <<= 1) {
          float v = __shfl_up(p, off, 64);
          if (li >= off) p *= v;
        }
        float E = __shfl_up(p, 1, 64);
        if (li == 0) E = 1.f;
        sm[OFF_SCAN + i0] = E * s0;
        sm[OFF_SCAN + i1] = E * s0 * s1;
        float ex0 = (r0 > 0) ? sm[OFF_SCAN + r0 - 1] : 1.f;
        float ex1 = (r1 > 0) ? sm[OFF_SCAN + r1 - 1] : 1.f;
        float w0 = wgag * (1.f - u0) * ex0;
        float w1 = wgag * (1.f - u1) * ex1;
        sm[OFF_WW + i0] = w0; sm[OFF_WW + i1] = w1;
        sm[OFF_USAGE + i0] = u0 + (1.f - u0) * w0;
        sm[OFF_USAGE + i1] = u1 + (1.f - u1) * w1;
        float wws = w0 + w1;
#pragma unroll
        for (int off = 32; off > 0; off >>= 1) wws += __shfl_xor(wws, off, 64);
        if (li == 0) sm[OFF_SCAL + S_WWSUM] = wws;
      }
      __syncthreads();
      // pass1: fused mem+dot+mn + register link + bw/fw partials
      {
        const int n = tid & 127, ws = tid >> 7;
        float4 er[4], wv[4], kf[4];
#pragma unroll
        for (int r = 0; r < 4; ++r) {
          er[r] = *(const float4*)(sm + OFF_ERASE + ws * 16 + r * 4);
          wv[r] = *(const float4*)(sm + OFF_WVEC + ws * 16 + r * 4);
          kf[r] = *(const float4*)(sm + OFF_ITF + ws * 16 + r * 4);
        }
        float wwn = sm[OFF_WW + n];
        float dotp = 0.f, mnp = 0.f;
        const int base = OFF_MEM + n * 65 + ws * 16;
#pragma unroll
        for (int q = 0; q < 16; ++q) {
          float m = sm[base + q];
          float ee = (&er[q >> 2].x)[q & 3];
          float vv = (&wv[q >> 2].x)[q & 3];
          float kk = (&kf[q >> 2].x)[q & 3];
          m = m * (1.f - wwn * ee) + wwn * vv;
          sm[base + q] = m;
          dotp += kk * m;
          mnp += m * m;
        }
        SCR[ws * 128 + n] = dotp;
        SCR[512 + ws * 128 + n] = mnp;
        const int m = n, ns = ws;
        float wwm = wwn;
        float prn = sm[OFF_PREC + m];
        float bwp = 0.f, fwp = 0.f;
#pragma unroll
        for (int kq = 0; kq < 8; ++kq) {
          float4 ww4 = *(const float4*)(sm + OFF_WW + ns * 32 + kq * 4);
          float4 pr4 = *(const float4*)(sm + OFF_PREC + ns * 32 + kq * 4);
          float4 rw4 = *(const float4*)(sm + OFF_RW + ns * 32 + kq * 4);
#pragma unroll
          for (int e = 0; e < 4; ++e) {
            int k = kq * 4 + e;
            int nn = ns * 32 + k;
            float wwo = (&ww4.x)[e];
            float pro = (&pr4.x)[e];
            float rwo = (&rw4.x)[e];
            float L = regL[k];
            L = (1.f - wwo - wwm) * L + pro * wwm;
            if (nn == m) L = 0.f;
            regL[k] = L;
            bwp += L * rwo;
            float LT = regLT[k];
            LT = (1.f - wwm - wwo) * LT + prn * wwo;
            if (nn == m) LT = 0.f;
            regLT[k] = LT;
            fwp += LT * rwo;
          }
        }
        SCR[1024 + ns * 128 + m] = bwp;
        SCR[1536 + ns * 128 + m] = fwp;
      }
      __syncthreads();
      {  // pass2: reductions + prec update
        const int n = tid & 127, role = tid >> 7;
        if (role == 0) {
          sm[OFF_DOT + n] = SCR[n] + SCR[128 + n] + SCR[256 + n] + SCR[384 + n];
          float wws = sm[OFF_SCAL + S_WWSUM];
          sm[OFF_PREC + n] = (1.f - wws) * sm[OFF_PREC + n] + sm[OFF_WW + n];
        } else if (role == 1) {
          float v = SCR[512 + n] + SCR[640 + n] + SCR[768 + n] + SCR[896 + n];
          sm[OFF_MN + n] = sqrtf(v) + 1e-8f;
        } else if (role == 2) {
          sm[OFF_BW + n] = SCR[1024 + n] + SCR[1152 + n] + SCR[1280 + n] + SCR[1408 + n];
        } else {
          sm[OFF_FW + n] = SCR[1536 + n] + SCR[1664 + n] + SCR[1792 + n] + SCR[1920 + n];
        }
      }
      __syncthreads();
      if (tid < 64) {  // cosine softmax + combine + normalize
        int i0 = 2 * tid, i1 = i0 + 1;
        float q0 = sm[OFF_DOT + i0] / (kn_r * sm[OFF_MN + i0]) * rstr_r;
        float q1 = sm[OFF_DOT + i1] / (kn_r * sm[OFF_MN + i1]) * rstr_r;
        float mx = fmaxf(q0, q1);
#pragma unroll
        for (int off = 32; off > 0; off >>= 1) mx = fmaxf(mx, __shfl_xor(mx, off, 64));
        float e0 = expf(q0 - mx), e1 = expf(q1 - mx);
        float es = e0 + e1;
#pragma unroll
        for (int off = 32; off > 0; off >>= 1) es += __shfl_xor(es, off, 64);
        float wv0 = rm0_r * sm[OFF_BW + i0] + rm1_r * sm[OFF_FW + i0] + rm2_r * (e0 / es) + 1e-8f;
        float wv1 = rm0_r * sm[OFF_BW + i1] + rm1_r * sm[OFF_FW + i1] + rm2_r * (e1 / es) + 1e-8f;
        float wsum = wv0 + wv1;
#pragma unroll
        for (int off = 32; off > 0; off >>= 1) wsum += __shfl_xor(wsum, off, 64);
        sm[OFF_RW + i0] = wv0 / wsum;
        sm[OFF_RW + i1] = wv1 / wsum;
      }
      __syncthreads();
      {  // rvec partials
        const int w = tid & 63, ns8 = tid >> 6;
        float4 rw4[4];
#pragma unroll
        for (int r = 0; r < 4; ++r)
          rw4[r] = *(const float4*)(sm + OFF_RW + ns8 * 16 + r * 4);
        float p = 0.f;
#pragma unroll
        for (int k = 0; k < 16; ++k)
          p += (&rw4[k >> 2].x)[k & 3] * sm[OFF_MEM + (ns8 * 16 + k) * 65 + w];
        SCR[ns8 * 64 + w] = p;
      }
      __syncthreads();
      if (tid < 64) {  // rvec reduce -> publish immediately (critical-path exit)
        float r = 0.f;
#pragma unroll
        for (int s2 = 0; s2 < 8; ++s2) r += SCR[s2 * 64 + tid];
        sm[OFF_H + 512 + tid] = r;
        cstore(g_rvecg + b * Wd + tid, r);
        if (tid == 0) publish(&g_rdone[b], (unsigned)(t + 1));
      }
      // ---- tail (hidden behind P1's next main GEMV): h gather + out proj
      if (tid < 32) {
        while (cloadu(&g_hdone[grp * 32 + tid]) < (unsigned)(t + 1))
          __builtin_amdgcn_s_sleep(1);
      }
      __syncthreads();
      if (tid < 256) {
        F2U v = cload2(g_hg + (t & 1) * (Bb * Hh) + (size_t)b * Hh + tid * 2);
        sm[OFF_H + tid * 2] = v.f[0];
        sm[OFF_H + tid * 2 + 1] = v.f[1];
      }
      __syncthreads();
      {
        const int o = tid >> 3, seg = tid & 7;
        const float4* wrow = (const float4*)(W_out + (size_t)o * 576) + seg * 18;
        const float4* hb = (const float4*)(sm + OFF_H) + seg * 18;
        float p = 0.f;
#pragma unroll
        for (int q = 0; q < 18; ++q) {
          float4 w = wrow[q]; float4 h = hb[q];
          p += w.x * h.x + w.y * h.y + w.z * h.z + w.w * h.w;
        }
        p += __shfl_down(p, 4, 8);
        p += __shfl_down(p, 2, 8);
        p += __shfl_down(p, 1, 8);
        if (seg == 0) out[((size_t)b * Tt + t) * Oo + o] = p + b_out[o];
      }
      __syncthreads();
    }
  }
}

extern "C" void kernel_launch(void* const* d_in, const int* in_sizes, int n_in,
                              void* d_out, int out_size, void* d_ws, size_t ws_size,
                              hipStream_t stream) {
  (void)in_sizes; (void)n_in; (void)d_ws; (void)ws_size; (void)out_size;
  const float* x    = (const float*)d_in[0];
  const float* W_ih = (const float*)d_in[1];
  const float* W_hh = (const float*)d_in[2];
  const float* b_ih = (const float*)d_in[3];
  const float* b_hh = (const float*)d_in[4];
  const float* W_if = (const float*)d_in[5];
  const float* b_if = (const float*)d_in[6];
  const float* W_out = (const float*)d_in[7];
  const float* b_out = (const float*)d_in[8];
  float* out = (float*)d_out;

  dnc_init<<<320, TIN, 0, stream>>>(W_ih, W_hh, b_ih, b_hh);

  hipFuncSetAttribute((const void*)dnc_main,
                      hipFuncAttributeMaxDynamicSharedMemorySize, SMEM_BYTES);

  void* args[] = {(void*)&x, (void*)&W_if, (void*)&b_if,
                  (void*)&W_out, (void*)&b_out, (void*)&out};
  hipLaunchCooperativeKernel((void*)dnc_main, dim3(NWG), dim3(NT), args,
                             SMEM_BYTES, stream);
}

// Round 9
// 1475.731 us; speedup vs baseline: 4.1277x; 1.1326x over previous
//
#include <hip/hip_runtime.h>
#include <math.h>

// DNC: B=32,T=64,I=64,O=64,H=512,N=128,W=64,IF=198
#define Bb 32
#define Tt 64
#define Ii 64
#define Oo 64
#define Hh 512
#define Nn 128
#define Wd 64
#define IFs 198
#define KV 640
#define G4 2048

#define NP1 128          /* 16 bb-groups x 8 jb-slices */
#define NWG 160          /* + 32 P2 wgs */
#define NT 512
#define VST2 648

// ---- LDS layout (float offsets)
#define OFF_MEM    0        /* 128*65 = 8320 (P2) */
#define OFF_V      8320     /* 2*648 = 1296 (P1, permuted rows) */
#define OFF_CC     9616     /* 128 LSTM c-state [bl*64+l] */
#define OFF_GL     9744     /* 520: gates [bl][gq][64] */
#define OFF_HSL    10264    /* 128 h-slice [bl*64+l] */
#define OFF_H      10392    /* 576 [h|rvec] (P2) */
#define OFF_PACC   10968    /* 8*65 float4 = 2080 ; SCR alias (needs 2048) */
#define OFF_ITF    13048    /* 224 */
#define OFF_ERASE  13272
#define OFF_WVEC   13336
#define OFF_USAGE  13400
#define OFF_PREC   13528
#define OFF_RW     13656
#define OFF_WW     13784
#define OFF_DOT    13912
#define OFF_MN     14040
#define OFF_BW     14168
#define OFF_FW     14296
#define OFF_SCAN   14424
#define OFF_SS     14552
#define OFF_SCAL   14680    /* 16 */
#define SMEM_FLOATS 14696   /* 58784 B */
#define SMEM_BYTES (SMEM_FLOATS * 4)

#define S_WWSUM 0

// WT row permutation: segment ks (160 rows) = [128 h | 16 x | 16 rvec] so each
// wave's K-segment ends with its own 16 rvec columns (short serialized tail).
__device__ __align__(16) float g_WT[KV * G4];      // g_WT[r_perm][j]
__device__ __align__(16) float g_bsum[G4];
__device__ __align__(16) float g_hg[2 * Bb * Hh];  // step-parity double buffer
__device__ __align__(16) float g_rvecg[Bb * Wd];
__device__ __align__(16) float g_itfp[Bb * 8 * 200]; // [b][jb(8)][o pad200]
__device__ unsigned g_hdone[NP1];   // P1 wg published h(t)    <=> == t+1
__device__ unsigned g_idone[NP1];   // P1 wg published itfp(t) <=> == t+1
__device__ unsigned g_rdone[Bb];    // P2 published rvec(t)    <=> == t+1

__device__ __forceinline__ float sigf(float v) { return 1.f / (1.f + expf(-v)); }

typedef unsigned long long u64;
union F2U { u64 u; float f[2]; };

__device__ __forceinline__ void cstore(float* p, float v) {
  __hip_atomic_store(p, v, __ATOMIC_RELAXED, __HIP_MEMORY_SCOPE_AGENT);
}
__device__ __forceinline__ F2U cload2(const float* p) {
  F2U v; v.u = __hip_atomic_load((const u64*)p, __ATOMIC_RELAXED, __HIP_MEMORY_SCOPE_AGENT);
  return v;
}
__device__ __forceinline__ float cload1(const float* p) {
  return __hip_atomic_load(p, __ATOMIC_RELAXED, __HIP_MEMORY_SCOPE_AGENT);
}
// RELEASE publish (R5-R8 validated): after __syncthreads, or after same-wave stores.
__device__ __forceinline__ void publish(unsigned* p, unsigned v) {
  __hip_atomic_store(p, v, __ATOMIC_RELEASE, __HIP_MEMORY_SCOPE_AGENT);
}
__device__ __forceinline__ unsigned cloadu(const unsigned* p) {
  return __hip_atomic_load(p, __ATOMIC_RELAXED, __HIP_MEMORY_SCOPE_AGENT);
}

#define TIN 512
__global__ __launch_bounds__(TIN) void dnc_init(const float* __restrict__ W_ih,
                                                const float* __restrict__ W_hh,
                                                const float* __restrict__ b_ih,
                                                const float* __restrict__ b_hh) {
  __shared__ float tile[64][65];
  const int tid = threadIdx.x;
  int i0 = blockIdx.x * blockDim.x + tid;
  int st = gridDim.x * blockDim.x;
  for (int idx = i0; idx < G4; idx += st) g_bsum[idx] = b_ih[idx] + b_hh[idx];
  for (int idx = i0; idx < 2 * Bb * Hh; idx += st) g_hg[idx] = 0.f;
  for (int idx = i0; idx < Bb * Wd; idx += st) g_rvecg[idx] = 0.f;
  if (i0 < NP1) { g_hdone[i0] = 0u; g_idone[i0] = 0u; }
  if (i0 < Bb) g_rdone[i0] = 0u;

  for (int tileId = blockIdx.x; tileId < 320; tileId += gridDim.x) {
    int tc = tileId >> 5, tj = tileId & 31;
    for (int k = tid; k < 64 * 64; k += TIN) {
      int r = k >> 6, cl = k & 63;
      int j = tj * 64 + r, c = tc * 64 + cl;
      tile[r][cl] = (c < 128) ? W_ih[j * 128 + c] : W_hh[j * 512 + (c - 128)];
    }
    __syncthreads();
    for (int k = tid; k < 64 * 64; k += TIN) {
      int cl = k >> 6, rjj = k & 63;
      int c = tc * 64 + cl;
      int rp;
      if (c < 64) rp = (c >> 4) * 160 + 128 + (c & 15);                 // x
      else if (c < 128) { int cc = c - 64; rp = (cc >> 4) * 160 + 144 + (cc & 15); }  // rvec
      else { int u = c - 128; rp = (u >> 7) * 160 + (u & 127); }        // h
      g_WT[(size_t)rp * G4 + tj * 64 + rjj] = tile[rjj][cl];
    }
    __syncthreads();
  }
}

__global__ __launch_bounds__(NT) void dnc_main(const float* __restrict__ x,
                                               const float* __restrict__ W_if,
                                               const float* __restrict__ b_if,
                                               const float* __restrict__ W_out,
                                               const float* __restrict__ b_out,
                                               float* __restrict__ out) {
  extern __shared__ float sm[];
  float* SCR = sm + OFF_PACC;
  const int tid = threadIdx.x;
  const int wg = blockIdx.x;

  if (wg < NP1) {
    // ======================= P1: gates GEMV + LSTM + itf partials
    // wg = bb*8 + jb -> wg%8 == jb: each XCD's 16 P1 wgs share ONE WT slice.
    const int jb = wg & 7;
    const int bb = wg >> 3;
    const int b0 = bb * 2;
    if (tid < 128) sm[OFF_CC + tid] = 0.f;
    __syncthreads();

    for (int t = 0; t < Tt; ++t) {
      // wait peers' h(t-1) (8 wgs of my bb group)
      if (tid < 8) {
        while (cloadu(&g_hdone[bb * 8 + tid]) < (unsigned)t) __builtin_amdgcn_s_sleep(1);
      }
      __syncthreads();
      {  // stage h(t-1) into permuted V rows (h: r = (u>>7)*160 + (u&127))
        const float* hsrc = g_hg + ((t + 1) & 1) * (Bb * Hh);
        const int bl = tid >> 8, u0 = (tid & 255) * 2;
        F2U v = cload2(hsrc + (size_t)(b0 + bl) * Hh + u0);
        const int rp = (u0 >> 7) * 160 + (u0 & 127);
        sm[OFF_V + bl * VST2 + rp] = v.f[0];
        sm[OFF_V + bl * VST2 + rp + 1] = v.f[1];
        // stage x: r = (i>>4)*160 + 128 + (i&15)
        if (tid < 128) {
          const int bl2 = tid >> 6, i = tid & 63;
          float xv = x[((size_t)(b0 + bl2) * Tt + t) * Ii + i];
          sm[OFF_V + bl2 * VST2 + (i >> 4) * 160 + 128 + (i & 15)] = xv;
        }
      }
      __syncthreads();

      // GEMV: wave w: bl = w&1, ks = w>>1. 144 h/x rows, then poll rvec, 16 rows.
      {
        const int fc = tid & 63, bl = (tid >> 6) & 1, ks = tid >> 7;
        const int lane = tid & 63;
        const int fcol = (fc >> 4) * 128 + jb * 16 + (fc & 15);
        const float* va = sm + OFF_V + bl * VST2 + ks * 160;
        const float4* wp = (const float4*)g_WT + (size_t)(ks * 160) * (G4 / 4) + fcol;
        float4 a = {0.f, 0.f, 0.f, 0.f};
#pragma unroll 8
        for (int r = 0; r < 144; ++r) {
          float4 w4 = wp[(size_t)r * (G4 / 4)];
          float fv = va[r];
          a.x += w4.x * fv; a.y += w4.y * fv; a.z += w4.z * fv; a.w += w4.w * fv;
        }
        // rvec tail: wave-uniform poll, lanes<16 stage own 16 cols (same-wave RAW ok)
        while (cloadu(&g_rdone[b0 + bl]) < (unsigned)t) __builtin_amdgcn_s_sleep(1);
        if (lane < 16) {
          float rv = cload1(g_rvecg + (b0 + bl) * Wd + ks * 16 + lane);
          sm[OFF_V + bl * VST2 + ks * 160 + 144 + lane] = rv;
        }
#pragma unroll
        for (int r = 144; r < 160; ++r) {
          float4 w4 = wp[(size_t)r * (G4 / 4)];
          float fv = va[r];
          a.x += w4.x * fv; a.y += w4.y * fv; a.z += w4.z * fv; a.w += w4.w * fv;
        }
        ((float4*)(sm + OFF_PACC))[(ks * 2 + bl) * 65 + fc] = a;
      }
      __syncthreads();
      if (tid < 128) {  // K-reduce(4) + bias -> GL[bl][gq][64]
        const int bl = tid >> 6, fc = tid & 63;
        const float4* pa = (const float4*)(sm + OFF_PACC);
        float4 g = {0.f, 0.f, 0.f, 0.f};
#pragma unroll
        for (int ks = 0; ks < 4; ++ks) {
          float4 a = pa[(ks * 2 + bl) * 65 + fc];
          g.x += a.x; g.y += a.y; g.z += a.z; g.w += a.w;
        }
        const int gq = fc >> 4, m = fc & 15;
        float4 bs = ((const float4*)g_bsum)[gq * 128 + jb * 16 + m];
        g.x += bs.x; g.y += bs.y; g.z += bs.z; g.w += bs.w;
        *(float4*)(sm + OFF_GL + bl * 256 + gq * 64 + m * 4) = g;
      }
      __syncthreads();
      if (tid < 128) {  // LSTM for 64 h-units x 2 batches (gates stay on-CU)
        const int bl = tid >> 6, l = tid & 63;
        const float* gl = sm + OFF_GL + bl * 256;
        float ig = gl[l], fg = gl[64 + l], gg = gl[128 + l], og = gl[192 + l];
        float co = sm[OFF_CC + bl * 64 + l];
        float cn = sigf(fg) * co + sigf(ig) * tanhf(gg);
        float hn = sigf(og) * tanhf(cn);
        sm[OFF_CC + bl * 64 + l] = cn;
        sm[OFF_HSL + bl * 64 + l] = hn;
        cstore(g_hg + (t & 1) * (Bb * Hh) + (size_t)(b0 + bl) * Hh + jb * 64 + l, hn);
      }
      __syncthreads();                       // h stores drained (all waves)
      if (tid == 0) publish(&g_hdone[wg], (unsigned)(t + 1));
      if (tid < 2 * IFs) {  // itf partials over my 64-unit slice, both batches
        const int o = tid >> 1, bl = tid & 1;
        const float4* wr = (const float4*)(W_if + (size_t)o * Hh + jb * 64);
        const float4* h4 = (const float4*)(sm + OFF_HSL + bl * 64);
        float acc = 0.f;
#pragma unroll 8
        for (int c4 = 0; c4 < 16; ++c4) {
          float4 w = wr[c4]; float4 h = h4[c4];
          acc += w.x * h.x + w.y * h.y + w.z * h.z + w.w * h.w;
        }
        cstore(g_itfp + ((size_t)(b0 + bl) * 8 + jb) * 200 + o, acc);
      }
      __syncthreads();                       // itfp stores drained
      if (tid == 0) publish(&g_idone[wg], (unsigned)(t + 1));
    }
  } else {
    // ======================= P2: DNC memory for batch b
    const int b = wg - NP1;
    float regL[32], regLT[32];
#pragma unroll
    for (int k = 0; k < 32; ++k) { regL[k] = 0.f; regLT[k] = 0.f; }
    for (int i = tid; i < Nn * 65; i += NT) sm[OFF_MEM + i] = 0.f;
    if (tid < 128) { sm[OFF_USAGE + tid] = 0.f; sm[OFF_PREC + tid] = 0.f; sm[OFF_RW + tid] = 0.f; }
    __syncthreads();

    for (int t = 0; t < Tt; ++t) {
      if (tid < 8) {  // itf(t) of my batch comes from the 8 wgs of bb = b>>1
        while (cloadu(&g_idone[(b >> 1) * 8 + tid]) < (unsigned)(t + 1))
          __builtin_amdgcn_s_sleep(1);
      }
      __syncthreads();
      if (tid < 2 * IFs) {  // gather itf partials: (o, 4-slice half)
        const int o = tid >> 1, hf = tid & 1;
        const float* src = g_itfp + ((size_t)b * 8 + hf * 4) * 200 + o;
        float s = cload1(src) + cload1(src + 200) + cload1(src + 400) + cload1(src + 600);
        s += __shfl_xor(s, 1, 64);
        if (hf == 0) sm[OFF_ITF + o] = s + b_if[o];
      }
      __syncthreads();
      // wave0 mega-block: scalars, ranks, scan, ww, usage
      float kn_r = 0.f, rstr_r = 0.f, rm0_r = 0.f, rm1_r = 0.f, rm2_r = 0.f;
      if (tid < 64) {
        const int li = tid, i0 = 2 * li, i1 = i0 + 1;
        float wgag = sigf(sm[OFF_ITF + 128]) * sigf(sm[OFF_ITF + 129]);
        float rs = sm[OFF_ITF + 194];
        rstr_r = (rs > 20.f) ? rs : log1pf(expf(rs));
        float m0 = sm[OFF_ITF + 195], m1 = sm[OFF_ITF + 196], m2 = sm[OFF_ITF + 197];
        float mx = fmaxf(m0, fmaxf(m1, m2));
        float e0 = expf(m0 - mx), e1 = expf(m1 - mx), e2 = expf(m2 - mx);
        float es = e0 + e1 + e2;
        rm0_r = e0 / es; rm1_r = e1 / es; rm2_r = e2 / es;
        float rk = sm[OFF_ITF + li];
        sm[OFF_ERASE + li] = sigf(rk);
        sm[OFF_WVEC + li] = sm[OFF_ITF + 64 + li];
        float sq = rk * rk;
#pragma unroll
        for (int off = 32; off > 0; off >>= 1) sq += __shfl_xor(sq, off, 64);
        kn_r = sqrtf(sq) + 1e-8f;
        float u0 = sm[OFF_USAGE + i0], u1 = sm[OFF_USAGE + i1];
        int r0 = 0, r1 = 0;
        for (int jc = 0; jc < 32; ++jc) {
          float4 uj4 = *(const float4*)(sm + OFF_USAGE + jc * 4);
#pragma unroll
          for (int e = 0; e < 4; ++e) {
            float uj = (&uj4.x)[e];
            int j = jc * 4 + e;
            r0 += (uj < u0 || (uj == u0 && j < i0)) ? 1 : 0;
            r1 += (uj < u1 || (uj == u1 && j < i1)) ? 1 : 0;
          }
        }
        sm[OFF_SS + r0] = u0;
        sm[OFF_SS + r1] = u1;
        float s0 = sm[OFF_SS + i0], s1 = sm[OFF_SS + i1];
        float p = s0 * s1;
#pragma unroll
        for (int off = 1; off < 64; off <<= 1) {
          float v = __shfl_up(p, off, 64);
          if (li >= off) p *= v;
        }
        float E = __shfl_up(p, 1, 64);
        if (li == 0) E = 1.f;
        sm[OFF_SCAN + i0] = E * s0;
        sm[OFF_SCAN + i1] = E * s0 * s1;
        float ex0 = (r0 > 0) ? sm[OFF_SCAN + r0 - 1] : 1.f;
        float ex1 = (r1 > 0) ? sm[OFF_SCAN + r1 - 1] : 1.f;
        float w0 = wgag * (1.f - u0) * ex0;
        float w1 = wgag * (1.f - u1) * ex1;
        sm[OFF_WW + i0] = w0; sm[OFF_WW + i1] = w1;
        sm[OFF_USAGE + i0] = u0 + (1.f - u0) * w0;
        sm[OFF_USAGE + i1] = u1 + (1.f - u1) * w1;
        float wws = w0 + w1;
#pragma unroll
        for (int off = 32; off > 0; off >>= 1) wws += __shfl_xor(wws, off, 64);
        if (li == 0) sm[OFF_SCAL + S_WWSUM] = wws;
      }
      __syncthreads();
      // pass1: fused mem+dot+mn + register link + bw/fw partials
      {
        const int n = tid & 127, ws = tid >> 7;
        float4 er[4], wv[4], kf[4];
#pragma unroll
        for (int r = 0; r < 4; ++r) {
          er[r] = *(const float4*)(sm + OFF_ERASE + ws * 16 + r * 4);
          wv[r] = *(const float4*)(sm + OFF_WVEC + ws * 16 + r * 4);
          kf[r] = *(const float4*)(sm + OFF_ITF + ws * 16 + r * 4);
        }
        float wwn = sm[OFF_WW + n];
        float dotp = 0.f, mnp = 0.f;
        const int base = OFF_MEM + n * 65 + ws * 16;
#pragma unroll
        for (int q = 0; q < 16; ++q) {
          float m = sm[base + q];
          float ee = (&er[q >> 2].x)[q & 3];
          float vv = (&wv[q >> 2].x)[q & 3];
          float kk = (&kf[q >> 2].x)[q & 3];
          m = m * (1.f - wwn * ee) + wwn * vv;
          sm[base + q] = m;
          dotp += kk * m;
          mnp += m * m;
        }
        SCR[ws * 128 + n] = dotp;
        SCR[512 + ws * 128 + n] = mnp;
        const int m = n, ns = ws;
        float wwm = wwn;
        float prn = sm[OFF_PREC + m];
        float bwp = 0.f, fwp = 0.f;
#pragma unroll
        for (int kq = 0; kq < 8; ++kq) {
          float4 ww4 = *(const float4*)(sm + OFF_WW + ns * 32 + kq * 4);
          float4 pr4 = *(const float4*)(sm + OFF_PREC + ns * 32 + kq * 4);
          float4 rw4 = *(const float4*)(sm + OFF_RW + ns * 32 + kq * 4);
#pragma unroll
          for (int e = 0; e < 4; ++e) {
            int k = kq * 4 + e;
            int nn = ns * 32 + k;
            float wwo = (&ww4.x)[e];
            float pro = (&pr4.x)[e];
            float rwo = (&rw4.x)[e];
            float L = regL[k];
            L = (1.f - wwo - wwm) * L + pro * wwm;
            if (nn == m) L = 0.f;
            regL[k] = L;
            bwp += L * rwo;
            float LT = regLT[k];
            LT = (1.f - wwm - wwo) * LT + prn * wwo;
            if (nn == m) LT = 0.f;
            regLT[k] = LT;
            fwp += LT * rwo;
          }
        }
        SCR[1024 + ns * 128 + m] = bwp;
        SCR[1536 + ns * 128 + m] = fwp;
      }
      __syncthreads();
      {  // pass2: reductions + prec update
        const int n = tid & 127, role = tid >> 7;
        if (role == 0) {
          sm[OFF_DOT + n] = SCR[n] + SCR[128 + n] + SCR[256 + n] + SCR[384 + n];
          float wws = sm[OFF_SCAL + S_WWSUM];
          sm[OFF_PREC + n] = (1.f - wws) * sm[OFF_PREC + n] + sm[OFF_WW + n];
        } else if (role == 1) {
          float v = SCR[512 + n] + SCR[640 + n] + SCR[768 + n] + SCR[896 + n];
          sm[OFF_MN + n] = sqrtf(v) + 1e-8f;
        } else if (role == 2) {
          sm[OFF_BW + n] = SCR[1024 + n] + SCR[1152 + n] + SCR[1280 + n] + SCR[1408 + n];
        } else {
          sm[OFF_FW + n] = SCR[1536 + n] + SCR[1664 + n] + SCR[1792 + n] + SCR[1920 + n];
        }
      }
      __syncthreads();
      if (tid < 64) {  // cosine softmax + combine + normalize
        int i0 = 2 * tid, i1 = i0 + 1;
        float q0 = sm[OFF_DOT + i0] / (kn_r * sm[OFF_MN + i0]) * rstr_r;
        float q1 = sm[OFF_DOT + i1] / (kn_r * sm[OFF_MN + i1]) * rstr_r;
        float mx = fmaxf(q0, q1);
#pragma unroll
        for (int off = 32; off > 0; off >>= 1) mx = fmaxf(mx, __shfl_xor(mx, off, 64));
        float e0 = expf(q0 - mx), e1 = expf(q1 - mx);
        float es = e0 + e1;
#pragma unroll
        for (int off = 32; off > 0; off >>= 1) es += __shfl_xor(es, off, 64);
        float wv0 = rm0_r * sm[OFF_BW + i0] + rm1_r * sm[OFF_FW + i0] + rm2_r * (e0 / es) + 1e-8f;
        float wv1 = rm0_r * sm[OFF_BW + i1] + rm1_r * sm[OFF_FW + i1] + rm2_r * (e1 / es) + 1e-8f;
        float wsum = wv0 + wv1;
#pragma unroll
        for (int off = 32; off > 0; off >>= 1) wsum += __shfl_xor(wsum, off, 64);
        sm[OFF_RW + i0] = wv0 / wsum;
        sm[OFF_RW + i1] = wv1 / wsum;
      }
      __syncthreads();
      {  // rvec partials
        const int w = tid & 63, ns8 = tid >> 6;
        float4 rw4[4];
#pragma unroll
        for (int r = 0; r < 4; ++r)
          rw4[r] = *(const float4*)(sm + OFF_RW + ns8 * 16 + r * 4);
        float p = 0.f;
#pragma unroll
        for (int k = 0; k < 16; ++k)
          p += (&rw4[k >> 2].x)[k & 3] * sm[OFF_MEM + (ns8 * 16 + k) * 65 + w];
        SCR[ns8 * 64 + w] = p;
      }
      __syncthreads();
      if (tid < 64) {  // rvec reduce -> publish immediately (critical-path exit)
        float r = 0.f;
#pragma unroll
        for (int s2 = 0; s2 < 8; ++s2) r += SCR[s2 * 64 + tid];
        sm[OFF_H + 512 + tid] = r;
        cstore(g_rvecg + b * Wd + tid, r);
        if (tid == 0) publish(&g_rdone[b], (unsigned)(t + 1));
      }
      __syncthreads();
      // ---- tail (hidden behind P1's next main GEMV): h gather + out proj
      // (h(t) visibility implied: hdone published before idone by same wgs)
      if (tid < 256) {
        F2U v = cload2(g_hg + (t & 1) * (Bb * Hh) + (size_t)b * Hh + tid * 2);
        sm[OFF_H + tid * 2] = v.f[0];
        sm[OFF_H + tid * 2 + 1] = v.f[1];
      }
      __syncthreads();
      {
        const int o = tid >> 3, seg = tid & 7;
        const float4* wrow = (const float4*)(W_out + (size_t)o * 576) + seg * 18;
        const float4* hb = (const float4*)(sm + OFF_H) + seg * 18;
        float p = 0.f;
#pragma unroll
        for (int q = 0; q < 18; ++q) {
          float4 w = wrow[q]; float4 h = hb[q];
          p += w.x * h.x + w.y * h.y + w.z * h.z + w.w * h.w;
        }
        p += __shfl_down(p, 4, 8);
        p += __shfl_down(p, 2, 8);
        p += __shfl_down(p, 1, 8);
        if (seg == 0) out[((size_t)b * Tt + t) * Oo + o] = p + b_out[o];
      }
      __syncthreads();
    }
  }
}

extern "C" void kernel_launch(void* const* d_in, const int* in_sizes, int n_in,
                              void* d_out, int out_size, void* d_ws, size_t ws_size,
                              hipStream_t stream) {
  (void)in_sizes; (void)n_in; (void)d_ws; (void)ws_size; (void)out_size;
  const float* x    = (const float*)d_in[0];
  const float* W_ih = (const float*)d_in[1];
  const float* W_hh = (const float*)d_in[2];
  const float* b_ih = (const float*)d_in[3];
  const float* b_hh = (const float*)d_in[4];
  const float* W_if = (const float*)d_in[5];
  const float* b_if = (const float*)d_in[6];
  const float* W_out = (const float*)d_in[7];
  const float* b_out = (const float*)d_in[8];
  float* out = (float*)d_out;

  dnc_init<<<320, TIN, 0, stream>>>(W_ih, W_hh, b_ih, b_hh);

  hipFuncSetAttribute((const void*)dnc_main,
                      hipFuncAttributeMaxDynamicSharedMemorySize, SMEM_BYTES);

  void* args[] = {(void*)&x, (void*)&W_if, (void*)&b_if,
                  (void*)&W_out, (void*)&b_out, (void*)&out};
  hipLaunchCooperativeKernel((void*)dnc_main, dim3(NWG), dim3(NT), args,
                             SMEM_BYTES, stream);
}

// Round 10
// 1157.105 us; speedup vs baseline: 5.2643x; 1.2754x over previous
//
#include <hip/hip_runtime.h>
#include <math.h>

// DNC: B=32,T=64,I=64,O=64,H=512,N=128,W=64,IF=198
#define Bb 32
#define Tt 64
#define Ii 64
#define Oo 64
#define Hh 512
#define Nn 128
#define Wd 64
#define IFs 198
#define KV 640
#define G4 2048

#define NP1 128          /* 16 bb-groups x 8 jb-slices */
#define NWG 160          /* + 32 P2 wgs */
#define NT 512
#define VST2 648

// ---- LDS layout (float offsets). P1 and P2 blocks OVERLAP (role is fixed
// per wg, regions never co-used).
// P2 block:
#define P2_MEM    0        /* 128*65 = 8320 */
#define P2_H      8320     /* 576 [h|rvec] */
#define P2_SCR    8896     /* 2048 */
#define P2_ITF    10944    /* 224 */
#define P2_ERASE  11168
#define P2_WVEC   11232
#define P2_USAGE  11296
#define P2_PREC   11424
#define P2_RW     11552
#define P2_WW     11680
#define P2_DOT    11808
#define P2_MN     11936
#define P2_BW     12064
#define P2_FW     12192
#define P2_SCAN   12320
#define P2_SS     12448
#define P2_SCAL   12576    /* 16 */
#define P2_BIF    12592    /* 224 */
// P1 block:
#define P1_WIF    0        /* 198*64 = 12672 (W_if slice, preloaded) */
#define P1_BS     12672    /* 64 float4 = 256 (bias slice) */
#define P1_V      12928    /* 2*648 = 1296 (permuted rows) */
#define P1_CC     14224    /* 128 */
#define P1_GL     14352    /* 520 */
#define P1_HSL    14872    /* 128 */
#define P1_PACC   15000    /* 8*65 float4 = 2080 */
#define SMEM_FLOATS 17080  /* 68320 B */
#define SMEM_BYTES (SMEM_FLOATS * 4)

#define S_WWSUM 0

// WT row permutation: segment ks (160 rows) = [128 h | 16 x | 16 rvec].
__device__ __align__(16) float g_WT[KV * G4];
__device__ __align__(16) float g_bsum[G4];
typedef unsigned long long u64;
// Tagged handoffs: u64 = (step_tag << 32) | float_bits. Relaxed agent atomics,
// ZERO fences/flags: data self-validates, one MALL transaction per element.
__device__ u64 g_h64[2 * Bb * Hh];   // h, step-parity double buffer, tag t+1
__device__ u64 g_rv64[Bb * Wd];      // rvec(t) tag t+1
__device__ u64 g_if64[Bb * 8 * 200]; // itf partials [b][jb(8)][o pad200] tag t+1

__device__ __forceinline__ float sigf(float v) { return 1.f / (1.f + expf(-v)); }

__device__ __forceinline__ u64 ldrelax(const u64* p) {
  return __hip_atomic_load(p, __ATOMIC_RELAXED, __HIP_MEMORY_SCOPE_AGENT);
}
__device__ __forceinline__ void tstore(u64* p, unsigned tag, float v) {
  u64 val = ((u64)tag << 32) | (u64)__float_as_uint(v);
  __hip_atomic_store(p, val, __ATOMIC_RELAXED, __HIP_MEMORY_SCOPE_AGENT);
}
__device__ __forceinline__ float fixwait(const u64* p, u64 v, unsigned tag) {
  while ((unsigned)(v >> 32) != tag) {
    __builtin_amdgcn_s_sleep(1);
    v = ldrelax(p);
  }
  return __uint_as_float((unsigned)(v & 0xffffffffu));
}

#define TIN 512
__global__ __launch_bounds__(TIN) void dnc_init(const float* __restrict__ W_ih,
                                                const float* __restrict__ W_hh,
                                                const float* __restrict__ b_ih,
                                                const float* __restrict__ b_hh) {
  __shared__ float tile[64][65];
  const int tid = threadIdx.x;
  int i0 = blockIdx.x * blockDim.x + tid;
  int st = gridDim.x * blockDim.x;
  for (int idx = i0; idx < G4; idx += st) g_bsum[idx] = b_ih[idx] + b_hh[idx];
  for (int idx = i0; idx < 2 * Bb * Hh; idx += st) g_h64[idx] = 0ull;   // tag0,val0
  for (int idx = i0; idx < Bb * Wd; idx += st) g_rv64[idx] = 0ull;
  for (int idx = i0; idx < Bb * 8 * 200; idx += st) g_if64[idx] = 0ull;

  for (int tileId = blockIdx.x; tileId < 320; tileId += gridDim.x) {
    int tc = tileId >> 5, tj = tileId & 31;
    for (int k = tid; k < 64 * 64; k += TIN) {
      int r = k >> 6, cl = k & 63;
      int j = tj * 64 + r, c = tc * 64 + cl;
      tile[r][cl] = (c < 128) ? W_ih[j * 128 + c] : W_hh[j * 512 + (c - 128)];
    }
    __syncthreads();
    for (int k = tid; k < 64 * 64; k += TIN) {
      int cl = k >> 6, rjj = k & 63;
      int c = tc * 64 + cl;
      int rp;
      if (c < 64) rp = (c >> 4) * 160 + 128 + (c & 15);                 // x
      else if (c < 128) { int cc = c - 64; rp = (cc >> 4) * 160 + 144 + (cc & 15); }  // rvec
      else { int u = c - 128; rp = (u >> 7) * 160 + (u & 127); }        // h
      g_WT[(size_t)rp * G4 + tj * 64 + rjj] = tile[rjj][cl];
    }
    __syncthreads();
  }
}

__global__ __launch_bounds__(NT) void dnc_main(const float* __restrict__ x,
                                               const float* __restrict__ W_if,
                                               const float* __restrict__ b_if,
                                               const float* __restrict__ W_out,
                                               const float* __restrict__ b_out,
                                               float* __restrict__ out) {
  extern __shared__ float sm[];
  const int tid = threadIdx.x;
  const int wg = blockIdx.x;

  if (wg < NP1) {
    // ======================= P1: gates GEMV + LSTM + itf partials
    // wg = bb*8 + jb -> wg%8 == jb: each XCD's 16 P1 wgs share ONE WT slice.
    const int jb = wg & 7;
    const int bb = wg >> 3;
    const int b0 = bb * 2;
    // preload W_if slice (50.7KB) + bias slice into LDS (itf tail leaves L2)
    for (int i = tid; i < IFs * 64; i += NT) {
      int o = i >> 6, c = i & 63;
      sm[P1_WIF + i] = W_if[(size_t)o * Hh + jb * 64 + c];
    }
    if (tid < 64) {
      int gq = tid >> 4, m = tid & 15;
      ((float4*)(sm + P1_BS))[tid] = ((const float4*)g_bsum)[gq * 128 + jb * 16 + m];
    }
    if (tid < 128) sm[P1_CC + tid] = 0.f;
    __syncthreads();

    for (int t = 0; t < Tt; ++t) {
      {  // stage h(t-1) (tagged: data+sync in one transaction per element)
        const u64* hsrc = g_h64 + (size_t)((t + 1) & 1) * (Bb * Hh);
        const int u = tid;   // 0..511
        const u64* a0 = hsrc + (size_t)b0 * Hh + u;
        const u64* a1 = hsrc + (size_t)(b0 + 1) * Hh + u;
        u64 v0 = ldrelax(a0), v1 = ldrelax(a1);     // both issued before fixups
        float h0 = fixwait(a0, v0, (unsigned)t);
        float h1 = fixwait(a1, v1, (unsigned)t);
        const int rp = (u >> 7) * 160 + (u & 127);
        sm[P1_V + rp] = h0;
        sm[P1_V + VST2 + rp] = h1;
        if (tid < 128) {  // stage x
          const int bl2 = tid >> 6, i = tid & 63;
          float xv = x[((size_t)(b0 + bl2) * Tt + t) * Ii + i];
          sm[P1_V + bl2 * VST2 + (i >> 4) * 160 + 128 + (i & 15)] = xv;
        }
      }
      __syncthreads();

      // GEMV: wave w: bl = w&1, ks = w>>1. 144 h/x rows, then tagged rvec, 16 rows.
      {
        const int fc = tid & 63, bl = (tid >> 6) & 1, ks = tid >> 7;
        const int lane = tid & 63;
        const int fcol = (fc >> 4) * 128 + jb * 16 + (fc & 15);
        const float* va = sm + P1_V + bl * VST2 + ks * 160;
        const float4* wp = (const float4*)g_WT + (size_t)(ks * 160) * (G4 / 4) + fcol;
        float4 a = {0.f, 0.f, 0.f, 0.f};
#pragma unroll 8
        for (int r = 0; r < 144; ++r) {
          float4 w4 = wp[(size_t)r * (G4 / 4)];
          float fv = va[r];
          a.x += w4.x * fv; a.y += w4.y * fv; a.z += w4.z * fv; a.w += w4.w * fv;
        }
        if (lane < 16) {  // tagged rvec: one MALL transaction, self-validating
          const u64* rp = g_rv64 + (size_t)(b0 + bl) * Wd + ks * 16 + lane;
          float rv = fixwait(rp, ldrelax(rp), (unsigned)t);
          sm[P1_V + bl * VST2 + ks * 160 + 144 + lane] = rv;
        }
#pragma unroll
        for (int r = 144; r < 160; ++r) {
          float4 w4 = wp[(size_t)r * (G4 / 4)];
          float fv = va[r];
          a.x += w4.x * fv; a.y += w4.y * fv; a.z += w4.z * fv; a.w += w4.w * fv;
        }
        ((float4*)(sm + P1_PACC))[(ks * 2 + bl) * 65 + fc] = a;
      }
      __syncthreads();
      if (tid < 128) {  // K-reduce(4) + bias(LDS) -> GL
        const int bl = tid >> 6, fc = tid & 63;
        const float4* pa = (const float4*)(sm + P1_PACC);
        float4 g = {0.f, 0.f, 0.f, 0.f};
#pragma unroll
        for (int ks = 0; ks < 4; ++ks) {
          float4 a = pa[(ks * 2 + bl) * 65 + fc];
          g.x += a.x; g.y += a.y; g.z += a.z; g.w += a.w;
        }
        float4 bs = ((const float4*)(sm + P1_BS))[fc];
        g.x += bs.x; g.y += bs.y; g.z += bs.z; g.w += bs.w;
        const int gq = fc >> 4, m = fc & 15;
        *(float4*)(sm + P1_GL + bl * 256 + gq * 64 + m * 4) = g;
      }
      __syncthreads();
      if (tid < 128) {  // LSTM; h published as tagged u64 (no fence, no drain)
        const int bl = tid >> 6, l = tid & 63;
        const float* gl = sm + P1_GL + bl * 256;
        float ig = gl[l], fg = gl[64 + l], gg = gl[128 + l], og = gl[192 + l];
        float co = sm[P1_CC + bl * 64 + l];
        float cn = sigf(fg) * co + sigf(ig) * tanhf(gg);
        float hn = sigf(og) * tanhf(cn);
        sm[P1_CC + bl * 64 + l] = cn;
        sm[P1_HSL + bl * 64 + l] = hn;
        tstore(g_h64 + (size_t)(t & 1) * (Bb * Hh) + (size_t)(b0 + bl) * Hh + jb * 64 + l,
               (unsigned)(t + 1), hn);
      }
      __syncthreads();
      if (tid < 2 * IFs) {  // itf partials from LDS W_if -> tagged stores; no barrier after
        const int o = tid >> 1, bl = tid & 1;
        const float4* wr = (const float4*)(sm + P1_WIF + o * 64);
        const float4* h4 = (const float4*)(sm + P1_HSL + bl * 64);
        float acc = 0.f;
#pragma unroll 8
        for (int c4 = 0; c4 < 16; ++c4) {
          float4 w = wr[c4]; float4 h = h4[c4];
          acc += w.x * h.x + w.y * h.y + w.z * h.z + w.w * h.w;
        }
        tstore(g_if64 + ((size_t)(b0 + bl) * 8 + jb) * 200 + o, (unsigned)(t + 1), acc);
      }
      // next iteration's staging writes P1_V (disjoint from WIF/HSL) -> safe
    }
  } else {
    // ======================= P2: DNC memory for batch b
    const int b = wg - NP1;
    float* SCR = sm + P2_SCR;
    float regL[32], regLT[32];
#pragma unroll
    for (int k = 0; k < 32; ++k) { regL[k] = 0.f; regLT[k] = 0.f; }
    for (int i = tid; i < Nn * 65; i += NT) sm[P2_MEM + i] = 0.f;
    if (tid < 128) { sm[P2_USAGE + tid] = 0.f; sm[P2_PREC + tid] = 0.f; sm[P2_RW + tid] = 0.f; }
    if (tid < IFs) sm[P2_BIF + tid] = b_if[tid];
    __syncthreads();

    for (int t = 0; t < Tt; ++t) {
      if (tid < 2 * IFs) {  // tagged itf gather: 4 loads issued, then fix-ups
        const int o = tid >> 1, hf = tid & 1;
        const u64* src = g_if64 + ((size_t)b * 8 + hf * 4) * 200 + o;
        u64 a0 = ldrelax(src), a1 = ldrelax(src + 200),
            a2 = ldrelax(src + 400), a3 = ldrelax(src + 600);
        float s = fixwait(src, a0, (unsigned)(t + 1))
                + fixwait(src + 200, a1, (unsigned)(t + 1))
                + fixwait(src + 400, a2, (unsigned)(t + 1))
                + fixwait(src + 600, a3, (unsigned)(t + 1));
        s += __shfl_xor(s, 1, 64);
        if (hf == 0) sm[P2_ITF + o] = s + sm[P2_BIF + o];
      }
      __syncthreads();
      // wave0 mega-block: scalars, ranks, scan, ww, usage
      float kn_r = 0.f, rstr_r = 0.f, rm0_r = 0.f, rm1_r = 0.f, rm2_r = 0.f;
      if (tid < 64) {
        const int li = tid, i0 = 2 * li, i1 = i0 + 1;
        float wgag = sigf(sm[P2_ITF + 128]) * sigf(sm[P2_ITF + 129]);
        float rs = sm[P2_ITF + 194];
        rstr_r = (rs > 20.f) ? rs : log1pf(expf(rs));
        float m0 = sm[P2_ITF + 195], m1 = sm[P2_ITF + 196], m2 = sm[P2_ITF + 197];
        float mx = fmaxf(m0, fmaxf(m1, m2));
        float e0 = expf(m0 - mx), e1 = expf(m1 - mx), e2 = expf(m2 - mx);
        float es = e0 + e1 + e2;
        rm0_r = e0 / es; rm1_r = e1 / es; rm2_r = e2 / es;
        float rk = sm[P2_ITF + li];
        sm[P2_ERASE + li] = sigf(rk);
        sm[P2_WVEC + li] = sm[P2_ITF + 64 + li];
        float sq = rk * rk;
#pragma unroll
        for (int off = 32; off > 0; off >>= 1) sq += __shfl_xor(sq, off, 64);
        kn_r = sqrtf(sq) + 1e-8f;
        float u0 = sm[P2_USAGE + i0], u1 = sm[P2_USAGE + i1];
        int r0 = 0, r1 = 0;
        for (int jc = 0; jc < 32; ++jc) {
          float4 uj4 = *(const float4*)(sm + P2_USAGE + jc * 4);
#pragma unroll
          for (int e = 0; e < 4; ++e) {
            float uj = (&uj4.x)[e];
            int j = jc * 4 + e;
            r0 += (uj < u0 || (uj == u0 && j < i0)) ? 1 : 0;
            r1 += (uj < u1 || (uj == u1 && j < i1)) ? 1 : 0;
          }
        }
        sm[P2_SS + r0] = u0;
        sm[P2_SS + r1] = u1;
        float s0 = sm[P2_SS + i0], s1 = sm[P2_SS + i1];
        float p = s0 * s1;
#pragma unroll
        for (int off = 1; off < 64; off <<= 1) {
          float v = __shfl_up(p, off, 64);
          if (li >= off) p *= v;
        }
        float E = __shfl_up(p, 1, 64);
        if (li == 0) E = 1.f;
        sm[P2_SCAN + i0] = E * s0;
        sm[P2_SCAN + i1] = E * s0 * s1;
        float ex0 = (r0 > 0) ? sm[P2_SCAN + r0 - 1] : 1.f;
        float ex1 = (r1 > 0) ? sm[P2_SCAN + r1 - 1] : 1.f;
        float w0 = wgag * (1.f - u0) * ex0;
        float w1 = wgag * (1.f - u1) * ex1;
        sm[P2_WW + i0] = w0; sm[P2_WW + i1] = w1;
        sm[P2_USAGE + i0] = u0 + (1.f - u0) * w0;
        sm[P2_USAGE + i1] = u1 + (1.f - u1) * w1;
        float wws = w0 + w1;
#pragma unroll
        for (int off = 32; off > 0; off >>= 1) wws += __shfl_xor(wws, off, 64);
        if (li == 0) sm[P2_SCAL + S_WWSUM] = wws;
      }
      __syncthreads();
      // pass1: fused mem+dot+mn + register link + bw/fw partials
      {
        const int n = tid & 127, ws = tid >> 7;
        float4 er[4], wv[4], kf[4];
#pragma unroll
        for (int r = 0; r < 4; ++r) {
          er[r] = *(const float4*)(sm + P2_ERASE + ws * 16 + r * 4);
          wv[r] = *(const float4*)(sm + P2_WVEC + ws * 16 + r * 4);
          kf[r] = *(const float4*)(sm + P2_ITF + ws * 16 + r * 4);
        }
        float wwn = sm[P2_WW + n];
        float dotp = 0.f, mnp = 0.f;
        const int base = P2_MEM + n * 65 + ws * 16;
#pragma unroll
        for (int q = 0; q < 16; ++q) {
          float m = sm[base + q];
          float ee = (&er[q >> 2].x)[q & 3];
          float vv = (&wv[q >> 2].x)[q & 3];
          float kk = (&kf[q >> 2].x)[q & 3];
          m = m * (1.f - wwn * ee) + wwn * vv;
          sm[base + q] = m;
          dotp += kk * m;
          mnp += m * m;
        }
        SCR[ws * 128 + n] = dotp;
        SCR[512 + ws * 128 + n] = mnp;
        const int m = n, ns = ws;
        float wwm = wwn;
        float prn = sm[P2_PREC + m];
        float bwp = 0.f, fwp = 0.f;
#pragma unroll
        for (int kq = 0; kq < 8; ++kq) {
          float4 ww4 = *(const float4*)(sm + P2_WW + ns * 32 + kq * 4);
          float4 pr4 = *(const float4*)(sm + P2_PREC + ns * 32 + kq * 4);
          float4 rw4 = *(const float4*)(sm + P2_RW + ns * 32 + kq * 4);
#pragma unroll
          for (int e = 0; e < 4; ++e) {
            int k = kq * 4 + e;
            int nn = ns * 32 + k;
            float wwo = (&ww4.x)[e];
            float pro = (&pr4.x)[e];
            float rwo = (&rw4.x)[e];
            float L = regL[k];
            L = (1.f - wwo - wwm) * L + pro * wwm;
            if (nn == m) L = 0.f;
            regL[k] = L;
            bwp += L * rwo;
            float LT = regLT[k];
            LT = (1.f - wwm - wwo) * LT + prn * wwo;
            if (nn == m) LT = 0.f;
            regLT[k] = LT;
            fwp += LT * rwo;
          }
        }
        SCR[1024 + ns * 128 + m] = bwp;
        SCR[1536 + ns * 128 + m] = fwp;
      }
      __syncthreads();
      {  // pass2: reductions + prec update
        const int n = tid & 127, role = tid >> 7;
        if (role == 0) {
          sm[P2_DOT + n] = SCR[n] + SCR[128 + n] + SCR[256 + n] + SCR[384 + n];
          float wws = sm[P2_SCAL + S_WWSUM];
          sm[P2_PREC + n] = (1.f - wws) * sm[P2_PREC + n] + sm[P2_WW + n];
        } else if (role == 1) {
          float v = SCR[512 + n] + SCR[640 + n] + SCR[768 + n] + SCR[896 + n];
          sm[P2_MN + n] = sqrtf(v) + 1e-8f;
        } else if (role == 2) {
          sm[P2_BW + n] = SCR[1024 + n] + SCR[1152 + n] + SCR[1280 + n] + SCR[1408 + n];
        } else {
          sm[P2_FW + n] = SCR[1536 + n] + SCR[1664 + n] + SCR[1792 + n] + SCR[1920 + n];
        }
      }
      __syncthreads();
      if (tid < 64) {  // cosine softmax + combine + normalize
        int i0 = 2 * tid, i1 = i0 + 1;
        float q0 = sm[P2_DOT + i0] / (kn_r * sm[P2_MN + i0]) * rstr_r;
        float q1 = sm[P2_DOT + i1] / (kn_r * sm[P2_MN + i1]) * rstr_r;
        float mx = fmaxf(q0, q1);
#pragma unroll
        for (int off = 32; off > 0; off >>= 1) mx = fmaxf(mx, __shfl_xor(mx, off, 64));
        float e0 = expf(q0 - mx), e1 = expf(q1 - mx);
        float es = e0 + e1;
#pragma unroll
        for (int off = 32; off > 0; off >>= 1) es += __shfl_xor(es, off, 64);
        float wv0 = rm0_r * sm[P2_BW + i0] + rm1_r * sm[P2_FW + i0] + rm2_r * (e0 / es) + 1e-8f;
        float wv1 = rm0_r * sm[P2_BW + i1] + rm1_r * sm[P2_FW + i1] + rm2_r * (e1 / es) + 1e-8f;
        float wsum = wv0 + wv1;
#pragma unroll
        for (int off = 32; off > 0; off >>= 1) wsum += __shfl_xor(wsum, off, 64);
        sm[P2_RW + i0] = wv0 / wsum;
        sm[P2_RW + i1] = wv1 / wsum;
      }
      __syncthreads();
      {  // rvec partials
        const int w = tid & 63, ns8 = tid >> 6;
        float4 rw4[4];
#pragma unroll
        for (int r = 0; r < 4; ++r)
          rw4[r] = *(const float4*)(sm + P2_RW + ns8 * 16 + r * 4);
        float p = 0.f;
#pragma unroll
        for (int k = 0; k < 16; ++k)
          p += (&rw4[k >> 2].x)[k & 3] * sm[P2_MEM + (ns8 * 16 + k) * 65 + w];
        SCR[ns8 * 64 + w] = p;
      }
      __syncthreads();
      if (tid < 64) {  // rvec reduce -> tagged store (critical-path exit, no fence)
        float r = 0.f;
#pragma unroll
        for (int s2 = 0; s2 < 8; ++s2) r += SCR[s2 * 64 + tid];
        sm[P2_H + 512 + tid] = r;
        tstore(g_rv64 + (size_t)b * Wd + tid, (unsigned)(t + 1), r);
      }
      __syncthreads();
      // ---- tail (hidden behind P1's next main GEMV): tagged h gather + out proj
      if (tid < 256) {
        const u64* hsrc = g_h64 + (size_t)(t & 1) * (Bb * Hh) + (size_t)b * Hh;
        const u64* a0 = hsrc + tid * 2;
        const u64* a1 = hsrc + tid * 2 + 1;
        u64 v0 = ldrelax(a0), v1 = ldrelax(a1);
        sm[P2_H + tid * 2] = fixwait(a0, v0, (unsigned)(t + 1));
        sm[P2_H + tid * 2 + 1] = fixwait(a1, v1, (unsigned)(t + 1));
      }
      __syncthreads();
      {
        const int o = tid >> 3, seg = tid & 7;
        const float4* wrow = (const float4*)(W_out + (size_t)o * 576) + seg * 18;
        const float4* hb = (const float4*)(sm + P2_H) + seg * 18;
        float p = 0.f;
#pragma unroll
        for (int q = 0; q < 18; ++q) {
          float4 w = wrow[q]; float4 h = hb[q];
          p += w.x * h.x + w.y * h.y + w.z * h.z + w.w * h.w;
        }
        p += __shfl_down(p, 4, 8);
        p += __shfl_down(p, 2, 8);
        p += __shfl_down(p, 1, 8);
        if (seg == 0) out[((size_t)b * Tt + t) * Oo + o] = p + b_out[o];
      }
      __syncthreads();
    }
  }
}

extern "C" void kernel_launch(void* const* d_in, const int* in_sizes, int n_in,
                              void* d_out, int out_size, void* d_ws, size_t ws_size,
                              hipStream_t stream) {
  (void)in_sizes; (void)n_in; (void)d_ws; (void)ws_size; (void)out_size;
  const float* x    = (const float*)d_in[0];
  const float* W_ih = (const float*)d_in[1];
  const float* W_hh = (const float*)d_in[2];
  const float* b_ih = (const float*)d_in[3];
  const float* b_hh = (const float*)d_in[4];
  const float* W_if = (const float*)d_in[5];
  const float* b_if = (const float*)d_in[6];
  const float* W_out = (const float*)d_in[7];
  const float* b_out = (const float*)d_in[8];
  float* out = (float*)d_out;

  dnc_init<<<320, TIN, 0, stream>>>(W_ih, W_hh, b_ih, b_hh);

  hipFuncSetAttribute((const void*)dnc_main,
                      hipFuncAttributeMaxDynamicSharedMemorySize, SMEM_BYTES);

  void* args[] = {(void*)&x, (void*)&W_if, (void*)&b_if,
                  (void*)&W_out, (void*)&b_out, (void*)&out};
  hipLaunchCooperativeKernel((void*)dnc_main, dim3(NWG), dim3(NT), args,
                             SMEM_BYTES, stream);
}